// Round 1
// baseline (1260.081 us; speedup 1.0000x reference)
//
#include <hip/hip_runtime.h>

#define N_NODES 20000
#define N_EDGES 320000
#define N_E2    (N_EDGES + N_NODES)   // 340000 edges incl self loops
#define N_GRAPHS 256
#define HID 256
#define EPS 1e-5f
#define NSCAN 20                       // ceil(20000/1024)

// ---------------------------------------------------------------- CSR build
__global__ void k_init(int* cnt, int* cursor) {
    int i = blockIdx.x * 256 + threadIdx.x;
    if (i < N_NODES) { cnt[i] = 1; cursor[i] = 0; }  // count starts at 1: self loop
}

__global__ void k_count(const int* __restrict__ dst, int* __restrict__ cnt) {
    int e = blockIdx.x * 256 + threadIdx.x;
    if (e < N_EDGES) atomicAdd(&cnt[dst[e]], 1);
}

__global__ void k_scan1(const int* __restrict__ cnt, int* __restrict__ rowp, int* __restrict__ part) {
    __shared__ int ls[256];
    int b = blockIdx.x, tid = threadIdx.x;
    int base = b * 1024 + tid * 4;
    int c[4]; int s = 0;
#pragma unroll
    for (int u = 0; u < 4; u++) { int i = base + u; c[u] = (i < N_NODES) ? cnt[i] : 0; s += c[u]; }
    ls[tid] = s; __syncthreads();
    for (int off = 1; off < 256; off <<= 1) {
        int v = (tid >= off) ? ls[tid - off] : 0;
        __syncthreads();
        ls[tid] += v;
        __syncthreads();
    }
    int excl = ls[tid] - s;
#pragma unroll
    for (int u = 0; u < 4; u++) { int i = base + u; if (i < N_NODES) rowp[i] = excl; excl += c[u]; }
    if (tid == 255) part[b] = ls[255];
}

__global__ void k_scan2(int* part, int* rowp) {
    int s = 0;
    for (int b = 0; b < NSCAN; b++) { int v = part[b]; part[b] = s; s += v; }
    rowp[N_NODES] = s;   // == N_E2
}

__global__ void k_scan3(int* __restrict__ rowp, const int* __restrict__ part) {
    int b = blockIdx.x, tid = threadIdx.x;
    int add = part[b];
    int base = b * 1024 + tid * 4;
#pragma unroll
    for (int u = 0; u < 4; u++) { int i = base + u; if (i < N_NODES) rowp[i] += add; }
}

__global__ void k_fill(const int* __restrict__ src, const int* __restrict__ dst,
                       const int* __restrict__ rowp, int* __restrict__ cursor,
                       int* __restrict__ csr_src, int* __restrict__ csr_aid) {
    int t = blockIdx.x * 256 + threadIdx.x;
    if (t < N_EDGES) {
        int d = dst[t];
        int pos = atomicAdd(&cursor[d], 1);
        int w = rowp[d] + pos;
        csr_src[w] = src[t];
        csr_aid[w] = t;
    } else if (t < N_E2) {
        int n = t - N_EDGES;
        int pos = atomicAdd(&cursor[n], 1);
        int w = rowp[n] + pos;
        csr_src[w] = n;
        csr_aid[w] = N_EDGES + n;   // self loop, attr = loop_attr[n]
    }
}

// loop_attr[n][j] = mean over incoming (original) edges of edge_attr
__global__ void k_loopattr(const int* __restrict__ rowp, const int* __restrict__ csr_aid,
                           const float* __restrict__ edge_attr, float* __restrict__ lattr) {
    int t = blockIdx.x * 256 + threadIdx.x;
    if (t >= N_NODES * 16) return;
    int n = t >> 4, j = t & 15;
    int st = rowp[n], en = rowp[n + 1];
    float s = 0.f;
    for (int i = st; i < en; i++) {
        int aid = csr_aid[i];
        if (aid < N_EDGES) s += edge_attr[(size_t)aid * 16 + j];
    }
    float deg = (float)(en - st - 1);
    lattr[(size_t)n * 16 + j] = s / fmaxf(deg, 1.0f);
}

// ---------------------------------------------------------------- GEMM (fp32)
// C[M,Nc] = epi(A[M,K] @ B[K,Nc] + bias) ; EPI: 0=bias 1=bias+relu 2=bias+bn+relu
#define BM 128
#define BN 64
#define BK 16

template <int EPI>
__global__ __launch_bounds__(256) void k_gemm(
    const float* __restrict__ A, const float* __restrict__ B,
    const float* __restrict__ bias,
    const float* __restrict__ bng, const float* __restrict__ bnb,
    const float* __restrict__ bnm, const float* __restrict__ bnv,
    float* __restrict__ C,
    int M, int K, int lda, int ldb, int ldc, int coff)
{
    __shared__ float As[BK][BM + 4];
    __shared__ float Bs[BK][BN + 4];
    int tid = threadIdx.x;
    int tr = tid >> 4, tc = tid & 15;        // 16x16 threads, 8x4 tile each
    int m0 = blockIdx.x * BM, n0 = blockIdx.y * BN;

    float acc[8][4];
#pragma unroll
    for (int i = 0; i < 8; i++)
#pragma unroll
        for (int j = 0; j < 4; j++) acc[i][j] = 0.f;

    int ktiles = K / BK;
    for (int kt = 0; kt < ktiles; kt++) {
        // stage A: 512 float4s, 2 per thread, store transposed
#pragma unroll
        for (int q = 0; q < 2; q++) {
            int f = q * 256 + tid;
            int row = f >> 2, kq = (f & 3) * 4;
            float4 v = make_float4(0.f, 0.f, 0.f, 0.f);
            if (m0 + row < M)
                v = *(const float4*)(A + (size_t)(m0 + row) * lda + kt * BK + kq);
            As[kq + 0][row] = v.x; As[kq + 1][row] = v.y;
            As[kq + 2][row] = v.z; As[kq + 3][row] = v.w;
        }
        // stage B: 256 float4s, 1 per thread
        {
            int k = tid >> 4, nq = (tid & 15) * 4;
            float4 v = *(const float4*)(B + (size_t)(kt * BK + k) * ldb + n0 + nq);
            *(float4*)&Bs[k][nq] = v;
        }
        __syncthreads();
#pragma unroll
        for (int kk = 0; kk < BK; kk++) {
            float4 a0 = *(const float4*)&As[kk][tr * 8];
            float4 a1 = *(const float4*)&As[kk][tr * 8 + 4];
            float4 b0 = *(const float4*)&Bs[kk][tc * 4];
            float a[8] = {a0.x, a0.y, a0.z, a0.w, a1.x, a1.y, a1.z, a1.w};
            float bb[4] = {b0.x, b0.y, b0.z, b0.w};
#pragma unroll
            for (int i = 0; i < 8; i++)
#pragma unroll
                for (int j = 0; j < 4; j++) acc[i][j] += a[i] * bb[j];
        }
        __syncthreads();
    }

#pragma unroll
    for (int i = 0; i < 8; i++) {
        int m = m0 + tr * 8 + i;
        if (m >= M) continue;
        float4 o;
#pragma unroll
        for (int j = 0; j < 4; j++) {
            int c = n0 + tc * 4 + j;
            float v = acc[i][j] + bias[c];
            if (EPI == 2)
                v = (v - bnm[c]) * rsqrtf(bnv[c] + EPS) * bng[c] + bnb[c];
            if (EPI >= 1) v = fmaxf(v, 0.f);
            ((float*)&o)[j] = v;
        }
        *(float4*)(C + (size_t)m * ldc + coff + n0 + tc * 4) = o;
    }
}

static void gemm(int epi, const float* A, const float* B, const float* bias,
                 const float* g, const float* b2, const float* m, const float* v,
                 float* C, int M, int K, int Nc, int lda, int ldb, int ldc, int coff,
                 hipStream_t st) {
    dim3 grid((M + BM - 1) / BM, Nc / BN);
    if (epi == 0)      k_gemm<0><<<grid, 256, 0, st>>>(A, B, bias, g, b2, m, v, C, M, K, lda, ldb, ldc, coff);
    else if (epi == 1) k_gemm<1><<<grid, 256, 0, st>>>(A, B, bias, g, b2, m, v, C, M, K, lda, ldb, ldc, coff);
    else               k_gemm<2><<<grid, 256, 0, st>>>(A, B, bias, g, b2, m, v, C, M, K, lda, ldb, ldc, coff);
}

// ---------------------------------------------------------------- GATv2 edge pass
// one wave per node; online softmax over incoming CSR edges; epilogue fuses
// +conv_bias -> BN -> relu -> +residual, updating h in place.
__global__ __launch_bounds__(256) void k_edge(
    const float* __restrict__ xlr,       // [N, 512]: cols 0..255 = xl, 256..511 = xr
    const float* __restrict__ edge_attr, // [E,16]
    const float* __restrict__ lattr,     // [N,16]
    const int* __restrict__ rowp, const int* __restrict__ csr_src, const int* __restrict__ csr_aid,
    const float* __restrict__ We,        // [16,256]
    const float* __restrict__ att,       // [4,64]
    const float* __restrict__ cbias,
    const float* __restrict__ bng, const float* __restrict__ bnb,
    const float* __restrict__ bnm, const float* __restrict__ bnv,
    float* __restrict__ h)               // [N,256] in/out
{
    int lane = threadIdx.x & 63;
    int wv = threadIdx.x >> 6;
    int n = blockIdx.x * 4 + wv;
    if (n >= N_NODES) return;

    // We kept entirely in registers: we_r[j][h] = We[j][h*64+lane]
    float we_r[16][4];
#pragma unroll
    for (int j = 0; j < 16; j++)
#pragma unroll
        for (int hh = 0; hh < 4; hh++)
            we_r[j][hh] = We[j * HID + hh * 64 + lane];

    float att_r[4], xr_r[4], hin_r[4];
#pragma unroll
    for (int hh = 0; hh < 4; hh++) {
        att_r[hh] = att[hh * 64 + lane];
        xr_r[hh]  = xlr[(size_t)n * 512 + 256 + hh * 64 + lane];
        hin_r[hh] = h[(size_t)n * 256 + hh * 64 + lane];
    }

    float m_r[4], den[4], acc[4];
#pragma unroll
    for (int hh = 0; hh < 4; hh++) { m_r[hh] = -3.0e38f; den[hh] = 0.f; acc[hh] = 0.f; }

    int st = rowp[n], en = rowp[n + 1];
    for (int idx = st; idx < en; idx++) {
        int s   = csr_src[idx];
        int aid = csr_aid[idx];
        const float* ap = (aid < N_EDGES) ? (edge_attr + (size_t)aid * 16)
                                          : (lattr + (size_t)(aid - N_EDGES) * 16);
        const float4* ea4 = (const float4*)ap;
        float4 e0 = ea4[0], e1 = ea4[1], e2 = ea4[2], e3 = ea4[3];

        float xl_s[4], z[4];
#pragma unroll
        for (int hh = 0; hh < 4; hh++) {
            xl_s[hh] = xlr[(size_t)s * 512 + hh * 64 + lane];
            float t = xl_s[hh] + xr_r[hh];
            t += e0.x * we_r[0][hh];  t += e0.y * we_r[1][hh];
            t += e0.z * we_r[2][hh];  t += e0.w * we_r[3][hh];
            t += e1.x * we_r[4][hh];  t += e1.y * we_r[5][hh];
            t += e1.z * we_r[6][hh];  t += e1.w * we_r[7][hh];
            t += e2.x * we_r[8][hh];  t += e2.y * we_r[9][hh];
            t += e2.z * we_r[10][hh]; t += e2.w * we_r[11][hh];
            t += e3.x * we_r[12][hh]; t += e3.y * we_r[13][hh];
            t += e3.z * we_r[14][hh]; t += e3.w * we_r[15][hh];
            z[hh] = (t >= 0.f) ? t : 0.2f * t;   // leaky_relu 0.2
        }
        float p0 = z[0] * att_r[0], p1 = z[1] * att_r[1];
        float p2 = z[2] * att_r[2], p3 = z[3] * att_r[3];
#pragma unroll
        for (int off = 32; off >= 1; off >>= 1) {
            p0 += __shfl_xor(p0, off, 64);
            p1 += __shfl_xor(p1, off, 64);
            p2 += __shfl_xor(p2, off, 64);
            p3 += __shfl_xor(p3, off, 64);
        }
        float al[4] = {p0, p1, p2, p3};
#pragma unroll
        for (int hh = 0; hh < 4; hh++) {
            float nm = fmaxf(m_r[hh], al[hh]);
            float sc = __expf(m_r[hh] - nm);
            float p  = __expf(al[hh] - nm);
            den[hh] = den[hh] * sc + p;
            acc[hh] = acc[hh] * sc + p * xl_s[hh];
            m_r[hh] = nm;
        }
    }

#pragma unroll
    for (int hh = 0; hh < 4; hh++) {
        int c = hh * 64 + lane;
        float o = acc[hh] / den[hh] + cbias[c];
        o = (o - bnm[c]) * rsqrtf(bnv[c] + EPS) * bng[c] + bnb[c];
        o = fmaxf(o, 0.f) + hin_r[hh];
        h[(size_t)n * 256 + c] = o;
    }
}

// ---------------------------------------------------------------- pooling + classifier tail
__global__ void k_pool(const float* __restrict__ h, float* __restrict__ xp) {
    int g = blockIdx.x, c = threadIdx.x;
    int st = (g * N_NODES + N_GRAPHS - 1) / N_GRAPHS;
    int en = ((g + 1) * N_NODES + N_GRAPHS - 1) / N_GRAPHS;
    float s = 0.f, mx = -3.0e38f;
    for (int i = st; i < en; i++) {
        float v = h[(size_t)i * 256 + c];
        s += v;
        mx = fmaxf(mx, v);
    }
    xp[g * 512 + c] = s / (float)(en - st);
    xp[g * 512 + 256 + c] = mx;
}

__global__ void k_final(const float* __restrict__ z2, const float* __restrict__ W3,
                        const float* __restrict__ b3, float* __restrict__ out) {
    int m = threadIdx.x;
    float s = b3[0];
    for (int k = 0; k < 128; k++) s += z2[m * 128 + k] * W3[k];
    out[m] = s;
}

// ---------------------------------------------------------------- launch
extern "C" void kernel_launch(void* const* d_in, const int* in_sizes, int n_in,
                              void* d_out, int out_size, void* d_ws, size_t ws_size,
                              hipStream_t stream) {
    const float* x         = (const float*)d_in[0];
    const int*   ei        = (const int*)d_in[1];
    const int*   src       = ei;
    const int*   dst       = ei + N_EDGES;
    const float* edge_attr = (const float*)d_in[3];
    const float* enc_W     = (const float*)d_in[4];
    const float* enc_b     = (const float*)d_in[5];
    const float* conv_Wl   = (const float*)d_in[6];
    const float* conv_bl   = (const float*)d_in[7];
    const float* conv_Wr   = (const float*)d_in[8];
    const float* conv_br   = (const float*)d_in[9];
    const float* conv_We   = (const float*)d_in[10];
    const float* conv_att  = (const float*)d_in[11];
    const float* conv_bias = (const float*)d_in[12];
    const float* bn_g      = (const float*)d_in[13];
    const float* bn_b      = (const float*)d_in[14];
    const float* bn_m      = (const float*)d_in[15];
    const float* bn_v      = (const float*)d_in[16];
    const float* cls_W1    = (const float*)d_in[17];
    const float* cls_b1    = (const float*)d_in[18];
    const float* cls_g1    = (const float*)d_in[19];
    const float* cls_bt1   = (const float*)d_in[20];
    const float* cls_m1    = (const float*)d_in[21];
    const float* cls_v1    = (const float*)d_in[22];
    const float* cls_W2    = (const float*)d_in[23];
    const float* cls_b2    = (const float*)d_in[24];
    const float* cls_g2    = (const float*)d_in[25];
    const float* cls_bt2   = (const float*)d_in[26];
    const float* cls_m2    = (const float*)d_in[27];
    const float* cls_v2    = (const float*)d_in[28];
    const float* cls_W3    = (const float*)d_in[29];
    const float* cls_b3    = (const float*)d_in[30];
    float* out = (float*)d_out;

    char* ws = (char*)d_ws;
    size_t off = 0;
    auto alloc = [&](size_t bytes) -> void* {
        void* p = ws + off;
        off += (bytes + 255) & ~(size_t)255;
        return p;
    };
    float* h       = (float*)alloc((size_t)N_NODES * 256 * 4);   // 20.5 MB
    float* xlr     = (float*)alloc((size_t)N_NODES * 512 * 4);   // 41 MB
    float* lattr   = (float*)alloc((size_t)N_NODES * 16 * 4);    // 1.3 MB
    float* xp      = (float*)alloc((size_t)N_GRAPHS * 512 * 4);
    float* z1      = (float*)alloc((size_t)N_GRAPHS * 256 * 4);
    float* z2      = (float*)alloc((size_t)N_GRAPHS * 128 * 4);
    int*   cnt     = (int*)alloc((size_t)N_NODES * 4);
    int*   rowp    = (int*)alloc((size_t)(N_NODES + 1) * 4);
    int*   cursor  = (int*)alloc((size_t)N_NODES * 4);
    int*   csr_src = (int*)alloc((size_t)N_E2 * 4);
    int*   csr_aid = (int*)alloc((size_t)N_E2 * 4);
    int*   part    = (int*)alloc(64 * 4);

    // CSR build
    k_init<<<(N_NODES + 255) / 256, 256, 0, stream>>>(cnt, cursor);
    k_count<<<(N_EDGES + 255) / 256, 256, 0, stream>>>(dst, cnt);
    k_scan1<<<NSCAN, 256, 0, stream>>>(cnt, rowp, part);
    k_scan2<<<1, 1, 0, stream>>>(part, rowp);
    k_scan3<<<NSCAN, 256, 0, stream>>>(rowp, part);
    k_fill<<<(N_E2 + 255) / 256, 256, 0, stream>>>(src, dst, rowp, cursor, csr_src, csr_aid);
    k_loopattr<<<(N_NODES * 16 + 255) / 256, 256, 0, stream>>>(rowp, csr_aid, edge_attr, lattr);

    // encoder: h = relu(x @ enc_W + enc_b)
    gemm(1, x, enc_W, enc_b, nullptr, nullptr, nullptr, nullptr,
         h, N_NODES, 64, 256, 64, 256, 256, 0, stream);

    // 3 GATv2 layers
    for (int i = 0; i < 3; i++) {
        gemm(0, h, conv_Wl + (size_t)i * HID * HID, conv_bl + i * HID,
             nullptr, nullptr, nullptr, nullptr,
             xlr, N_NODES, HID, HID, HID, HID, 512, 0, stream);
        gemm(0, h, conv_Wr + (size_t)i * HID * HID, conv_br + i * HID,
             nullptr, nullptr, nullptr, nullptr,
             xlr, N_NODES, HID, HID, HID, HID, 512, 256, stream);
        k_edge<<<N_NODES / 4, 256, 0, stream>>>(
            xlr, edge_attr, lattr, rowp, csr_src, csr_aid,
            conv_We + (size_t)i * 16 * HID, conv_att + (size_t)i * 256,
            conv_bias + (size_t)i * HID,
            bn_g + (size_t)i * HID, bn_b + (size_t)i * HID,
            bn_m + (size_t)i * HID, bn_v + (size_t)i * HID, h);
    }

    // pooling + classifier
    k_pool<<<N_GRAPHS, 256, 0, stream>>>(h, xp);
    gemm(2, xp, cls_W1, cls_b1, cls_g1, cls_bt1, cls_m1, cls_v1,
         z1, N_GRAPHS, 512, 256, 512, 256, 256, 0, stream);
    gemm(2, z1, cls_W2, cls_b2, cls_g2, cls_bt2, cls_m2, cls_v2,
         z2, N_GRAPHS, 256, 128, 256, 128, 128, 0, stream);
    k_final<<<1, 256, 0, stream>>>(z2, cls_W3, cls_b3, out);
}

// Round 2
// 994.375 us; speedup vs baseline: 1.2672x; 1.2672x over previous
//
#include <hip/hip_runtime.h>

#define N_NODES 20000
#define N_EDGES 320000
#define N_E2    (N_EDGES + N_NODES)   // 340000 edges incl self loops
#define N_GRAPHS 256
#define HID 256
#define EPS 1e-5f
#define NSCAN 20                       // ceil(20000/1024)

// ---------------------------------------------------------------- CSR build
__global__ void k_init(int* cnt, int* cursor) {
    int i = blockIdx.x * 256 + threadIdx.x;
    if (i < N_NODES) { cnt[i] = 1; cursor[i] = 0; }  // count starts at 1: self loop
}

__global__ void k_count(const int* __restrict__ dst, int* __restrict__ cnt) {
    int e = blockIdx.x * 256 + threadIdx.x;
    if (e < N_EDGES) atomicAdd(&cnt[dst[e]], 1);
}

__global__ void k_scan1(const int* __restrict__ cnt, int* __restrict__ rowp, int* __restrict__ part) {
    __shared__ int ls[256];
    int b = blockIdx.x, tid = threadIdx.x;
    int base = b * 1024 + tid * 4;
    int c[4]; int s = 0;
#pragma unroll
    for (int u = 0; u < 4; u++) { int i = base + u; c[u] = (i < N_NODES) ? cnt[i] : 0; s += c[u]; }
    ls[tid] = s; __syncthreads();
    for (int off = 1; off < 256; off <<= 1) {
        int v = (tid >= off) ? ls[tid - off] : 0;
        __syncthreads();
        ls[tid] += v;
        __syncthreads();
    }
    int excl = ls[tid] - s;
#pragma unroll
    for (int u = 0; u < 4; u++) { int i = base + u; if (i < N_NODES) rowp[i] = excl; excl += c[u]; }
    if (tid == 255) part[b] = ls[255];
}

__global__ void k_scan2(int* part, int* rowp) {
    int s = 0;
    for (int b = 0; b < NSCAN; b++) { int v = part[b]; part[b] = s; s += v; }
    rowp[N_NODES] = s;   // == N_E2
}

__global__ void k_scan3(int* __restrict__ rowp, const int* __restrict__ part) {
    int b = blockIdx.x, tid = threadIdx.x;
    int add = part[b];
    int base = b * 1024 + tid * 4;
#pragma unroll
    for (int u = 0; u < 4; u++) { int i = base + u; if (i < N_NODES) rowp[i] += add; }
}

__global__ void k_fill(const int* __restrict__ src, const int* __restrict__ dst,
                       const int* __restrict__ rowp, int* __restrict__ cursor,
                       int* __restrict__ csr_src, int* __restrict__ csr_dst,
                       int* __restrict__ csr_aid) {
    int t = blockIdx.x * 256 + threadIdx.x;
    if (t < N_EDGES) {
        int d = dst[t];
        int pos = atomicAdd(&cursor[d], 1);
        int w = rowp[d] + pos;
        csr_src[w] = src[t];
        csr_dst[w] = d;
        csr_aid[w] = t;
    } else if (t < N_E2) {
        int n = t - N_EDGES;
        int pos = atomicAdd(&cursor[n], 1);
        int w = rowp[n] + pos;
        csr_src[w] = n;
        csr_dst[w] = n;
        csr_aid[w] = N_EDGES + n;   // self loop, attr = loop_attr[n]
    }
}

// loop_attr[n][j] = mean over incoming (original) edges of edge_attr
__global__ void k_loopattr(const int* __restrict__ rowp, const int* __restrict__ csr_aid,
                           const float* __restrict__ edge_attr, float* __restrict__ lattr) {
    int t = blockIdx.x * 256 + threadIdx.x;
    if (t >= N_NODES * 16) return;
    int n = t >> 4, j = t & 15;
    int st = rowp[n], en = rowp[n + 1];
    float s = 0.f;
    for (int i = st; i < en; i++) {
        int aid = csr_aid[i];
        if (aid < N_EDGES) s += edge_attr[(size_t)aid * 16 + j];
    }
    float deg = (float)(en - st - 1);
    lattr[(size_t)n * 16 + j] = s / fmaxf(deg, 1.0f);
}

// ---------------------------------------------------------------- GEMM (fp32)
#define BM 128
#define BN 64
#define BK 16

template <int EPI>
__global__ __launch_bounds__(256) void k_gemm(
    const float* __restrict__ A, const float* __restrict__ B,
    const float* __restrict__ bias,
    const float* __restrict__ bng, const float* __restrict__ bnb,
    const float* __restrict__ bnm, const float* __restrict__ bnv,
    float* __restrict__ C,
    int M, int K, int lda, int ldb, int ldc, int coff)
{
    __shared__ float As[BK][BM + 4];
    __shared__ float Bs[BK][BN + 4];
    int tid = threadIdx.x;
    int tr = tid >> 4, tc = tid & 15;        // 16x16 threads, 8x4 tile each
    int m0 = blockIdx.x * BM, n0 = blockIdx.y * BN;

    float acc[8][4];
#pragma unroll
    for (int i = 0; i < 8; i++)
#pragma unroll
        for (int j = 0; j < 4; j++) acc[i][j] = 0.f;

    int ktiles = K / BK;
    for (int kt = 0; kt < ktiles; kt++) {
#pragma unroll
        for (int q = 0; q < 2; q++) {
            int f = q * 256 + tid;
            int row = f >> 2, kq = (f & 3) * 4;
            float4 v = make_float4(0.f, 0.f, 0.f, 0.f);
            if (m0 + row < M)
                v = *(const float4*)(A + (size_t)(m0 + row) * lda + kt * BK + kq);
            As[kq + 0][row] = v.x; As[kq + 1][row] = v.y;
            As[kq + 2][row] = v.z; As[kq + 3][row] = v.w;
        }
        {
            int k = tid >> 4, nq = (tid & 15) * 4;
            float4 v = *(const float4*)(B + (size_t)(kt * BK + k) * ldb + n0 + nq);
            *(float4*)&Bs[k][nq] = v;
        }
        __syncthreads();
#pragma unroll
        for (int kk = 0; kk < BK; kk++) {
            float4 a0 = *(const float4*)&As[kk][tr * 8];
            float4 a1 = *(const float4*)&As[kk][tr * 8 + 4];
            float4 b0 = *(const float4*)&Bs[kk][tc * 4];
            float a[8] = {a0.x, a0.y, a0.z, a0.w, a1.x, a1.y, a1.z, a1.w};
            float bb[4] = {b0.x, b0.y, b0.z, b0.w};
#pragma unroll
            for (int i = 0; i < 8; i++)
#pragma unroll
                for (int j = 0; j < 4; j++) acc[i][j] += a[i] * bb[j];
        }
        __syncthreads();
    }

#pragma unroll
    for (int i = 0; i < 8; i++) {
        int m = m0 + tr * 8 + i;
        if (m >= M) continue;
        float4 o;
#pragma unroll
        for (int j = 0; j < 4; j++) {
            int c = n0 + tc * 4 + j;
            float v = acc[i][j] + bias[c];
            if (EPI == 2)
                v = (v - bnm[c]) * rsqrtf(bnv[c] + EPS) * bng[c] + bnb[c];
            if (EPI >= 1) v = fmaxf(v, 0.f);
            ((float*)&o)[j] = v;
        }
        *(float4*)(C + (size_t)m * ldc + coff + n0 + tc * 4) = o;
    }
}

static void gemm(int epi, const float* A, const float* B, const float* bias,
                 const float* g, const float* b2, const float* m, const float* v,
                 float* C, int M, int K, int Nc, int lda, int ldb, int ldc, int coff,
                 hipStream_t st) {
    dim3 grid((M + BM - 1) / BM, Nc / BN);
    if (epi == 0)      k_gemm<0><<<grid, 256, 0, st>>>(A, B, bias, g, b2, m, v, C, M, K, lda, ldb, ldc, coff);
    else if (epi == 1) k_gemm<1><<<grid, 256, 0, st>>>(A, B, bias, g, b2, m, v, C, M, K, lda, ldb, ldc, coff);
    else               k_gemm<2><<<grid, 256, 0, st>>>(A, B, bias, g, b2, m, v, C, M, K, lda, ldb, ldc, coff);
}

// ---------------------------------------------------------------- GATv2 pass 1: alpha per edge
// one wave per 8 CSR edges; lane l -> head g=l>>4, channels c0 = g*64 + (l&15)*4 .. +3
#define EPW 8
__global__ __launch_bounds__(256) void k_alpha(
    const float* __restrict__ xlr,       // [N,512] xl|xr
    const float* __restrict__ edge_attr, const float* __restrict__ lattr,
    const int* __restrict__ csr_src, const int* __restrict__ csr_dst,
    const int* __restrict__ csr_aid,
    const float* __restrict__ We,        // [16,256]
    const float* __restrict__ att,       // [4,64] flat = [256]
    float* __restrict__ alpha)           // [E2,4], CSR order
{
    int lane = threadIdx.x & 63;
    int wid = blockIdx.x * 4 + (threadIdx.x >> 6);
    int e0 = wid * EPW;
    if (e0 >= N_E2) return;
    int g = lane >> 4, t = lane & 15;
    int c0 = g * 64 + t * 4;

    float werr[16][4];
#pragma unroll
    for (int j = 0; j < 16; j++) {
        float4 v = *(const float4*)(We + j * HID + c0);
        werr[j][0] = v.x; werr[j][1] = v.y; werr[j][2] = v.z; werr[j][3] = v.w;
    }
    float4 atv = *(const float4*)(att + c0);
    float attv[4] = {atv.x, atv.y, atv.z, atv.w};

    int e1 = min(e0 + EPW, N_E2);
    for (int e = e0; e < e1; e++) {
        int s   = __builtin_amdgcn_readfirstlane(csr_src[e]);
        int d   = __builtin_amdgcn_readfirstlane(csr_dst[e]);
        int aid = __builtin_amdgcn_readfirstlane(csr_aid[e]);
        const float* ap = (aid < N_EDGES) ? edge_attr + (size_t)aid * 16
                                          : lattr + (size_t)(aid - N_EDGES) * 16;
        float eav[16];
#pragma unroll
        for (int q = 0; q < 4; q++) {
            float4 v = ((const float4*)ap)[q];
            eav[q * 4 + 0] = v.x; eav[q * 4 + 1] = v.y;
            eav[q * 4 + 2] = v.z; eav[q * 4 + 3] = v.w;
        }
        float4 xlv = *(const float4*)(xlr + (size_t)s * 512 + c0);
        float4 xrv = *(const float4*)(xlr + (size_t)d * 512 + 256 + c0);
        float xl[4] = {xlv.x, xlv.y, xlv.z, xlv.w};
        float xr[4] = {xrv.x, xrv.y, xrv.z, xrv.w};

        float p = 0.f;
#pragma unroll
        for (int u = 0; u < 4; u++) {
            float tt = xl[u] + xr[u];
#pragma unroll
            for (int j = 0; j < 16; j++) tt += eav[j] * werr[j][u];
            tt = (tt >= 0.f) ? tt : 0.2f * tt;   // leaky_relu 0.2
            p += tt * attv[u];
        }
        p += __shfl_xor(p, 1, 64);
        p += __shfl_xor(p, 2, 64);
        p += __shfl_xor(p, 4, 64);
        p += __shfl_xor(p, 8, 64);
        if (t == 0) alpha[(size_t)e * 4 + g] = p;
    }
}

// ---------------------------------------------------------------- GATv2 pass 2: softmax + aggregate
// one wave per node; chunked (64 edges) softmax over precomputed alphas; fused epilogue.
__global__ __launch_bounds__(256) void k_aggr(
    const float* __restrict__ xlr, const float* __restrict__ alpha,
    const int* __restrict__ rowp, const int* __restrict__ csr_src,
    const float* __restrict__ cbias,
    const float* __restrict__ bng, const float* __restrict__ bnb,
    const float* __restrict__ bnm, const float* __restrict__ bnv,
    float* __restrict__ h)               // [N,256] in/out
{
    __shared__ float lex[4][64][4];      // [wave][edge-in-chunk][head]
    __shared__ int   lsrc[4][64];
    int lane = threadIdx.x & 63;
    int wv = threadIdx.x >> 6;
    int n = blockIdx.x * 4 + wv;
    if (n >= N_NODES) return;
    int st = rowp[n], en = rowp[n + 1];
    int hsel = lane >> 4;                // head owning channels c0..c0+3
    int c0 = lane * 4;

    float m4[4]  = {-3.0e38f, -3.0e38f, -3.0e38f, -3.0e38f};
    float den4[4] = {0.f, 0.f, 0.f, 0.f};
    float acc[4]  = {0.f, 0.f, 0.f, 0.f};

    for (int cs = st; cs < en; cs += 64) {
        int cnt = min(64, en - cs);
        float a4[4];
        int s_i = 0;
        if (lane < cnt) {
            float4 v = *(const float4*)(alpha + (size_t)(cs + lane) * 4);
            a4[0] = v.x; a4[1] = v.y; a4[2] = v.z; a4[3] = v.w;
            s_i = csr_src[cs + lane];
        } else {
            a4[0] = a4[1] = a4[2] = a4[3] = -3.0e38f;
        }
        // chunk max per head (full-wave butterfly)
        float cm[4] = {a4[0], a4[1], a4[2], a4[3]};
#pragma unroll
        for (int o = 32; o >= 1; o >>= 1)
#pragma unroll
            for (int u = 0; u < 4; u++) cm[u] = fmaxf(cm[u], __shfl_xor(cm[u], o, 64));
        // merge with running max, rescale den/acc
        float sc[4];
#pragma unroll
        for (int u = 0; u < 4; u++) {
            float nm = fmaxf(m4[u], cm[u]);
            sc[u] = __expf(m4[u] - nm);      // m4=-3e38 first chunk: -3e38-(-3e38)=0 -> 1, den=0 anyway
            den4[u] *= sc[u];
            m4[u] = nm;
        }
        float scl = sc[hsel];
#pragma unroll
        for (int u = 0; u < 4; u++) acc[u] *= scl;
        // exp
        float ex[4];
#pragma unroll
        for (int u = 0; u < 4; u++) ex[u] = (lane < cnt) ? __expf(a4[u] - m4[u]) : 0.f;
        float sx[4] = {ex[0], ex[1], ex[2], ex[3]};
#pragma unroll
        for (int o = 32; o >= 1; o >>= 1)
#pragma unroll
            for (int u = 0; u < 4; u++) sx[u] += __shfl_xor(sx[u], o, 64);
#pragma unroll
        for (int u = 0; u < 4; u++) den4[u] += sx[u];
        // stash chunk to LDS (wave-private region; no barrier needed)
        *(float4*)&lex[wv][lane][0] = make_float4(ex[0], ex[1], ex[2], ex[3]);
        lsrc[wv][lane] = s_i;
        // weighted gather-sum
        int j = 0;
        for (; j + 4 <= cnt; j += 4) {
#pragma unroll
            for (int q = 0; q < 4; q++) {
                float a = lex[wv][j + q][hsel];
                int sj = lsrc[wv][j + q];
                float4 xl = *(const float4*)(xlr + (size_t)sj * 512 + c0);
                acc[0] += a * xl.x; acc[1] += a * xl.y;
                acc[2] += a * xl.z; acc[3] += a * xl.w;
            }
        }
        for (; j < cnt; j++) {
            float a = lex[wv][j][hsel];
            int sj = lsrc[wv][j];
            float4 xl = *(const float4*)(xlr + (size_t)sj * 512 + c0);
            acc[0] += a * xl.x; acc[1] += a * xl.y;
            acc[2] += a * xl.z; acc[3] += a * xl.w;
        }
    }

    float dd = den4[hsel];
    float4 hin = *(const float4*)(h + (size_t)n * 256 + c0);
    float4 cb  = *(const float4*)(cbias + c0);
    float4 gg  = *(const float4*)(bng + c0);
    float4 bb  = *(const float4*)(bnb + c0);
    float4 mm  = *(const float4*)(bnm + c0);
    float4 vv  = *(const float4*)(bnv + c0);
    float hi[4] = {hin.x, hin.y, hin.z, hin.w};
    float cbv[4] = {cb.x, cb.y, cb.z, cb.w};
    float gv[4] = {gg.x, gg.y, gg.z, gg.w};
    float bv[4] = {bb.x, bb.y, bb.z, bb.w};
    float mv[4] = {mm.x, mm.y, mm.z, mm.w};
    float vvv[4] = {vv.x, vv.y, vv.z, vv.w};
    float4 o;
#pragma unroll
    for (int u = 0; u < 4; u++) {
        float val = acc[u] / dd + cbv[u];
        val = (val - mv[u]) * rsqrtf(vvv[u] + EPS) * gv[u] + bv[u];
        ((float*)&o)[u] = fmaxf(val, 0.f) + hi[u];
    }
    *(float4*)(h + (size_t)n * 256 + c0) = o;
}

// ---------------------------------------------------------------- pooling + classifier tail
__global__ void k_pool(const float* __restrict__ h, float* __restrict__ xp) {
    int g = blockIdx.x, c = threadIdx.x;
    int st = (g * N_NODES + N_GRAPHS - 1) / N_GRAPHS;
    int en = ((g + 1) * N_NODES + N_GRAPHS - 1) / N_GRAPHS;
    float s = 0.f, mx = -3.0e38f;
    for (int i = st; i < en; i++) {
        float v = h[(size_t)i * 256 + c];
        s += v;
        mx = fmaxf(mx, v);
    }
    xp[g * 512 + c] = s / (float)(en - st);
    xp[g * 512 + 256 + c] = mx;
}

__global__ void k_final(const float* __restrict__ z2, const float* __restrict__ W3,
                        const float* __restrict__ b3, float* __restrict__ out) {
    int m = threadIdx.x;
    float s = b3[0];
    for (int k = 0; k < 128; k++) s += z2[m * 128 + k] * W3[k];
    out[m] = s;
}

// ---------------------------------------------------------------- launch
extern "C" void kernel_launch(void* const* d_in, const int* in_sizes, int n_in,
                              void* d_out, int out_size, void* d_ws, size_t ws_size,
                              hipStream_t stream) {
    const float* x         = (const float*)d_in[0];
    const int*   ei        = (const int*)d_in[1];
    const int*   src       = ei;
    const int*   dst       = ei + N_EDGES;
    const float* edge_attr = (const float*)d_in[3];
    const float* enc_W     = (const float*)d_in[4];
    const float* enc_b     = (const float*)d_in[5];
    const float* conv_Wl   = (const float*)d_in[6];
    const float* conv_bl   = (const float*)d_in[7];
    const float* conv_Wr   = (const float*)d_in[8];
    const float* conv_br   = (const float*)d_in[9];
    const float* conv_We   = (const float*)d_in[10];
    const float* conv_att  = (const float*)d_in[11];
    const float* conv_bias = (const float*)d_in[12];
    const float* bn_g      = (const float*)d_in[13];
    const float* bn_b      = (const float*)d_in[14];
    const float* bn_m      = (const float*)d_in[15];
    const float* bn_v      = (const float*)d_in[16];
    const float* cls_W1    = (const float*)d_in[17];
    const float* cls_b1    = (const float*)d_in[18];
    const float* cls_g1    = (const float*)d_in[19];
    const float* cls_bt1   = (const float*)d_in[20];
    const float* cls_m1    = (const float*)d_in[21];
    const float* cls_v1    = (const float*)d_in[22];
    const float* cls_W2    = (const float*)d_in[23];
    const float* cls_b2    = (const float*)d_in[24];
    const float* cls_g2    = (const float*)d_in[25];
    const float* cls_bt2   = (const float*)d_in[26];
    const float* cls_m2    = (const float*)d_in[27];
    const float* cls_v2    = (const float*)d_in[28];
    const float* cls_W3    = (const float*)d_in[29];
    const float* cls_b3    = (const float*)d_in[30];
    float* out = (float*)d_out;

    char* ws = (char*)d_ws;
    size_t off = 0;
    auto alloc = [&](size_t bytes) -> void* {
        void* p = ws + off;
        off += (bytes + 255) & ~(size_t)255;
        return p;
    };
    float* h       = (float*)alloc((size_t)N_NODES * 256 * 4);   // 20.5 MB
    float* xlr     = (float*)alloc((size_t)N_NODES * 512 * 4);   // 41 MB
    float* lattr   = (float*)alloc((size_t)N_NODES * 16 * 4);    // 1.3 MB
    float* alphas  = (float*)alloc((size_t)N_E2 * 4 * 4);        // 5.4 MB
    float* xp      = (float*)alloc((size_t)N_GRAPHS * 512 * 4);
    float* z1      = (float*)alloc((size_t)N_GRAPHS * 256 * 4);
    float* z2      = (float*)alloc((size_t)N_GRAPHS * 128 * 4);
    int*   cnt     = (int*)alloc((size_t)N_NODES * 4);
    int*   rowp    = (int*)alloc((size_t)(N_NODES + 1) * 4);
    int*   cursor  = (int*)alloc((size_t)N_NODES * 4);
    int*   csr_src = (int*)alloc((size_t)N_E2 * 4);
    int*   csr_dst = (int*)alloc((size_t)N_E2 * 4);
    int*   csr_aid = (int*)alloc((size_t)N_E2 * 4);
    int*   part    = (int*)alloc(64 * 4);

    // CSR build
    k_init<<<(N_NODES + 255) / 256, 256, 0, stream>>>(cnt, cursor);
    k_count<<<(N_EDGES + 255) / 256, 256, 0, stream>>>(dst, cnt);
    k_scan1<<<NSCAN, 256, 0, stream>>>(cnt, rowp, part);
    k_scan2<<<1, 1, 0, stream>>>(part, rowp);
    k_scan3<<<NSCAN, 256, 0, stream>>>(rowp, part);
    k_fill<<<(N_E2 + 255) / 256, 256, 0, stream>>>(src, dst, rowp, cursor, csr_src, csr_dst, csr_aid);
    k_loopattr<<<(N_NODES * 16 + 255) / 256, 256, 0, stream>>>(rowp, csr_aid, edge_attr, lattr);

    // encoder: h = relu(x @ enc_W + enc_b)
    gemm(1, x, enc_W, enc_b, nullptr, nullptr, nullptr, nullptr,
         h, N_NODES, 64, 256, 64, 256, 256, 0, stream);

    // 3 GATv2 layers
    int nwaves = (N_E2 + EPW - 1) / EPW;
    int ablocks = (nwaves + 3) / 4;
    for (int i = 0; i < 3; i++) {
        gemm(0, h, conv_Wl + (size_t)i * HID * HID, conv_bl + i * HID,
             nullptr, nullptr, nullptr, nullptr,
             xlr, N_NODES, HID, HID, HID, HID, 512, 0, stream);
        gemm(0, h, conv_Wr + (size_t)i * HID * HID, conv_br + i * HID,
             nullptr, nullptr, nullptr, nullptr,
             xlr, N_NODES, HID, HID, HID, HID, 512, 256, stream);
        k_alpha<<<ablocks, 256, 0, stream>>>(
            xlr, edge_attr, lattr, csr_src, csr_dst, csr_aid,
            conv_We + (size_t)i * 16 * HID, conv_att + (size_t)i * 256, alphas);
        k_aggr<<<N_NODES / 4, 256, 0, stream>>>(
            xlr, alphas, rowp, csr_src,
            conv_bias + (size_t)i * HID,
            bn_g + (size_t)i * HID, bn_b + (size_t)i * HID,
            bn_m + (size_t)i * HID, bn_v + (size_t)i * HID, h);
    }

    // pooling + classifier
    k_pool<<<N_GRAPHS, 256, 0, stream>>>(h, xp);
    gemm(2, xp, cls_W1, cls_b1, cls_g1, cls_bt1, cls_m1, cls_v1,
         z1, N_GRAPHS, 512, 256, 512, 256, 256, 0, stream);
    gemm(2, z1, cls_W2, cls_b2, cls_g2, cls_bt2, cls_m2, cls_v2,
         z2, N_GRAPHS, 256, 128, 256, 128, 128, 0, stream);
    k_final<<<1, 256, 0, stream>>>(z2, cls_W3, cls_b3, out);
}

// Round 3
// 941.790 us; speedup vs baseline: 1.3380x; 1.0558x over previous
//
#include <hip/hip_runtime.h>

#define N_NODES 20000
#define N_EDGES 320000
#define N_E2    (N_EDGES + N_NODES)   // 340000 edges incl self loops
#define N_GRAPHS 256
#define HID 256
#define EPS 1e-5f
#define NSCAN 20                       // ceil(20000/1024)

// ---------------------------------------------------------------- CSR build
__global__ void k_init(int* cnt, int* cursor) {
    int i = blockIdx.x * 256 + threadIdx.x;
    if (i < N_NODES) { cnt[i] = 1; cursor[i] = 0; }  // count starts at 1: self loop
}

__global__ void k_count(const int* __restrict__ dst, int* __restrict__ cnt) {
    int e = blockIdx.x * 256 + threadIdx.x;
    if (e < N_EDGES) atomicAdd(&cnt[dst[e]], 1);
}

__global__ void k_scan1(const int* __restrict__ cnt, int* __restrict__ rowp, int* __restrict__ part) {
    __shared__ int ls[256];
    int b = blockIdx.x, tid = threadIdx.x;
    int base = b * 1024 + tid * 4;
    int c[4]; int s = 0;
#pragma unroll
    for (int u = 0; u < 4; u++) { int i = base + u; c[u] = (i < N_NODES) ? cnt[i] : 0; s += c[u]; }
    ls[tid] = s; __syncthreads();
    for (int off = 1; off < 256; off <<= 1) {
        int v = (tid >= off) ? ls[tid - off] : 0;
        __syncthreads();
        ls[tid] += v;
        __syncthreads();
    }
    int excl = ls[tid] - s;
#pragma unroll
    for (int u = 0; u < 4; u++) { int i = base + u; if (i < N_NODES) rowp[i] = excl; excl += c[u]; }
    if (tid == 255) part[b] = ls[255];
}

__global__ void k_scan2(int* part, int* rowp) {
    int s = 0;
    for (int b = 0; b < NSCAN; b++) { int v = part[b]; part[b] = s; s += v; }
    rowp[N_NODES] = s;   // == N_E2
}

__global__ void k_scan3(int* __restrict__ rowp, const int* __restrict__ part) {
    int b = blockIdx.x, tid = threadIdx.x;
    int add = part[b];
    int base = b * 1024 + tid * 4;
#pragma unroll
    for (int u = 0; u < 4; u++) { int i = base + u; if (i < N_NODES) rowp[i] += add; }
}

__global__ void k_fill(const int* __restrict__ src, const int* __restrict__ dst,
                       const int* __restrict__ rowp, int* __restrict__ cursor,
                       int* __restrict__ csr_src, int* __restrict__ csr_dst,
                       int* __restrict__ csr_aid) {
    int t = blockIdx.x * 256 + threadIdx.x;
    if (t < N_EDGES) {
        int d = dst[t];
        int pos = atomicAdd(&cursor[d], 1);
        int w = rowp[d] + pos;
        csr_src[w] = src[t];
        csr_dst[w] = d;
        csr_aid[w] = t;
    } else if (t < N_E2) {
        int n = t - N_EDGES;
        int pos = atomicAdd(&cursor[n], 1);
        int w = rowp[n] + pos;
        csr_src[w] = n;
        csr_dst[w] = n;
        csr_aid[w] = N_EDGES + n;   // self loop, attr = loop_attr[n]
    }
}

// loop_attr[n][j] = mean over incoming (original) edges of edge_attr
__global__ void k_loopattr(const int* __restrict__ rowp, const int* __restrict__ csr_aid,
                           const float* __restrict__ edge_attr, float* __restrict__ lattr) {
    int t = blockIdx.x * 256 + threadIdx.x;
    if (t >= N_NODES * 16) return;
    int n = t >> 4, j = t & 15;
    int st = rowp[n], en = rowp[n + 1];
    float s = 0.f;
    for (int i = st; i < en; i++) {
        int aid = csr_aid[i];
        if (aid < N_EDGES) s += edge_attr[(size_t)aid * 16 + j];
    }
    float deg = (float)(en - st - 1);
    lattr[(size_t)n * 16 + j] = s / fmaxf(deg, 1.0f);
}

// ea_csr[e][0:16] = edge_attr[csr_aid[e]] (or loop_attr), CSR order — built once.
__global__ void k_eacsr(const int* __restrict__ csr_aid,
                        const float* __restrict__ edge_attr,
                        const float* __restrict__ lattr,
                        float* __restrict__ ea_csr) {
    int t = blockIdx.x * 256 + threadIdx.x;
    if (t >= N_E2 * 4) return;
    int e = t >> 2, q = t & 3;
    int aid = csr_aid[e];
    const float* ap = (aid < N_EDGES) ? edge_attr + (size_t)aid * 16
                                      : lattr + (size_t)(aid - N_EDGES) * 16;
    ((float4*)ea_csr)[t] = ((const float4*)ap)[q];
}

// ---------------------------------------------------------------- GEMM (fp32)
#define BM 128
#define BN 64
#define BK 16

template <int EPI>
__global__ __launch_bounds__(256) void k_gemm(
    const float* __restrict__ A, const float* __restrict__ B,
    const float* __restrict__ bias,
    const float* __restrict__ bng, const float* __restrict__ bnb,
    const float* __restrict__ bnm, const float* __restrict__ bnv,
    float* __restrict__ C,
    int M, int K, int lda, int ldb, int ldc, int coff)
{
    __shared__ float As[BK][BM + 4];
    __shared__ float Bs[BK][BN + 4];
    int tid = threadIdx.x;
    int tr = tid >> 4, tc = tid & 15;        // 16x16 threads, 8x4 tile each
    int m0 = blockIdx.x * BM, n0 = blockIdx.y * BN;

    float acc[8][4];
#pragma unroll
    for (int i = 0; i < 8; i++)
#pragma unroll
        for (int j = 0; j < 4; j++) acc[i][j] = 0.f;

    int ktiles = K / BK;
    for (int kt = 0; kt < ktiles; kt++) {
#pragma unroll
        for (int q = 0; q < 2; q++) {
            int f = q * 256 + tid;
            int row = f >> 2, kq = (f & 3) * 4;
            float4 v = make_float4(0.f, 0.f, 0.f, 0.f);
            if (m0 + row < M)
                v = *(const float4*)(A + (size_t)(m0 + row) * lda + kt * BK + kq);
            As[kq + 0][row] = v.x; As[kq + 1][row] = v.y;
            As[kq + 2][row] = v.z; As[kq + 3][row] = v.w;
        }
        {
            int k = tid >> 4, nq = (tid & 15) * 4;
            float4 v = *(const float4*)(B + (size_t)(kt * BK + k) * ldb + n0 + nq);
            *(float4*)&Bs[k][nq] = v;
        }
        __syncthreads();
#pragma unroll
        for (int kk = 0; kk < BK; kk++) {
            float4 a0 = *(const float4*)&As[kk][tr * 8];
            float4 a1 = *(const float4*)&As[kk][tr * 8 + 4];
            float4 b0 = *(const float4*)&Bs[kk][tc * 4];
            float a[8] = {a0.x, a0.y, a0.z, a0.w, a1.x, a1.y, a1.z, a1.w};
            float bb[4] = {b0.x, b0.y, b0.z, b0.w};
#pragma unroll
            for (int i = 0; i < 8; i++)
#pragma unroll
                for (int j = 0; j < 4; j++) acc[i][j] += a[i] * bb[j];
        }
        __syncthreads();
    }

#pragma unroll
    for (int i = 0; i < 8; i++) {
        int m = m0 + tr * 8 + i;
        if (m >= M) continue;
        float4 o;
#pragma unroll
        for (int j = 0; j < 4; j++) {
            int c = n0 + tc * 4 + j;
            float v = acc[i][j] + bias[c];
            if (EPI == 2)
                v = (v - bnm[c]) * rsqrtf(bnv[c] + EPS) * bng[c] + bnb[c];
            if (EPI >= 1) v = fmaxf(v, 0.f);
            ((float*)&o)[j] = v;
        }
        *(float4*)(C + (size_t)m * ldc + coff + n0 + tc * 4) = o;
    }
}

static void gemm(int epi, const float* A, const float* B, const float* bias,
                 const float* g, const float* b2, const float* m, const float* v,
                 float* C, int M, int K, int Nc, int lda, int ldb, int ldc, int coff,
                 hipStream_t st) {
    dim3 grid((M + BM - 1) / BM, Nc / BN);
    if (epi == 0)      k_gemm<0><<<grid, 256, 0, st>>>(A, B, bias, g, b2, m, v, C, M, K, lda, ldb, ldc, coff);
    else if (epi == 1) k_gemm<1><<<grid, 256, 0, st>>>(A, B, bias, g, b2, m, v, C, M, K, lda, ldb, ldc, coff);
    else               k_gemm<2><<<grid, 256, 0, st>>>(A, B, bias, g, b2, m, v, C, M, K, lda, ldb, ldc, coff);
}

// ---------------------------------------------------------------- GATv2 pass 1: alpha per edge
// one wave per 8 CSR edges; all 16 xl/xr gathers issued before compute;
// ea staged via LDS (sequential ea_csr reads). lane l -> head g=l>>4, t=l&15.
#define EPW 8
__global__ __launch_bounds__(256) void k_alpha(
    const float* __restrict__ xlr,       // [N,512] xl|xr
    const float* __restrict__ ea_csr,    // [E2,16] CSR order
    const int* __restrict__ csr_src, const int* __restrict__ csr_dst,
    const float* __restrict__ We,        // [16,256]
    const float* __restrict__ att,       // [4,64] flat = [256]
    float* __restrict__ alpha)           // [E2,4], CSR order
{
    __shared__ float eas[4][EPW * 16];   // per-wave staging of 8 edges x 16 attrs
    int lane = threadIdx.x & 63;
    int wv = threadIdx.x >> 6;
    int wid = blockIdx.x * 4 + wv;
    int e0 = wid * EPW;                  // grid sized exactly: e0 < N_E2 always
    int g = lane >> 4, t = lane & 15;
    int c0 = g * 64 + t * 4;

    // stage ea for the wave's 8 edges: 128 floats, 2 per lane (coalesced)
    float2 ev = *(const float2*)(ea_csr + (size_t)e0 * 16 + lane * 2);
    *(float2*)&eas[wv][lane * 2] = ev;

    float werr[16][4];
#pragma unroll
    for (int j = 0; j < 16; j++) {
        float4 v = *(const float4*)(We + j * HID + c0);
        werr[j][0] = v.x; werr[j][1] = v.y; werr[j][2] = v.z; werr[j][3] = v.w;
    }
    float4 atv = *(const float4*)(att + c0);
    float attv[4] = {atv.x, atv.y, atv.z, atv.w};

    int sarr[EPW], darr[EPW];
#pragma unroll
    for (int u = 0; u < EPW; u++) {
        sarr[u] = __builtin_amdgcn_readfirstlane(csr_src[e0 + u]);
        darr[u] = __builtin_amdgcn_readfirstlane(csr_dst[e0 + u]);
    }
    // all 16 row-gathers in flight before any compute
    float4 xlv[EPW], xrv[EPW];
#pragma unroll
    for (int u = 0; u < EPW; u++) {
        xlv[u] = *(const float4*)(xlr + (size_t)sarr[u] * 512 + c0);
        xrv[u] = *(const float4*)(xlr + (size_t)darr[u] * 512 + 256 + c0);
    }

#pragma unroll
    for (int u = 0; u < EPW; u++) {
        const float* ea = &eas[wv][u * 16];
        float xl[4] = {xlv[u].x, xlv[u].y, xlv[u].z, xlv[u].w};
        float xr[4] = {xrv[u].x, xrv[u].y, xrv[u].z, xrv[u].w};
        float p = 0.f;
#pragma unroll
        for (int ch = 0; ch < 4; ch++) {
            float tt = xl[ch] + xr[ch];
#pragma unroll
            for (int j = 0; j < 16; j++) tt += ea[j] * werr[j][ch];
            tt = (tt >= 0.f) ? tt : 0.2f * tt;   // leaky_relu 0.2
            p += tt * attv[ch];
        }
        p += __shfl_xor(p, 1, 64);
        p += __shfl_xor(p, 2, 64);
        p += __shfl_xor(p, 4, 64);
        p += __shfl_xor(p, 8, 64);
        if (t == 0) alpha[(size_t)(e0 + u) * 4 + g] = p;
    }
}

// ---------------------------------------------------------------- GATv2 pass 2: softmax + aggregate
__global__ __launch_bounds__(256) void k_aggr(
    const float* __restrict__ xlr, const float* __restrict__ alpha,
    const int* __restrict__ rowp, const int* __restrict__ csr_src,
    const float* __restrict__ cbias,
    const float* __restrict__ bng, const float* __restrict__ bnb,
    const float* __restrict__ bnm, const float* __restrict__ bnv,
    float* __restrict__ h)               // [N,256] in/out
{
    __shared__ float lex[4][64][4];      // [wave][edge-in-chunk][head]
    __shared__ int   lsrc[4][64];
    int lane = threadIdx.x & 63;
    int wv = threadIdx.x >> 6;
    int n = blockIdx.x * 4 + wv;
    if (n >= N_NODES) return;
    int st = rowp[n], en = rowp[n + 1];
    int hsel = lane >> 4;                // head owning channels c0..c0+3
    int c0 = lane * 4;

    float m4[4]  = {-3.0e38f, -3.0e38f, -3.0e38f, -3.0e38f};
    float den4[4] = {0.f, 0.f, 0.f, 0.f};
    float acc[4]  = {0.f, 0.f, 0.f, 0.f};

    for (int cs = st; cs < en; cs += 64) {
        int cnt = min(64, en - cs);
        float a4[4];
        int s_i = 0;
        if (lane < cnt) {
            float4 v = *(const float4*)(alpha + (size_t)(cs + lane) * 4);
            a4[0] = v.x; a4[1] = v.y; a4[2] = v.z; a4[3] = v.w;
            s_i = csr_src[cs + lane];
        } else {
            a4[0] = a4[1] = a4[2] = a4[3] = -3.0e38f;
        }
        float cm[4] = {a4[0], a4[1], a4[2], a4[3]};
#pragma unroll
        for (int o = 32; o >= 1; o >>= 1)
#pragma unroll
            for (int u = 0; u < 4; u++) cm[u] = fmaxf(cm[u], __shfl_xor(cm[u], o, 64));
        float sc[4];
#pragma unroll
        for (int u = 0; u < 4; u++) {
            float nm = fmaxf(m4[u], cm[u]);
            sc[u] = __expf(m4[u] - nm);
            den4[u] *= sc[u];
            m4[u] = nm;
        }
        float scl = sc[hsel];
#pragma unroll
        for (int u = 0; u < 4; u++) acc[u] *= scl;
        float ex[4];
#pragma unroll
        for (int u = 0; u < 4; u++) ex[u] = (lane < cnt) ? __expf(a4[u] - m4[u]) : 0.f;
        float sx[4] = {ex[0], ex[1], ex[2], ex[3]};
#pragma unroll
        for (int o = 32; o >= 1; o >>= 1)
#pragma unroll
            for (int u = 0; u < 4; u++) sx[u] += __shfl_xor(sx[u], o, 64);
#pragma unroll
        for (int u = 0; u < 4; u++) den4[u] += sx[u];
        *(float4*)&lex[wv][lane][0] = make_float4(ex[0], ex[1], ex[2], ex[3]);
        lsrc[wv][lane] = s_i;
        // weighted gather-sum: 8 row-gathers in flight per step
        int j = 0;
        for (; j + 8 <= cnt; j += 8) {
            float a[8]; int sj[8];
#pragma unroll
            for (int q = 0; q < 8; q++) { a[q] = lex[wv][j + q][hsel]; sj[q] = lsrc[wv][j + q]; }
            float4 xg[8];
#pragma unroll
            for (int q = 0; q < 8; q++) xg[q] = *(const float4*)(xlr + (size_t)sj[q] * 512 + c0);
#pragma unroll
            for (int q = 0; q < 8; q++) {
                acc[0] += a[q] * xg[q].x; acc[1] += a[q] * xg[q].y;
                acc[2] += a[q] * xg[q].z; acc[3] += a[q] * xg[q].w;
            }
        }
        for (; j < cnt; j++) {
            float a = lex[wv][j][hsel];
            int sj = lsrc[wv][j];
            float4 xl = *(const float4*)(xlr + (size_t)sj * 512 + c0);
            acc[0] += a * xl.x; acc[1] += a * xl.y;
            acc[2] += a * xl.z; acc[3] += a * xl.w;
        }
    }

    float dd = den4[hsel];
    float4 hin = *(const float4*)(h + (size_t)n * 256 + c0);
    float4 cb  = *(const float4*)(cbias + c0);
    float4 gg  = *(const float4*)(bng + c0);
    float4 bb  = *(const float4*)(bnb + c0);
    float4 mm  = *(const float4*)(bnm + c0);
    float4 vv  = *(const float4*)(bnv + c0);
    float hi[4] = {hin.x, hin.y, hin.z, hin.w};
    float cbv[4] = {cb.x, cb.y, cb.z, cb.w};
    float gv[4] = {gg.x, gg.y, gg.z, gg.w};
    float bv[4] = {bb.x, bb.y, bb.z, bb.w};
    float mv[4] = {mm.x, mm.y, mm.z, mm.w};
    float vvv[4] = {vv.x, vv.y, vv.z, vv.w};
    float4 o;
#pragma unroll
    for (int u = 0; u < 4; u++) {
        float val = acc[u] / dd + cbv[u];
        val = (val - mv[u]) * rsqrtf(vvv[u] + EPS) * gv[u] + bv[u];
        ((float*)&o)[u] = fmaxf(val, 0.f) + hi[u];
    }
    *(float4*)(h + (size_t)n * 256 + c0) = o;
}

// ---------------------------------------------------------------- pooling + classifier tail
__global__ void k_pool(const float* __restrict__ h, float* __restrict__ xp) {
    int g = blockIdx.x, c = threadIdx.x;
    int st = (g * N_NODES + N_GRAPHS - 1) / N_GRAPHS;
    int en = ((g + 1) * N_NODES + N_GRAPHS - 1) / N_GRAPHS;
    float s = 0.f, mx = -3.0e38f;
    for (int i = st; i < en; i++) {
        float v = h[(size_t)i * 256 + c];
        s += v;
        mx = fmaxf(mx, v);
    }
    xp[g * 512 + c] = s / (float)(en - st);
    xp[g * 512 + 256 + c] = mx;
}

__global__ void k_final(const float* __restrict__ z2, const float* __restrict__ W3,
                        const float* __restrict__ b3, float* __restrict__ out) {
    int m = threadIdx.x;
    float s = b3[0];
    for (int k = 0; k < 128; k++) s += z2[m * 128 + k] * W3[k];
    out[m] = s;
}

// ---------------------------------------------------------------- launch
extern "C" void kernel_launch(void* const* d_in, const int* in_sizes, int n_in,
                              void* d_out, int out_size, void* d_ws, size_t ws_size,
                              hipStream_t stream) {
    const float* x         = (const float*)d_in[0];
    const int*   ei        = (const int*)d_in[1];
    const int*   src       = ei;
    const int*   dst       = ei + N_EDGES;
    const float* edge_attr = (const float*)d_in[3];
    const float* enc_W     = (const float*)d_in[4];
    const float* enc_b     = (const float*)d_in[5];
    const float* conv_Wl   = (const float*)d_in[6];
    const float* conv_bl   = (const float*)d_in[7];
    const float* conv_Wr   = (const float*)d_in[8];
    const float* conv_br   = (const float*)d_in[9];
    const float* conv_We   = (const float*)d_in[10];
    const float* conv_att  = (const float*)d_in[11];
    const float* conv_bias = (const float*)d_in[12];
    const float* bn_g      = (const float*)d_in[13];
    const float* bn_b      = (const float*)d_in[14];
    const float* bn_m      = (const float*)d_in[15];
    const float* bn_v      = (const float*)d_in[16];
    const float* cls_W1    = (const float*)d_in[17];
    const float* cls_b1    = (const float*)d_in[18];
    const float* cls_g1    = (const float*)d_in[19];
    const float* cls_bt1   = (const float*)d_in[20];
    const float* cls_m1    = (const float*)d_in[21];
    const float* cls_v1    = (const float*)d_in[22];
    const float* cls_W2    = (const float*)d_in[23];
    const float* cls_b2    = (const float*)d_in[24];
    const float* cls_g2    = (const float*)d_in[25];
    const float* cls_bt2   = (const float*)d_in[26];
    const float* cls_m2    = (const float*)d_in[27];
    const float* cls_v2    = (const float*)d_in[28];
    const float* cls_W3    = (const float*)d_in[29];
    const float* cls_b3    = (const float*)d_in[30];
    float* out = (float*)d_out;

    char* ws = (char*)d_ws;
    size_t off = 0;
    auto alloc = [&](size_t bytes) -> void* {
        void* p = ws + off;
        off += (bytes + 255) & ~(size_t)255;
        return p;
    };
    float* h       = (float*)alloc((size_t)N_NODES * 256 * 4);   // 20.5 MB
    float* xlr     = (float*)alloc((size_t)N_NODES * 512 * 4);   // 41 MB
    float* lattr   = (float*)alloc((size_t)N_NODES * 16 * 4);    // 1.3 MB
    float* ea_csr  = (float*)alloc((size_t)N_E2 * 16 * 4);       // 21.8 MB
    float* alphas  = (float*)alloc((size_t)N_E2 * 4 * 4);        // 5.4 MB
    float* xp      = (float*)alloc((size_t)N_GRAPHS * 512 * 4);
    float* z1      = (float*)alloc((size_t)N_GRAPHS * 256 * 4);
    float* z2      = (float*)alloc((size_t)N_GRAPHS * 128 * 4);
    int*   cnt     = (int*)alloc((size_t)N_NODES * 4);
    int*   rowp    = (int*)alloc((size_t)(N_NODES + 1) * 4);
    int*   cursor  = (int*)alloc((size_t)N_NODES * 4);
    int*   csr_src = (int*)alloc((size_t)N_E2 * 4);
    int*   csr_dst = (int*)alloc((size_t)N_E2 * 4);
    int*   csr_aid = (int*)alloc((size_t)N_E2 * 4);
    int*   part    = (int*)alloc(64 * 4);

    // CSR build
    k_init<<<(N_NODES + 255) / 256, 256, 0, stream>>>(cnt, cursor);
    k_count<<<(N_EDGES + 255) / 256, 256, 0, stream>>>(dst, cnt);
    k_scan1<<<NSCAN, 256, 0, stream>>>(cnt, rowp, part);
    k_scan2<<<1, 1, 0, stream>>>(part, rowp);
    k_scan3<<<NSCAN, 256, 0, stream>>>(rowp, part);
    k_fill<<<(N_E2 + 255) / 256, 256, 0, stream>>>(src, dst, rowp, cursor, csr_src, csr_dst, csr_aid);
    k_loopattr<<<(N_NODES * 16 + 255) / 256, 256, 0, stream>>>(rowp, csr_aid, edge_attr, lattr);
    k_eacsr<<<(N_E2 * 4 + 255) / 256, 256, 0, stream>>>(csr_aid, edge_attr, lattr, ea_csr);

    // encoder: h = relu(x @ enc_W + enc_b)
    gemm(1, x, enc_W, enc_b, nullptr, nullptr, nullptr, nullptr,
         h, N_NODES, 64, 256, 64, 256, 256, 0, stream);

    // 3 GATv2 layers
    int nwaves = (N_E2 + EPW - 1) / EPW;   // 42500
    int ablocks = (nwaves + 3) / 4;        // 10625
    for (int i = 0; i < 3; i++) {
        gemm(0, h, conv_Wl + (size_t)i * HID * HID, conv_bl + i * HID,
             nullptr, nullptr, nullptr, nullptr,
             xlr, N_NODES, HID, HID, HID, HID, 512, 0, stream);
        gemm(0, h, conv_Wr + (size_t)i * HID * HID, conv_br + i * HID,
             nullptr, nullptr, nullptr, nullptr,
             xlr, N_NODES, HID, HID, HID, HID, 512, 256, stream);
        k_alpha<<<ablocks, 256, 0, stream>>>(
            xlr, ea_csr, csr_src, csr_dst,
            conv_We + (size_t)i * 16 * HID, conv_att + (size_t)i * 256, alphas);
        k_aggr<<<N_NODES / 4, 256, 0, stream>>>(
            xlr, alphas, rowp, csr_src,
            conv_bias + (size_t)i * HID,
            bn_g + (size_t)i * HID, bn_b + (size_t)i * HID,
            bn_m + (size_t)i * HID, bn_v + (size_t)i * HID, h);
    }

    // pooling + classifier
    k_pool<<<N_GRAPHS, 256, 0, stream>>>(h, xp);
    gemm(2, xp, cls_W1, cls_b1, cls_g1, cls_bt1, cls_m1, cls_v1,
         z1, N_GRAPHS, 512, 256, 512, 256, 256, 0, stream);
    gemm(2, z1, cls_W2, cls_b2, cls_g2, cls_bt2, cls_m2, cls_v2,
         z2, N_GRAPHS, 256, 128, 256, 128, 128, 0, stream);
    k_final<<<1, 256, 0, stream>>>(z2, cls_W3, cls_b3, out);
}

// Round 5
// 662.384 us; speedup vs baseline: 1.9023x; 1.4218x over previous
//
#include <hip/hip_runtime.h>
#include <hip/hip_bf16.h>

#define N_NODES 20000
#define N_EDGES 320000
#define N_E2    (N_EDGES + N_NODES)   // 340000 edges incl self loops
#define N_GRAPHS 256
#define HID 256
#define EPS 1e-5f
#define NSCAN 20                       // ceil(20000/1024)

typedef unsigned short u16;
typedef __attribute__((ext_vector_type(8))) short short8;
typedef __attribute__((ext_vector_type(4))) float f32x4;

__device__ __forceinline__ float b2f(u16 u) {
    union { unsigned int i; float f; } v; v.i = ((unsigned int)u) << 16; return v.f;
}
__device__ __forceinline__ u16 f2b(float f) {
    __hip_bfloat16 h = __float2bfloat16(f);   // RNE
    return *reinterpret_cast<u16*>(&h);
}

// ---------------------------------------------------------------- CSR build
__global__ void k_init(int* cnt, int* cursor) {
    int i = blockIdx.x * 256 + threadIdx.x;
    if (i < N_NODES) { cnt[i] = 1; cursor[i] = 0; }  // count starts at 1: self loop
}

__global__ void k_count(const int* __restrict__ dst, int* __restrict__ cnt) {
    int e = blockIdx.x * 256 + threadIdx.x;
    if (e < N_EDGES) atomicAdd(&cnt[dst[e]], 1);
}

__global__ void k_scan1(const int* __restrict__ cnt, int* __restrict__ rowp, int* __restrict__ part) {
    __shared__ int ls[256];
    int b = blockIdx.x, tid = threadIdx.x;
    int base = b * 1024 + tid * 4;
    int c[4]; int s = 0;
#pragma unroll
    for (int u = 0; u < 4; u++) { int i = base + u; c[u] = (i < N_NODES) ? cnt[i] : 0; s += c[u]; }
    ls[tid] = s; __syncthreads();
    for (int off = 1; off < 256; off <<= 1) {
        int v = (tid >= off) ? ls[tid - off] : 0;
        __syncthreads();
        ls[tid] += v;
        __syncthreads();
    }
    int excl = ls[tid] - s;
#pragma unroll
    for (int u = 0; u < 4; u++) { int i = base + u; if (i < N_NODES) rowp[i] = excl; excl += c[u]; }
    if (tid == 255) part[b] = ls[255];
}

__global__ void k_scan2(int* part, int* rowp) {
    int s = 0;
    for (int b = 0; b < NSCAN; b++) { int v = part[b]; part[b] = s; s += v; }
    rowp[N_NODES] = s;   // == N_E2
}

__global__ void k_scan3(int* __restrict__ rowp, const int* __restrict__ part) {
    int b = blockIdx.x, tid = threadIdx.x;
    int add = part[b];
    int base = b * 1024 + tid * 4;
#pragma unroll
    for (int u = 0; u < 4; u++) { int i = base + u; if (i < N_NODES) rowp[i] += add; }
}

__global__ void k_fill(const int* __restrict__ src, const int* __restrict__ dst,
                       const int* __restrict__ rowp, int* __restrict__ cursor,
                       int* __restrict__ csr_src, int* __restrict__ csr_dst,
                       int* __restrict__ csr_aid) {
    int t = blockIdx.x * 256 + threadIdx.x;
    if (t < N_EDGES) {
        int d = dst[t];
        int pos = atomicAdd(&cursor[d], 1);
        int w = rowp[d] + pos;
        csr_src[w] = src[t];
        csr_dst[w] = d;
        csr_aid[w] = t;
    } else if (t < N_E2) {
        int n = t - N_EDGES;
        int pos = atomicAdd(&cursor[n], 1);
        int w = rowp[n] + pos;
        csr_src[w] = n;
        csr_dst[w] = n;
        csr_aid[w] = N_EDGES + n;   // self loop, attr = loop_attr[n]
    }
}

// loop_attr[n][j] = mean over incoming (original) edges of edge_attr
__global__ void k_loopattr(const int* __restrict__ rowp, const int* __restrict__ csr_aid,
                           const float* __restrict__ edge_attr, float* __restrict__ lattr) {
    int t = blockIdx.x * 256 + threadIdx.x;
    if (t >= N_NODES * 16) return;
    int n = t >> 4, j = t & 15;
    int st = rowp[n], en = rowp[n + 1];
    float s = 0.f;
    for (int i = st; i < en; i++) {
        int aid = csr_aid[i];
        if (aid < N_EDGES) s += edge_attr[(size_t)aid * 16 + j];
    }
    float deg = (float)(en - st - 1);
    lattr[(size_t)n * 16 + j] = s / fmaxf(deg, 1.0f);
}

// ea_csr[e][0:16] = edge_attr[csr_aid[e]] (or loop_attr), CSR order — built once.
__global__ void k_eacsr(const int* __restrict__ csr_aid,
                        const float* __restrict__ edge_attr,
                        const float* __restrict__ lattr,
                        float* __restrict__ ea_csr) {
    int t = blockIdx.x * 256 + threadIdx.x;
    if (t >= N_E2 * 4) return;
    int e = t >> 2, q = t & 3;
    int aid = csr_aid[e];
    const float* ap = (aid < N_EDGES) ? edge_attr + (size_t)aid * 16
                                      : lattr + (size_t)(aid - N_EDGES) * 16;
    ((float4*)ea_csr)[t] = ((const float4*)ap)[q];
}

// W[m][k][n] fp32 -> Wt[m][n][k] bf16 (32x32 LDS tile transpose)
__global__ void k_tw(const float* __restrict__ W, u16* __restrict__ Wt) {
    __shared__ float tile[32][33];
    int m = blockIdx.z;
    int bi = blockIdx.x * 32, bj = blockIdx.y * 32;   // bi: k base, bj: n base
    int tx = threadIdx.x & 31, ty = threadIdx.x >> 5; // 32 x 8
#pragma unroll
    for (int q = 0; q < 4; q++) {
        int k = bi + ty + q * 8;
        tile[ty + q * 8][tx] = W[(size_t)m * 65536 + (size_t)k * 256 + bj + tx];
    }
    __syncthreads();
#pragma unroll
    for (int q = 0; q < 4; q++) {
        int n = bj + ty + q * 8;
        Wt[(size_t)m * 65536 + (size_t)n * 256 + bi + tx] = f2b(tile[tx][ty + q * 8]);
    }
}

// ---------------------------------------------------------------- GEMM fp32 (encoder + classifier)
#define BM 128
#define BN 64
#define BK 16

template <int EPI>
__global__ __launch_bounds__(256) void k_gemm(
    const float* __restrict__ A, const float* __restrict__ B,
    const float* __restrict__ bias,
    const float* __restrict__ bng, const float* __restrict__ bnb,
    const float* __restrict__ bnm, const float* __restrict__ bnv,
    float* __restrict__ C, u16* __restrict__ Cbf,
    int M, int K, int lda, int ldb, int ldc, int coff)
{
    __shared__ float As[BK][BM + 4];
    __shared__ float Bs[BK][BN + 4];
    int tid = threadIdx.x;
    int tr = tid >> 4, tc = tid & 15;        // 16x16 threads, 8x4 tile each
    int m0 = blockIdx.x * BM, n0 = blockIdx.y * BN;

    float acc[8][4];
#pragma unroll
    for (int i = 0; i < 8; i++)
#pragma unroll
        for (int j = 0; j < 4; j++) acc[i][j] = 0.f;

    int ktiles = K / BK;
    for (int kt = 0; kt < ktiles; kt++) {
#pragma unroll
        for (int q = 0; q < 2; q++) {
            int f = q * 256 + tid;
            int row = f >> 2, kq = (f & 3) * 4;
            float4 v = make_float4(0.f, 0.f, 0.f, 0.f);
            if (m0 + row < M)
                v = *(const float4*)(A + (size_t)(m0 + row) * lda + kt * BK + kq);
            As[kq + 0][row] = v.x; As[kq + 1][row] = v.y;
            As[kq + 2][row] = v.z; As[kq + 3][row] = v.w;
        }
        {
            int k = tid >> 4, nq = (tid & 15) * 4;
            float4 v = *(const float4*)(B + (size_t)(kt * BK + k) * ldb + n0 + nq);
            *(float4*)&Bs[k][nq] = v;
        }
        __syncthreads();
#pragma unroll
        for (int kk = 0; kk < BK; kk++) {
            float4 a0 = *(const float4*)&As[kk][tr * 8];
            float4 a1 = *(const float4*)&As[kk][tr * 8 + 4];
            float4 b0 = *(const float4*)&Bs[kk][tc * 4];
            float a[8] = {a0.x, a0.y, a0.z, a0.w, a1.x, a1.y, a1.z, a1.w};
            float bb[4] = {b0.x, b0.y, b0.z, b0.w};
#pragma unroll
            for (int i = 0; i < 8; i++)
#pragma unroll
                for (int j = 0; j < 4; j++) acc[i][j] += a[i] * bb[j];
        }
        __syncthreads();
    }

#pragma unroll
    for (int i = 0; i < 8; i++) {
        int m = m0 + tr * 8 + i;
        if (m >= M) continue;
        float4 o;
        ushort4 ob;
#pragma unroll
        for (int j = 0; j < 4; j++) {
            int c = n0 + tc * 4 + j;
            float v = acc[i][j] + bias[c];
            if (EPI == 2)
                v = (v - bnm[c]) * rsqrtf(bnv[c] + EPS) * bng[c] + bnb[c];
            if (EPI >= 1) v = fmaxf(v, 0.f);
            ((float*)&o)[j] = v;
            ((u16*)&ob)[j] = f2b(v);
        }
        *(float4*)(C + (size_t)m * ldc + coff + n0 + tc * 4) = o;
        if (Cbf) *(ushort4*)(Cbf + (size_t)m * ldc + coff + n0 + tc * 4) = ob;
    }
}

static void gemm(int epi, const float* A, const float* B, const float* bias,
                 const float* g, const float* b2, const float* m, const float* v,
                 float* C, u16* Cbf, int M, int K, int Nc, int lda, int ldb, int ldc, int coff,
                 hipStream_t st) {
    dim3 grid((M + BM - 1) / BM, Nc / BN);
    if (epi == 0)      k_gemm<0><<<grid, 256, 0, st>>>(A, B, bias, g, b2, m, v, C, Cbf, M, K, lda, ldb, ldc, coff);
    else if (epi == 1) k_gemm<1><<<grid, 256, 0, st>>>(A, B, bias, g, b2, m, v, C, Cbf, M, K, lda, ldb, ldc, coff);
    else               k_gemm<2><<<grid, 256, 0, st>>>(A, B, bias, g, b2, m, v, C, Cbf, M, K, lda, ldb, ldc, coff);
}

// ---------------------------------------------------------------- GEMM bf16 MFMA (layer Wl/Wr)
// C[M,256] = A[M,256] @ Wt^T + bias  (Wt is n-major: Wt[n][k]); C stored bf16 at ldc=512+coff.
// tile 128x64, 4 waves (wave w: rows w*32..+32), K-step 32, mfma 16x16x32_bf16.
__global__ __launch_bounds__(256) void k_gemm_bf(
    const u16* __restrict__ A,     // [M,256] bf16
    const u16* __restrict__ Bt,    // [256,256] bf16, n-major
    const float* __restrict__ bias,
    u16* __restrict__ C,           // [M,512] bf16
    int M, int coff)
{
    __shared__ __align__(16) u16 As[128 * 40];   // [128][32+8]
    __shared__ __align__(16) u16 Bs[64 * 40];    // [64][32+8]
    int tid = threadIdx.x;
    int lane = tid & 63, w = tid >> 6;
    int m0 = blockIdx.x * 128, n0 = blockIdx.y * 64;

    f32x4 acc[2][4];
#pragma unroll
    for (int i = 0; i < 2; i++)
#pragma unroll
        for (int j = 0; j < 4; j++) acc[i][j] = (f32x4){0.f, 0.f, 0.f, 0.f};

    int srow = tid >> 2, skc = (tid & 3) * 8;    // staging: row, k-chunk
    int lr = lane & 15, lk = (lane >> 4) * 8;

    for (int kt = 0; kt < 8; kt++) {
        if (kt) __syncthreads();
        // stage A: 128 rows x 4 chunks = 512 chunks, 2 per thread  (R4 BUG FIX)
#pragma unroll
        for (int q = 0; q < 2; q++) {
            int arow = q * 64 + srow;
            uint4 av = make_uint4(0, 0, 0, 0);
            if (m0 + arow < M)
                av = *(const uint4*)(A + (size_t)(m0 + arow) * 256 + kt * 32 + skc);
            *(uint4*)&As[arow * 40 + skc] = av;
        }
        // stage B: 64 rows x 4 chunks = 256 chunks, 1 per thread
        {
            uint4 bv = *(const uint4*)(Bt + (size_t)(n0 + srow) * 256 + kt * 32 + skc);
            *(uint4*)&Bs[srow * 40 + skc] = bv;
        }
        __syncthreads();

        short8 af0 = *(const short8*)&As[(w * 32 + lr) * 40 + lk];
        short8 af1 = *(const short8*)&As[(w * 32 + 16 + lr) * 40 + lk];
        short8 bf[4];
#pragma unroll
        for (int nt = 0; nt < 4; nt++)
            bf[nt] = *(const short8*)&Bs[(nt * 16 + lr) * 40 + lk];
#pragma unroll
        for (int nt = 0; nt < 4; nt++) {
            acc[0][nt] = __builtin_amdgcn_mfma_f32_16x16x32_bf16(af0, bf[nt], acc[0][nt], 0, 0, 0);
            acc[1][nt] = __builtin_amdgcn_mfma_f32_16x16x32_bf16(af1, bf[nt], acc[1][nt], 0, 0, 0);
        }
    }

    // C/D layout: col = lane&15, row = (lane>>4)*4 + j
    int rq = (lane >> 4) * 4;
#pragma unroll
    for (int nt = 0; nt < 4; nt++) {
        int col = n0 + nt * 16 + lr;
        float bv = bias[col];
#pragma unroll
        for (int mt = 0; mt < 2; mt++) {
#pragma unroll
            for (int j = 0; j < 4; j++) {
                int row = m0 + w * 32 + mt * 16 + rq + j;
                if (row < M)
                    C[(size_t)row * 512 + coff + col] = f2b(acc[mt][nt][j] + bv);
            }
        }
    }
}

// ---------------------------------------------------------------- GATv2 pass 1: alpha per edge
#define EPW 8
__global__ __launch_bounds__(256) void k_alpha(
    const u16* __restrict__ xlr,         // [N,512] bf16 xl|xr
    const float* __restrict__ ea_csr,    // [E2,16] CSR order
    const int* __restrict__ csr_src, const int* __restrict__ csr_dst,
    const float* __restrict__ We,        // [16,256]
    const float* __restrict__ att,       // [4,64] flat = [256]
    float* __restrict__ alpha)           // [E2,4], CSR order
{
    __shared__ float eas[4][EPW * 16];   // per-wave staging of 8 edges x 16 attrs
    int lane = threadIdx.x & 63;
    int wv = threadIdx.x >> 6;
    int wid = blockIdx.x * 4 + wv;
    int e0 = wid * EPW;                  // grid sized exactly: e0 < N_E2 always
    int g = lane >> 4, t = lane & 15;
    int c0 = g * 64 + t * 4;

    float2 ev = *(const float2*)(ea_csr + (size_t)e0 * 16 + lane * 2);
    *(float2*)&eas[wv][lane * 2] = ev;

    float werr[16][4];
#pragma unroll
    for (int j = 0; j < 16; j++) {
        float4 v = *(const float4*)(We + j * HID + c0);
        werr[j][0] = v.x; werr[j][1] = v.y; werr[j][2] = v.z; werr[j][3] = v.w;
    }
    float4 atv = *(const float4*)(att + c0);
    float attv[4] = {atv.x, atv.y, atv.z, atv.w};

    int sarr[EPW], darr[EPW];
#pragma unroll
    for (int u = 0; u < EPW; u++) {
        sarr[u] = __builtin_amdgcn_readfirstlane(csr_src[e0 + u]);
        darr[u] = __builtin_amdgcn_readfirstlane(csr_dst[e0 + u]);
    }
    // all 16 row-gathers (8B each) in flight before any compute
    ushort4 xlv[EPW], xrv[EPW];
#pragma unroll
    for (int u = 0; u < EPW; u++) {
        xlv[u] = *(const ushort4*)(xlr + (size_t)sarr[u] * 512 + c0);
        xrv[u] = *(const ushort4*)(xlr + (size_t)darr[u] * 512 + 256 + c0);
    }

#pragma unroll
    for (int u = 0; u < EPW; u++) {
        const float* ea = &eas[wv][u * 16];
        float p = 0.f;
#pragma unroll
        for (int ch = 0; ch < 4; ch++) {
            float tt = b2f(((const u16*)&xlv[u])[ch]) + b2f(((const u16*)&xrv[u])[ch]);
#pragma unroll
            for (int j = 0; j < 16; j++) tt += ea[j] * werr[j][ch];
            tt = (tt >= 0.f) ? tt : 0.2f * tt;   // leaky_relu 0.2
            p += tt * attv[ch];
        }
        p += __shfl_xor(p, 1, 64);
        p += __shfl_xor(p, 2, 64);
        p += __shfl_xor(p, 4, 64);
        p += __shfl_xor(p, 8, 64);
        if (t == 0) alpha[(size_t)(e0 + u) * 4 + g] = p;
    }
}

// ---------------------------------------------------------------- GATv2 pass 2: softmax + aggregate
__global__ __launch_bounds__(256) void k_aggr(
    const u16* __restrict__ xlr, const float* __restrict__ alpha,
    const int* __restrict__ rowp, const int* __restrict__ csr_src,
    const float* __restrict__ cbias,
    const float* __restrict__ bng, const float* __restrict__ bnb,
    const float* __restrict__ bnm, const float* __restrict__ bnv,
    float* __restrict__ h, u16* __restrict__ h_bf)   // [N,256] in/out + bf16 copy
{
    __shared__ float lex[4][64][4];      // [wave][edge-in-chunk][head]
    __shared__ int   lsrc[4][64];
    int lane = threadIdx.x & 63;
    int wv = threadIdx.x >> 6;
    int n = blockIdx.x * 4 + wv;
    if (n >= N_NODES) return;
    int st = rowp[n], en = rowp[n + 1];
    int hsel = lane >> 4;                // head owning channels c0..c0+3
    int c0 = lane * 4;

    float m4[4]  = {-3.0e38f, -3.0e38f, -3.0e38f, -3.0e38f};
    float den4[4] = {0.f, 0.f, 0.f, 0.f};
    float acc[4]  = {0.f, 0.f, 0.f, 0.f};

    for (int cs = st; cs < en; cs += 64) {
        int cnt = min(64, en - cs);
        float a4[4];
        int s_i = 0;
        if (lane < cnt) {
            float4 v = *(const float4*)(alpha + (size_t)(cs + lane) * 4);
            a4[0] = v.x; a4[1] = v.y; a4[2] = v.z; a4[3] = v.w;
            s_i = csr_src[cs + lane];
        } else {
            a4[0] = a4[1] = a4[2] = a4[3] = -3.0e38f;
        }
        float cm[4] = {a4[0], a4[1], a4[2], a4[3]};
#pragma unroll
        for (int o = 32; o >= 1; o >>= 1)
#pragma unroll
            for (int u = 0; u < 4; u++) cm[u] = fmaxf(cm[u], __shfl_xor(cm[u], o, 64));
        float sc[4];
#pragma unroll
        for (int u = 0; u < 4; u++) {
            float nm = fmaxf(m4[u], cm[u]);
            sc[u] = __expf(m4[u] - nm);
            den4[u] *= sc[u];
            m4[u] = nm;
        }
        float scl = sc[hsel];
#pragma unroll
        for (int u = 0; u < 4; u++) acc[u] *= scl;
        float ex[4];
#pragma unroll
        for (int u = 0; u < 4; u++) ex[u] = (lane < cnt) ? __expf(a4[u] - m4[u]) : 0.f;
        float sx[4] = {ex[0], ex[1], ex[2], ex[3]};
#pragma unroll
        for (int o = 32; o >= 1; o >>= 1)
#pragma unroll
            for (int u = 0; u < 4; u++) sx[u] += __shfl_xor(sx[u], o, 64);
#pragma unroll
        for (int u = 0; u < 4; u++) den4[u] += sx[u];
        *(float4*)&lex[wv][lane][0] = make_float4(ex[0], ex[1], ex[2], ex[3]);
        lsrc[wv][lane] = s_i;
        // weighted gather-sum: 8 row-gathers (8B bf16x4) in flight per step
        int j = 0;
        for (; j + 8 <= cnt; j += 8) {
            float a[8]; int sj[8];
#pragma unroll
            for (int q = 0; q < 8; q++) { a[q] = lex[wv][j + q][hsel]; sj[q] = lsrc[wv][j + q]; }
            ushort4 xg[8];
#pragma unroll
            for (int q = 0; q < 8; q++) xg[q] = *(const ushort4*)(xlr + (size_t)sj[q] * 512 + c0);
#pragma unroll
            for (int q = 0; q < 8; q++) {
                acc[0] += a[q] * b2f(((const u16*)&xg[q])[0]);
                acc[1] += a[q] * b2f(((const u16*)&xg[q])[1]);
                acc[2] += a[q] * b2f(((const u16*)&xg[q])[2]);
                acc[3] += a[q] * b2f(((const u16*)&xg[q])[3]);
            }
        }
        for (; j < cnt; j++) {
            float a = lex[wv][j][hsel];
            int sj = lsrc[wv][j];
            ushort4 xg = *(const ushort4*)(xlr + (size_t)sj * 512 + c0);
            acc[0] += a * b2f(((const u16*)&xg)[0]);
            acc[1] += a * b2f(((const u16*)&xg)[1]);
            acc[2] += a * b2f(((const u16*)&xg)[2]);
            acc[3] += a * b2f(((const u16*)&xg)[3]);
        }
    }

    float dd = den4[hsel];
    float4 hin = *(const float4*)(h + (size_t)n * 256 + c0);
    float4 cb  = *(const float4*)(cbias + c0);
    float4 gg  = *(const float4*)(bng + c0);
    float4 bb  = *(const float4*)(bnb + c0);
    float4 mm  = *(const float4*)(bnm + c0);
    float4 vv  = *(const float4*)(bnv + c0);
    float hi[4] = {hin.x, hin.y, hin.z, hin.w};
    float cbv[4] = {cb.x, cb.y, cb.z, cb.w};
    float gv[4] = {gg.x, gg.y, gg.z, gg.w};
    float bv[4] = {bb.x, bb.y, bb.z, bb.w};
    float mv[4] = {mm.x, mm.y, mm.z, mm.w};
    float vvv[4] = {vv.x, vv.y, vv.z, vv.w};
    float4 o;
    ushort4 ob;
#pragma unroll
    for (int u = 0; u < 4; u++) {
        float val = acc[u] / dd + cbv[u];
        val = (val - mv[u]) * rsqrtf(vvv[u] + EPS) * gv[u] + bv[u];
        val = fmaxf(val, 0.f) + hi[u];
        ((float*)&o)[u] = val;
        ((u16*)&ob)[u] = f2b(val);
    }
    *(float4*)(h + (size_t)n * 256 + c0) = o;
    *(ushort4*)(h_bf + (size_t)n * 256 + c0) = ob;
}

// ---------------------------------------------------------------- pooling + classifier tail
__global__ void k_pool(const float* __restrict__ h, float* __restrict__ xp) {
    int g = blockIdx.x, c = threadIdx.x;
    int st = (g * N_NODES + N_GRAPHS - 1) / N_GRAPHS;
    int en = ((g + 1) * N_NODES + N_GRAPHS - 1) / N_GRAPHS;
    float s = 0.f, mx = -3.0e38f;
    for (int i = st; i < en; i++) {
        float v = h[(size_t)i * 256 + c];
        s += v;
        mx = fmaxf(mx, v);
    }
    xp[g * 512 + c] = s / (float)(en - st);
    xp[g * 512 + 256 + c] = mx;
}

__global__ void k_final(const float* __restrict__ z2, const float* __restrict__ W3,
                        const float* __restrict__ b3, float* __restrict__ out) {
    int m = threadIdx.x;
    float s = b3[0];
    for (int k = 0; k < 128; k++) s += z2[m * 128 + k] * W3[k];
    out[m] = s;
}

// ---------------------------------------------------------------- launch
extern "C" void kernel_launch(void* const* d_in, const int* in_sizes, int n_in,
                              void* d_out, int out_size, void* d_ws, size_t ws_size,
                              hipStream_t stream) {
    const float* x         = (const float*)d_in[0];
    const int*   ei        = (const int*)d_in[1];
    const int*   src       = ei;
    const int*   dst       = ei + N_EDGES;
    const float* edge_attr = (const float*)d_in[3];
    const float* enc_W     = (const float*)d_in[4];
    const float* enc_b     = (const float*)d_in[5];
    const float* conv_Wl   = (const float*)d_in[6];
    const float* conv_bl   = (const float*)d_in[7];
    const float* conv_Wr   = (const float*)d_in[8];
    const float* conv_br   = (const float*)d_in[9];
    const float* conv_We   = (const float*)d_in[10];
    const float* conv_att  = (const float*)d_in[11];
    const float* conv_bias = (const float*)d_in[12];
    const float* bn_g      = (const float*)d_in[13];
    const float* bn_b      = (const float*)d_in[14];
    const float* bn_m      = (const float*)d_in[15];
    const float* bn_v      = (const float*)d_in[16];
    const float* cls_W1    = (const float*)d_in[17];
    const float* cls_b1    = (const float*)d_in[18];
    const float* cls_g1    = (const float*)d_in[19];
    const float* cls_bt1   = (const float*)d_in[20];
    const float* cls_m1    = (const float*)d_in[21];
    const float* cls_v1    = (const float*)d_in[22];
    const float* cls_W2    = (const float*)d_in[23];
    const float* cls_b2    = (const float*)d_in[24];
    const float* cls_g2    = (const float*)d_in[25];
    const float* cls_bt2   = (const float*)d_in[26];
    const float* cls_m2    = (const float*)d_in[27];
    const float* cls_v2    = (const float*)d_in[28];
    const float* cls_W3    = (const float*)d_in[29];
    const float* cls_b3    = (const float*)d_in[30];
    float* out = (float*)d_out;

    char* ws = (char*)d_ws;
    size_t off = 0;
    auto alloc = [&](size_t bytes) -> void* {
        void* p = ws + off;
        off += (bytes + 255) & ~(size_t)255;
        return p;
    };
    float* h       = (float*)alloc((size_t)N_NODES * 256 * 4);   // 20.5 MB
    u16*   h_bf    = (u16*)alloc((size_t)N_NODES * 256 * 2);     // 10.2 MB
    u16*   xlr_bf  = (u16*)alloc((size_t)N_NODES * 512 * 2);     // 20.5 MB
    float* lattr   = (float*)alloc((size_t)N_NODES * 16 * 4);    // 1.3 MB
    float* ea_csr  = (float*)alloc((size_t)N_E2 * 16 * 4);       // 21.8 MB
    float* alphas  = (float*)alloc((size_t)N_E2 * 4 * 4);        // 5.4 MB
    u16*   Wtl     = (u16*)alloc((size_t)3 * 65536 * 2);         // 0.4 MB
    u16*   Wtr     = (u16*)alloc((size_t)3 * 65536 * 2);         // 0.4 MB
    float* xp      = (float*)alloc((size_t)N_GRAPHS * 512 * 4);
    float* z1      = (float*)alloc((size_t)N_GRAPHS * 256 * 4);
    float* z2      = (float*)alloc((size_t)N_GRAPHS * 128 * 4);
    int*   cnt     = (int*)alloc((size_t)N_NODES * 4);
    int*   rowp    = (int*)alloc((size_t)(N_NODES + 1) * 4);
    int*   cursor  = (int*)alloc((size_t)N_NODES * 4);
    int*   csr_src = (int*)alloc((size_t)N_E2 * 4);
    int*   csr_dst = (int*)alloc((size_t)N_E2 * 4);
    int*   csr_aid = (int*)alloc((size_t)N_E2 * 4);
    int*   part    = (int*)alloc(64 * 4);

    // CSR build
    k_init<<<(N_NODES + 255) / 256, 256, 0, stream>>>(cnt, cursor);
    k_count<<<(N_EDGES + 255) / 256, 256, 0, stream>>>(dst, cnt);
    k_scan1<<<NSCAN, 256, 0, stream>>>(cnt, rowp, part);
    k_scan2<<<1, 1, 0, stream>>>(part, rowp);
    k_scan3<<<NSCAN, 256, 0, stream>>>(rowp, part);
    k_fill<<<(N_E2 + 255) / 256, 256, 0, stream>>>(src, dst, rowp, cursor, csr_src, csr_dst, csr_aid);
    k_loopattr<<<(N_NODES * 16 + 255) / 256, 256, 0, stream>>>(rowp, csr_aid, edge_attr, lattr);
    k_eacsr<<<(N_E2 * 4 + 255) / 256, 256, 0, stream>>>(csr_aid, edge_attr, lattr, ea_csr);

    // weight transposes to bf16 n-major
    k_tw<<<dim3(8, 8, 3), 256, 0, stream>>>(conv_Wl, Wtl);
    k_tw<<<dim3(8, 8, 3), 256, 0, stream>>>(conv_Wr, Wtr);

    // encoder: h = relu(x @ enc_W + enc_b), also emit h_bf
    gemm(1, x, enc_W, enc_b, nullptr, nullptr, nullptr, nullptr,
         h, h_bf, N_NODES, 64, 256, 64, 256, 256, 0, stream);

    // 3 GATv2 layers
    int nwaves = (N_E2 + EPW - 1) / EPW;   // 42500
    int ablocks = (nwaves + 3) / 4;        // 10625
    dim3 ggrid((N_NODES + 127) / 128, 4);
    for (int i = 0; i < 3; i++) {
        k_gemm_bf<<<ggrid, 256, 0, stream>>>(h_bf, Wtl + (size_t)i * 65536,
                                             conv_bl + i * HID, xlr_bf, N_NODES, 0);
        k_gemm_bf<<<ggrid, 256, 0, stream>>>(h_bf, Wtr + (size_t)i * 65536,
                                             conv_br + i * HID, xlr_bf, N_NODES, 256);
        k_alpha<<<ablocks, 256, 0, stream>>>(
            xlr_bf, ea_csr, csr_src, csr_dst,
            conv_We + (size_t)i * 16 * HID, conv_att + (size_t)i * 256, alphas);
        k_aggr<<<N_NODES / 4, 256, 0, stream>>>(
            xlr_bf, alphas, rowp, csr_src,
            conv_bias + (size_t)i * HID,
            bn_g + (size_t)i * HID, bn_b + (size_t)i * HID,
            bn_m + (size_t)i * HID, bn_v + (size_t)i * HID, h, h_bf);
    }

    // pooling + classifier
    k_pool<<<N_GRAPHS, 256, 0, stream>>>(h, xp);
    gemm(2, xp, cls_W1, cls_b1, cls_g1, cls_bt1, cls_m1, cls_v1,
         z1, nullptr, N_GRAPHS, 512, 256, 512, 256, 256, 0, stream);
    gemm(2, z1, cls_W2, cls_b2, cls_g2, cls_bt2, cls_m2, cls_v2,
         z2, nullptr, N_GRAPHS, 256, 128, 256, 128, 128, 0, stream);
    k_final<<<1, 256, 0, stream>>>(z2, cls_W3, cls_b3, out);
}

// Round 6
// 553.555 us; speedup vs baseline: 2.2763x; 1.1966x over previous
//
#include <hip/hip_runtime.h>
#include <hip/hip_bf16.h>

#define N_NODES 20000
#define N_EDGES 320000
#define N_E2    (N_EDGES + N_NODES)   // 340000 edges incl self loops
#define N_GRAPHS 256
#define HID 256
#define EPS 1e-5f
#define NSCAN 20                       // ceil(20000/1024)

typedef unsigned short u16;
typedef __attribute__((ext_vector_type(8))) short short8;
typedef __attribute__((ext_vector_type(4))) float f32x4;

__device__ __forceinline__ float b2f(u16 u) {
    union { unsigned int i; float f; } v; v.i = ((unsigned int)u) << 16; return v.f;
}
__device__ __forceinline__ u16 f2b(float f) {
    __hip_bfloat16 h = __float2bfloat16(f);   // RNE
    return *reinterpret_cast<u16*>(&h);
}

// ---------------------------------------------------------------- CSR build
__global__ void k_init(int* cnt, int* cursor) {
    int i = blockIdx.x * 256 + threadIdx.x;
    if (i < N_NODES) { cnt[i] = 1; cursor[i] = 0; }  // count starts at 1: self loop
}

__global__ void k_count(const int* __restrict__ dst, int* __restrict__ cnt) {
    int e = blockIdx.x * 256 + threadIdx.x;
    if (e < N_EDGES) atomicAdd(&cnt[dst[e]], 1);
}

__global__ void k_scan1(const int* __restrict__ cnt, int* __restrict__ rowp, int* __restrict__ part) {
    __shared__ int ls[256];
    int b = blockIdx.x, tid = threadIdx.x;
    int base = b * 1024 + tid * 4;
    int c[4]; int s = 0;
#pragma unroll
    for (int u = 0; u < 4; u++) { int i = base + u; c[u] = (i < N_NODES) ? cnt[i] : 0; s += c[u]; }
    ls[tid] = s; __syncthreads();
    for (int off = 1; off < 256; off <<= 1) {
        int v = (tid >= off) ? ls[tid - off] : 0;
        __syncthreads();
        ls[tid] += v;
        __syncthreads();
    }
    int excl = ls[tid] - s;
#pragma unroll
    for (int u = 0; u < 4; u++) { int i = base + u; if (i < N_NODES) rowp[i] = excl; excl += c[u]; }
    if (tid == 255) part[b] = ls[255];
}

__global__ void k_scan2(int* part, int* rowp) {
    int s = 0;
    for (int b = 0; b < NSCAN; b++) { int v = part[b]; part[b] = s; s += v; }
    rowp[N_NODES] = s;   // == N_E2
}

__global__ void k_scan3(int* __restrict__ rowp, const int* __restrict__ part) {
    int b = blockIdx.x, tid = threadIdx.x;
    int add = part[b];
    int base = b * 1024 + tid * 4;
#pragma unroll
    for (int u = 0; u < 4; u++) { int i = base + u; if (i < N_NODES) rowp[i] += add; }
}

__global__ void k_fill(const int* __restrict__ src, const int* __restrict__ dst,
                       const int* __restrict__ rowp, int* __restrict__ cursor,
                       int* __restrict__ csr_src, int* __restrict__ csr_dst,
                       int* __restrict__ csr_aid) {
    int t = blockIdx.x * 256 + threadIdx.x;
    if (t < N_EDGES) {
        int d = dst[t];
        int pos = atomicAdd(&cursor[d], 1);
        int w = rowp[d] + pos;
        csr_src[w] = src[t];
        csr_dst[w] = d;
        csr_aid[w] = t;
    } else if (t < N_E2) {
        int n = t - N_EDGES;
        int pos = atomicAdd(&cursor[n], 1);
        int w = rowp[n] + pos;
        csr_src[w] = n;
        csr_dst[w] = n;
        csr_aid[w] = N_EDGES + n;   // self loop, attr = loop_attr[n]
    }
}

// zero the +64 padding of csr_src/csr_dst (tail-block int4 reads)
__global__ void k_pad(int* csr_src, int* csr_dst) {
    int i = threadIdx.x;   // 64 threads
    csr_src[N_E2 + i] = 0;
    csr_dst[N_E2 + i] = 0;
}

// loop_attr[n][j] = mean over incoming (original) edges of edge_attr
__global__ void k_loopattr(const int* __restrict__ rowp, const int* __restrict__ csr_aid,
                           const float* __restrict__ edge_attr, float* __restrict__ lattr) {
    int t = blockIdx.x * 256 + threadIdx.x;
    if (t >= N_NODES * 16) return;
    int n = t >> 4, j = t & 15;
    int st = rowp[n], en = rowp[n + 1];
    float s = 0.f;
    for (int i = st; i < en; i++) {
        int aid = csr_aid[i];
        if (aid < N_EDGES) s += edge_attr[(size_t)aid * 16 + j];
    }
    float deg = (float)(en - st - 1);
    lattr[(size_t)n * 16 + j] = s / fmaxf(deg, 1.0f);
}

// ea_bf[e][0:16] = bf16(edge_attr[csr_aid[e]]) (or loop_attr), CSR order — built once.
__global__ void k_eacsr(const int* __restrict__ csr_aid,
                        const float* __restrict__ edge_attr,
                        const float* __restrict__ lattr,
                        u16* __restrict__ ea_bf) {
    int t = blockIdx.x * 256 + threadIdx.x;   // one thread per 8 attrs
    if (t >= N_E2 * 2) return;
    int e = t >> 1, hf = t & 1;
    int aid = csr_aid[e];
    const float* ap = (aid < N_EDGES) ? edge_attr + (size_t)aid * 16
                                      : lattr + (size_t)(aid - N_EDGES) * 16;
    float4 a = ((const float4*)ap)[hf * 2];
    float4 b = ((const float4*)ap)[hf * 2 + 1];
    u16 v[8] = {f2b(a.x), f2b(a.y), f2b(a.z), f2b(a.w),
                f2b(b.x), f2b(b.y), f2b(b.z), f2b(b.w)};
    *(uint4*)(ea_bf + (size_t)t * 8) = *(uint4*)v;
}

// We[layer][16][256] fp32 -> B-fragment layout Wef[layer][nt][lane][8] bf16 (K padded to 32)
__global__ void k_wef(const float* __restrict__ We, u16* __restrict__ Wef) {
    int t = blockIdx.x * 256 + threadIdx.x;   // 3*16*64 = 3072
    if (t >= 3 * 16 * 64) return;
    int layer = t >> 10, r = t & 1023;
    int nt = r >> 6, l = r & 63;
    int kc = l >> 4, ch = nt * 16 + (l & 15);
    u16 v[8];
#pragma unroll
    for (int q = 0; q < 8; q++) {
        float x = 0.f;
        if (kc < 2) x = We[(size_t)layer * 4096 + (size_t)(kc * 8 + q) * 256 + ch];
        v[q] = f2b(x);
    }
    *(uint4*)(Wef + (size_t)t * 8) = *(uint4*)v;
}

// W[m][k][n] fp32 -> Wt[m][n][k] bf16 (32x32 LDS tile transpose)
__global__ void k_tw(const float* __restrict__ W, u16* __restrict__ Wt) {
    __shared__ float tile[32][33];
    int m = blockIdx.z;
    int bi = blockIdx.x * 32, bj = blockIdx.y * 32;   // bi: k base, bj: n base
    int tx = threadIdx.x & 31, ty = threadIdx.x >> 5; // 32 x 8
#pragma unroll
    for (int q = 0; q < 4; q++) {
        int k = bi + ty + q * 8;
        tile[ty + q * 8][tx] = W[(size_t)m * 65536 + (size_t)k * 256 + bj + tx];
    }
    __syncthreads();
#pragma unroll
    for (int q = 0; q < 4; q++) {
        int n = bj + ty + q * 8;
        Wt[(size_t)m * 65536 + (size_t)n * 256 + bi + tx] = f2b(tile[tx][ty + q * 8]);
    }
}

// ---------------------------------------------------------------- GEMM fp32 (encoder + classifier)
#define BM 128
#define BN 64
#define BK 16

template <int EPI>
__global__ __launch_bounds__(256) void k_gemm(
    const float* __restrict__ A, const float* __restrict__ B,
    const float* __restrict__ bias,
    const float* __restrict__ bng, const float* __restrict__ bnb,
    const float* __restrict__ bnm, const float* __restrict__ bnv,
    float* __restrict__ C, u16* __restrict__ Cbf,
    int M, int K, int lda, int ldb, int ldc, int coff)
{
    __shared__ float As[BK][BM + 4];
    __shared__ float Bs[BK][BN + 4];
    int tid = threadIdx.x;
    int tr = tid >> 4, tc = tid & 15;        // 16x16 threads, 8x4 tile each
    int m0 = blockIdx.x * BM, n0 = blockIdx.y * BN;

    float acc[8][4];
#pragma unroll
    for (int i = 0; i < 8; i++)
#pragma unroll
        for (int j = 0; j < 4; j++) acc[i][j] = 0.f;

    int ktiles = K / BK;
    for (int kt = 0; kt < ktiles; kt++) {
#pragma unroll
        for (int q = 0; q < 2; q++) {
            int f = q * 256 + tid;
            int row = f >> 2, kq = (f & 3) * 4;
            float4 v = make_float4(0.f, 0.f, 0.f, 0.f);
            if (m0 + row < M)
                v = *(const float4*)(A + (size_t)(m0 + row) * lda + kt * BK + kq);
            As[kq + 0][row] = v.x; As[kq + 1][row] = v.y;
            As[kq + 2][row] = v.z; As[kq + 3][row] = v.w;
        }
        {
            int k = tid >> 4, nq = (tid & 15) * 4;
            float4 v = *(const float4*)(B + (size_t)(kt * BK + k) * ldb + n0 + nq);
            *(float4*)&Bs[k][nq] = v;
        }
        __syncthreads();
#pragma unroll
        for (int kk = 0; kk < BK; kk++) {
            float4 a0 = *(const float4*)&As[kk][tr * 8];
            float4 a1 = *(const float4*)&As[kk][tr * 8 + 4];
            float4 b0 = *(const float4*)&Bs[kk][tc * 4];
            float a[8] = {a0.x, a0.y, a0.z, a0.w, a1.x, a1.y, a1.z, a1.w};
            float bb[4] = {b0.x, b0.y, b0.z, b0.w};
#pragma unroll
            for (int i = 0; i < 8; i++)
#pragma unroll
                for (int j = 0; j < 4; j++) acc[i][j] += a[i] * bb[j];
        }
        __syncthreads();
    }

#pragma unroll
    for (int i = 0; i < 8; i++) {
        int m = m0 + tr * 8 + i;
        if (m >= M) continue;
        float4 o;
        ushort4 ob;
#pragma unroll
        for (int j = 0; j < 4; j++) {
            int c = n0 + tc * 4 + j;
            float v = acc[i][j] + bias[c];
            if (EPI == 2)
                v = (v - bnm[c]) * rsqrtf(bnv[c] + EPS) * bng[c] + bnb[c];
            if (EPI >= 1) v = fmaxf(v, 0.f);
            ((float*)&o)[j] = v;
            ((u16*)&ob)[j] = f2b(v);
        }
        *(float4*)(C + (size_t)m * ldc + coff + n0 + tc * 4) = o;
        if (Cbf) *(ushort4*)(Cbf + (size_t)m * ldc + coff + n0 + tc * 4) = ob;
    }
}

static void gemm(int epi, const float* A, const float* B, const float* bias,
                 const float* g, const float* b2, const float* m, const float* v,
                 float* C, u16* Cbf, int M, int K, int Nc, int lda, int ldb, int ldc, int coff,
                 hipStream_t st) {
    dim3 grid((M + BM - 1) / BM, Nc / BN);
    if (epi == 0)      k_gemm<0><<<grid, 256, 0, st>>>(A, B, bias, g, b2, m, v, C, Cbf, M, K, lda, ldb, ldc, coff);
    else if (epi == 1) k_gemm<1><<<grid, 256, 0, st>>>(A, B, bias, g, b2, m, v, C, Cbf, M, K, lda, ldb, ldc, coff);
    else               k_gemm<2><<<grid, 256, 0, st>>>(A, B, bias, g, b2, m, v, C, Cbf, M, K, lda, ldb, ldc, coff);
}

// ---------------------------------------------------------------- GEMM bf16 MFMA (layer Wl/Wr)
__global__ __launch_bounds__(256) void k_gemm_bf(
    const u16* __restrict__ A,     // [M,256] bf16
    const u16* __restrict__ Bt,    // [256,256] bf16, n-major
    const float* __restrict__ bias,
    u16* __restrict__ C,           // [M,512] bf16
    int M, int coff)
{
    __shared__ __align__(16) u16 As[128 * 40];   // [128][32+8]
    __shared__ __align__(16) u16 Bs[64 * 40];    // [64][32+8]
    int tid = threadIdx.x;
    int lane = tid & 63, w = tid >> 6;
    int m0 = blockIdx.x * 128, n0 = blockIdx.y * 64;

    f32x4 acc[2][4];
#pragma unroll
    for (int i = 0; i < 2; i++)
#pragma unroll
        for (int j = 0; j < 4; j++) acc[i][j] = (f32x4){0.f, 0.f, 0.f, 0.f};

    int srow = tid >> 2, skc = (tid & 3) * 8;    // staging: row, k-chunk
    int lr = lane & 15, lk = (lane >> 4) * 8;

    for (int kt = 0; kt < 8; kt++) {
        if (kt) __syncthreads();
#pragma unroll
        for (int q = 0; q < 2; q++) {
            int arow = q * 64 + srow;
            uint4 av = make_uint4(0, 0, 0, 0);
            if (m0 + arow < M)
                av = *(const uint4*)(A + (size_t)(m0 + arow) * 256 + kt * 32 + skc);
            *(uint4*)&As[arow * 40 + skc] = av;
        }
        {
            uint4 bv = *(const uint4*)(Bt + (size_t)(n0 + srow) * 256 + kt * 32 + skc);
            *(uint4*)&Bs[srow * 40 + skc] = bv;
        }
        __syncthreads();

        short8 af0 = *(const short8*)&As[(w * 32 + lr) * 40 + lk];
        short8 af1 = *(const short8*)&As[(w * 32 + 16 + lr) * 40 + lk];
        short8 bf[4];
#pragma unroll
        for (int nt = 0; nt < 4; nt++)
            bf[nt] = *(const short8*)&Bs[(nt * 16 + lr) * 40 + lk];
#pragma unroll
        for (int nt = 0; nt < 4; nt++) {
            acc[0][nt] = __builtin_amdgcn_mfma_f32_16x16x32_bf16(af0, bf[nt], acc[0][nt], 0, 0, 0);
            acc[1][nt] = __builtin_amdgcn_mfma_f32_16x16x32_bf16(af1, bf[nt], acc[1][nt], 0, 0, 0);
        }
    }

    // C/D layout: col = lane&15, row = (lane>>4)*4 + j
    int rq = (lane >> 4) * 4;
#pragma unroll
    for (int nt = 0; nt < 4; nt++) {
        int col = n0 + nt * 16 + lr;
        float bv = bias[col];
#pragma unroll
        for (int mt = 0; mt < 2; mt++) {
#pragma unroll
            for (int j = 0; j < 4; j++) {
                int row = m0 + w * 32 + mt * 16 + rq + j;
                if (row < M)
                    C[(size_t)row * 512 + coff + col] = f2b(acc[mt][nt][j] + bv);
            }
        }
    }
}

// ---------------------------------------------------------------- GATv2 pass 1: alpha per edge (MFMA ea@We)
// one wave per 16 edges; per 16-ch block nt: one mfma_16x16x32 gives ef[edge][ch];
// D layout row=(lane>>4)*4+j (edge), col=lane&15 (ch). Fused z/leaky/att + 16-lane reduce.
__global__ __launch_bounds__(256) void k_alpha3(
    const u16* __restrict__ xlr,        // [N,512] bf16 xl|xr
    const u16* __restrict__ ea_bf,      // [E2,16] bf16 CSR order
    const int* __restrict__ csr_src, const int* __restrict__ csr_dst,  // padded +64
    const u16* __restrict__ Wef,        // [16][64][8] bf16 fragments, this layer
    const float* __restrict__ att,      // [256]
    float* __restrict__ alpha)          // [E2,4]
{
    __shared__ __align__(16) u16 wef_s[16 * 64 * 8];   // 16 KB
    int tid = threadIdx.x, lane = tid & 63, w = tid >> 6;
    // stage Wef: 1024 uint4, 4 per thread
    {
        const uint4* s = (const uint4*)Wef;
        uint4* d = (uint4*)wef_s;
#pragma unroll
        for (int q = 0; q < 4; q++) d[q * 256 + tid] = s[q * 256 + tid];
    }
    int eg = lane >> 4, t16 = lane & 15;
    int e_base = blockIdx.x * 64 + w * 16;

    // A fragment: row = t16 (edge), k-chunk = eg (0,1 real; 2,3 zero-pad)
    short8 afrag = {0, 0, 0, 0, 0, 0, 0, 0};
    if (eg < 2) {
        int e = e_base + t16; if (e > N_E2 - 1) e = N_E2 - 1;
        afrag = *(const short8*)(ea_bf + (size_t)e * 16 + eg * 8);
    }
    // my group's 4 edges
    int4 s4 = *(const int4*)(csr_src + e_base + eg * 4);
    int4 d4 = *(const int4*)(csr_dst + e_base + eg * 4);
    const u16* xlp[4]; const u16* xrp[4];
    xlp[0] = xlr + (size_t)s4.x * 512;       xlp[1] = xlr + (size_t)s4.y * 512;
    xlp[2] = xlr + (size_t)s4.z * 512;       xlp[3] = xlr + (size_t)s4.w * 512;
    xrp[0] = xlr + (size_t)d4.x * 512 + 256; xrp[1] = xlr + (size_t)d4.y * 512 + 256;
    xrp[2] = xlr + (size_t)d4.z * 512 + 256; xrp[3] = xlr + (size_t)d4.w * 512 + 256;

    float att_r[16];
#pragma unroll
    for (int q = 0; q < 16; q++) att_r[q] = att[q * 16 + t16];
    __syncthreads();

    float pj[4] = {0.f, 0.f, 0.f, 0.f};
#pragma unroll
    for (int nt = 0; nt < 16; nt++) {
        short8 bfrag = *(const short8*)&wef_s[(nt * 64 + lane) * 8];
        f32x4 D = __builtin_amdgcn_mfma_f32_16x16x32_bf16(
            afrag, bfrag, (f32x4){0.f, 0.f, 0.f, 0.f}, 0, 0, 0);
        int ch = nt * 16 + t16;
#pragma unroll
        for (int j = 0; j < 4; j++) {
            float z = D[j] + b2f(xlp[j][ch]) + b2f(xrp[j][ch]);
            z = fmaxf(z, 0.f) + 0.2f * fminf(z, 0.f);   // leaky_relu 0.2
            pj[j] = fmaf(z, att_r[nt], pj[j]);
        }
        if ((nt & 3) == 3) {
            int h = nt >> 2;
#pragma unroll
            for (int j = 0; j < 4; j++) {
                float p = pj[j];
                p += __shfl_xor(p, 1, 64);
                p += __shfl_xor(p, 2, 64);
                p += __shfl_xor(p, 4, 64);
                p += __shfl_xor(p, 8, 64);
                int e = e_base + eg * 4 + j;
                if (t16 == 0 && e < N_E2) alpha[(size_t)e * 4 + h] = p;
                pj[j] = 0.f;
            }
        }
    }
}

// ---------------------------------------------------------------- GATv2 pass 2: softmax + aggregate
__global__ __launch_bounds__(256) void k_aggr(
    const u16* __restrict__ xlr, const float* __restrict__ alpha,
    const int* __restrict__ rowp, const int* __restrict__ csr_src,
    const float* __restrict__ cbias,
    const float* __restrict__ bng, const float* __restrict__ bnb,
    const float* __restrict__ bnm, const float* __restrict__ bnv,
    float* __restrict__ h, u16* __restrict__ h_bf)   // [N,256] in/out + bf16 copy
{
    __shared__ float lex[4][64][4];      // [wave][edge-in-chunk][head]
    __shared__ int   lsrc[4][64];
    int lane = threadIdx.x & 63;
    int wv = threadIdx.x >> 6;
    int n = blockIdx.x * 4 + wv;
    if (n >= N_NODES) return;
    int st = rowp[n], en = rowp[n + 1];
    int hsel = lane >> 4;                // head owning channels c0..c0+3
    int c0 = lane * 4;

    float m4[4]  = {-3.0e38f, -3.0e38f, -3.0e38f, -3.0e38f};
    float den4[4] = {0.f, 0.f, 0.f, 0.f};
    float acc[4]  = {0.f, 0.f, 0.f, 0.f};

    for (int cs = st; cs < en; cs += 64) {
        int cnt = min(64, en - cs);
        float a4[4];
        int s_i = 0;
        if (lane < cnt) {
            float4 v = *(const float4*)(alpha + (size_t)(cs + lane) * 4);
            a4[0] = v.x; a4[1] = v.y; a4[2] = v.z; a4[3] = v.w;
            s_i = csr_src[cs + lane];
        } else {
            a4[0] = a4[1] = a4[2] = a4[3] = -3.0e38f;
        }
        float cm[4] = {a4[0], a4[1], a4[2], a4[3]};
#pragma unroll
        for (int o = 32; o >= 1; o >>= 1)
#pragma unroll
            for (int u = 0; u < 4; u++) cm[u] = fmaxf(cm[u], __shfl_xor(cm[u], o, 64));
        float sc[4];
#pragma unroll
        for (int u = 0; u < 4; u++) {
            float nm = fmaxf(m4[u], cm[u]);
            sc[u] = __expf(m4[u] - nm);
            den4[u] *= sc[u];
            m4[u] = nm;
        }
        float scl = sc[hsel];
#pragma unroll
        for (int u = 0; u < 4; u++) acc[u] *= scl;
        float ex[4];
#pragma unroll
        for (int u = 0; u < 4; u++) ex[u] = (lane < cnt) ? __expf(a4[u] - m4[u]) : 0.f;
        float sx[4] = {ex[0], ex[1], ex[2], ex[3]};
#pragma unroll
        for (int o = 32; o >= 1; o >>= 1)
#pragma unroll
            for (int u = 0; u < 4; u++) sx[u] += __shfl_xor(sx[u], o, 64);
#pragma unroll
        for (int u = 0; u < 4; u++) den4[u] += sx[u];
        *(float4*)&lex[wv][lane][0] = make_float4(ex[0], ex[1], ex[2], ex[3]);
        lsrc[wv][lane] = s_i;
        // weighted gather-sum: 8 row-gathers (8B bf16x4) in flight per step
        int j = 0;
        for (; j + 8 <= cnt; j += 8) {
            float a[8]; int sj[8];
#pragma unroll
            for (int q = 0; q < 8; q++) { a[q] = lex[wv][j + q][hsel]; sj[q] = lsrc[wv][j + q]; }
            ushort4 xg[8];
#pragma unroll
            for (int q = 0; q < 8; q++) xg[q] = *(const ushort4*)(xlr + (size_t)sj[q] * 512 + c0);
#pragma unroll
            for (int q = 0; q < 8; q++) {
                acc[0] += a[q] * b2f(((const u16*)&xg[q])[0]);
                acc[1] += a[q] * b2f(((const u16*)&xg[q])[1]);
                acc[2] += a[q] * b2f(((const u16*)&xg[q])[2]);
                acc[3] += a[q] * b2f(((const u16*)&xg[q])[3]);
            }
        }
        for (; j < cnt; j++) {
            float a = lex[wv][j][hsel];
            int sj = lsrc[wv][j];
            ushort4 xg = *(const ushort4*)(xlr + (size_t)sj * 512 + c0);
            acc[0] += a * b2f(((const u16*)&xg)[0]);
            acc[1] += a * b2f(((const u16*)&xg)[1]);
            acc[2] += a * b2f(((const u16*)&xg)[2]);
            acc[3] += a * b2f(((const u16*)&xg)[3]);
        }
    }

    float dd = den4[hsel];
    float4 hin = *(const float4*)(h + (size_t)n * 256 + c0);
    float4 cb  = *(const float4*)(cbias + c0);
    float4 gg  = *(const float4*)(bng + c0);
    float4 bb  = *(const float4*)(bnb + c0);
    float4 mm  = *(const float4*)(bnm + c0);
    float4 vv  = *(const float4*)(bnv + c0);
    float hi[4] = {hin.x, hin.y, hin.z, hin.w};
    float cbv[4] = {cb.x, cb.y, cb.z, cb.w};
    float gv[4] = {gg.x, gg.y, gg.z, gg.w};
    float bv[4] = {bb.x, bb.y, bb.z, bb.w};
    float mv[4] = {mm.x, mm.y, mm.z, mm.w};
    float vvv[4] = {vv.x, vv.y, vv.z, vv.w};
    float4 o;
    ushort4 ob;
#pragma unroll
    for (int u = 0; u < 4; u++) {
        float val = acc[u] / dd + cbv[u];
        val = (val - mv[u]) * rsqrtf(vvv[u] + EPS) * gv[u] + bv[u];
        val = fmaxf(val, 0.f) + hi[u];
        ((float*)&o)[u] = val;
        ((u16*)&ob)[u] = f2b(val);
    }
    *(float4*)(h + (size_t)n * 256 + c0) = o;
    *(ushort4*)(h_bf + (size_t)n * 256 + c0) = ob;
}

// ---------------------------------------------------------------- pooling + classifier tail
__global__ void k_pool(const float* __restrict__ h, float* __restrict__ xp) {
    int g = blockIdx.x, c = threadIdx.x;
    int st = (g * N_NODES + N_GRAPHS - 1) / N_GRAPHS;
    int en = ((g + 1) * N_NODES + N_GRAPHS - 1) / N_GRAPHS;
    float s = 0.f, mx = -3.0e38f;
    for (int i = st; i < en; i++) {
        float v = h[(size_t)i * 256 + c];
        s += v;
        mx = fmaxf(mx, v);
    }
    xp[g * 512 + c] = s / (float)(en - st);
    xp[g * 512 + 256 + c] = mx;
}

__global__ void k_final(const float* __restrict__ z2, const float* __restrict__ W3,
                        const float* __restrict__ b3, float* __restrict__ out) {
    int m = threadIdx.x;
    float s = b3[0];
    for (int k = 0; k < 128; k++) s += z2[m * 128 + k] * W3[k];
    out[m] = s;
}

// ---------------------------------------------------------------- launch
extern "C" void kernel_launch(void* const* d_in, const int* in_sizes, int n_in,
                              void* d_out, int out_size, void* d_ws, size_t ws_size,
                              hipStream_t stream) {
    const float* x         = (const float*)d_in[0];
    const int*   ei        = (const int*)d_in[1];
    const int*   src       = ei;
    const int*   dst       = ei + N_EDGES;
    const float* edge_attr = (const float*)d_in[3];
    const float* enc_W     = (const float*)d_in[4];
    const float* enc_b     = (const float*)d_in[5];
    const float* conv_Wl   = (const float*)d_in[6];
    const float* conv_bl   = (const float*)d_in[7];
    const float* conv_Wr   = (const float*)d_in[8];
    const float* conv_br   = (const float*)d_in[9];
    const float* conv_We   = (const float*)d_in[10];
    const float* conv_att  = (const float*)d_in[11];
    const float* conv_bias = (const float*)d_in[12];
    const float* bn_g      = (const float*)d_in[13];
    const float* bn_b      = (const float*)d_in[14];
    const float* bn_m      = (const float*)d_in[15];
    const float* bn_v      = (const float*)d_in[16];
    const float* cls_W1    = (const float*)d_in[17];
    const float* cls_b1    = (const float*)d_in[18];
    const float* cls_g1    = (const float*)d_in[19];
    const float* cls_bt1   = (const float*)d_in[20];
    const float* cls_m1    = (const float*)d_in[21];
    const float* cls_v1    = (const float*)d_in[22];
    const float* cls_W2    = (const float*)d_in[23];
    const float* cls_b2    = (const float*)d_in[24];
    const float* cls_g2    = (const float*)d_in[25];
    const float* cls_bt2   = (const float*)d_in[26];
    const float* cls_m2    = (const float*)d_in[27];
    const float* cls_v2    = (const float*)d_in[28];
    const float* cls_W3    = (const float*)d_in[29];
    const float* cls_b3    = (const float*)d_in[30];
    float* out = (float*)d_out;

    char* ws = (char*)d_ws;
    size_t off = 0;
    auto alloc = [&](size_t bytes) -> void* {
        void* p = ws + off;
        off += (bytes + 255) & ~(size_t)255;
        return p;
    };
    float* h       = (float*)alloc((size_t)N_NODES * 256 * 4);    // 20.5 MB
    u16*   h_bf    = (u16*)alloc((size_t)N_NODES * 256 * 2);      // 10.2 MB
    u16*   xlr_bf  = (u16*)alloc((size_t)N_NODES * 512 * 2);      // 20.5 MB
    float* lattr   = (float*)alloc((size_t)N_NODES * 16 * 4);     // 1.3 MB
    u16*   ea_bf   = (u16*)alloc((size_t)N_E2 * 16 * 2);          // 10.9 MB
    float* alphas  = (float*)alloc((size_t)N_E2 * 4 * 4);         // 5.4 MB
    u16*   Wtl     = (u16*)alloc((size_t)3 * 65536 * 2);          // 0.4 MB
    u16*   Wtr     = (u16*)alloc((size_t)3 * 65536 * 2);          // 0.4 MB
    u16*   Wef     = (u16*)alloc((size_t)3 * 16 * 64 * 8 * 2);    // 48 KB
    float* xp      = (float*)alloc((size_t)N_GRAPHS * 512 * 4);
    float* z1      = (float*)alloc((size_t)N_GRAPHS * 256 * 4);
    float* z2      = (float*)alloc((size_t)N_GRAPHS * 128 * 4);
    int*   cnt     = (int*)alloc((size_t)N_NODES * 4);
    int*   rowp    = (int*)alloc((size_t)(N_NODES + 1) * 4);
    int*   cursor  = (int*)alloc((size_t)N_NODES * 4);
    int*   csr_src = (int*)alloc((size_t)(N_E2 + 64) * 4);
    int*   csr_dst = (int*)alloc((size_t)(N_E2 + 64) * 4);
    int*   csr_aid = (int*)alloc((size_t)N_E2 * 4);
    int*   part    = (int*)alloc(64 * 4);

    // CSR build
    k_init<<<(N_NODES + 255) / 256, 256, 0, stream>>>(cnt, cursor);
    k_count<<<(N_EDGES + 255) / 256, 256, 0, stream>>>(dst, cnt);
    k_scan1<<<NSCAN, 256, 0, stream>>>(cnt, rowp, part);
    k_scan2<<<1, 1, 0, stream>>>(part, rowp);
    k_scan3<<<NSCAN, 256, 0, stream>>>(rowp, part);
    k_fill<<<(N_E2 + 255) / 256, 256, 0, stream>>>(src, dst, rowp, cursor, csr_src, csr_dst, csr_aid);
    k_pad<<<1, 64, 0, stream>>>(csr_src, csr_dst);
    k_loopattr<<<(N_NODES * 16 + 255) / 256, 256, 0, stream>>>(rowp, csr_aid, edge_attr, lattr);
    k_eacsr<<<(N_E2 * 2 + 255) / 256, 256, 0, stream>>>(csr_aid, edge_attr, lattr, ea_bf);

    // weight prep
    k_tw<<<dim3(8, 8, 3), 256, 0, stream>>>(conv_Wl, Wtl);
    k_tw<<<dim3(8, 8, 3), 256, 0, stream>>>(conv_Wr, Wtr);
    k_wef<<<12, 256, 0, stream>>>(conv_We, Wef);

    // encoder: h = relu(x @ enc_W + enc_b), also emit h_bf
    gemm(1, x, enc_W, enc_b, nullptr, nullptr, nullptr, nullptr,
         h, h_bf, N_NODES, 64, 256, 64, 256, 256, 0, stream);

    // 3 GATv2 layers
    int ablocks = (N_E2 + 63) / 64;   // 5313
    dim3 ggrid((N_NODES + 127) / 128, 4);
    for (int i = 0; i < 3; i++) {
        k_gemm_bf<<<ggrid, 256, 0, stream>>>(h_bf, Wtl + (size_t)i * 65536,
                                             conv_bl + i * HID, xlr_bf, N_NODES, 0);
        k_gemm_bf<<<ggrid, 256, 0, stream>>>(h_bf, Wtr + (size_t)i * 65536,
                                             conv_br + i * HID, xlr_bf, N_NODES, 256);
        k_alpha3<<<ablocks, 256, 0, stream>>>(
            xlr_bf, ea_bf, csr_src, csr_dst,
            Wef + (size_t)i * 8192, conv_att + (size_t)i * 256, alphas);
        k_aggr<<<N_NODES / 4, 256, 0, stream>>>(
            xlr_bf, alphas, rowp, csr_src,
            conv_bias + (size_t)i * HID,
            bn_g + (size_t)i * HID, bn_b + (size_t)i * HID,
            bn_m + (size_t)i * HID, bn_v + (size_t)i * HID, h, h_bf);
    }

    // pooling + classifier
    k_pool<<<N_GRAPHS, 256, 0, stream>>>(h, xp);
    gemm(2, xp, cls_W1, cls_b1, cls_g1, cls_bt1, cls_m1, cls_v1,
         z1, nullptr, N_GRAPHS, 512, 256, 512, 256, 256, 0, stream);
    gemm(2, z1, cls_W2, cls_b2, cls_g2, cls_bt2, cls_m2, cls_v2,
         z2, nullptr, N_GRAPHS, 256, 128, 256, 128, 128, 0, stream);
    k_final<<<1, 256, 0, stream>>>(z2, cls_W3, cls_b3, out);
}

// Round 7
// 496.329 us; speedup vs baseline: 2.5388x; 1.1153x over previous
//
#include <hip/hip_runtime.h>
#include <hip/hip_bf16.h>

#define N_NODES 20000
#define N_EDGES 320000
#define N_E2    (N_EDGES + N_NODES)   // 340000 edges incl self loops
#define N_GRAPHS 256
#define HID 256
#define EPS 1e-5f
#define NSCAN 20                       // ceil(20000/1024)
#define CPB 8                          // 64-edge chunks per k_alpha3 block

typedef unsigned short u16;
typedef __attribute__((ext_vector_type(8))) short short8;
typedef __attribute__((ext_vector_type(4))) float f32x4;

__device__ __forceinline__ float b2f(u16 u) {
    union { unsigned int i; float f; } v; v.i = ((unsigned int)u) << 16; return v.f;
}
__device__ __forceinline__ u16 f2b(float f) {
    __hip_bfloat16 h = __float2bfloat16(f);   // RNE
    return *reinterpret_cast<u16*>(&h);
}

// ---------------------------------------------------------------- CSR build
__global__ void k_init(int* cnt, int* cursor) {
    int i = blockIdx.x * 256 + threadIdx.x;
    if (i < N_NODES) { cnt[i] = 1; cursor[i] = 0; }  // count starts at 1: self loop
}

__global__ void k_count(const int* __restrict__ dst, int* __restrict__ cnt) {
    int e = blockIdx.x * 256 + threadIdx.x;
    if (e < N_EDGES) atomicAdd(&cnt[dst[e]], 1);
}

__global__ void k_scan1(const int* __restrict__ cnt, int* __restrict__ rowp, int* __restrict__ part) {
    __shared__ int ls[256];
    int b = blockIdx.x, tid = threadIdx.x;
    int base = b * 1024 + tid * 4;
    int c[4]; int s = 0;
#pragma unroll
    for (int u = 0; u < 4; u++) { int i = base + u; c[u] = (i < N_NODES) ? cnt[i] : 0; s += c[u]; }
    ls[tid] = s; __syncthreads();
    for (int off = 1; off < 256; off <<= 1) {
        int v = (tid >= off) ? ls[tid - off] : 0;
        __syncthreads();
        ls[tid] += v;
        __syncthreads();
    }
    int excl = ls[tid] - s;
#pragma unroll
    for (int u = 0; u < 4; u++) { int i = base + u; if (i < N_NODES) rowp[i] = excl; excl += c[u]; }
    if (tid == 255) part[b] = ls[255];
}

__global__ void k_scan2(int* part, int* rowp) {
    int s = 0;
    for (int b = 0; b < NSCAN; b++) { int v = part[b]; part[b] = s; s += v; }
    rowp[N_NODES] = s;   // == N_E2
}

__global__ void k_scan3(int* __restrict__ rowp, const int* __restrict__ part) {
    int b = blockIdx.x, tid = threadIdx.x;
    int add = part[b];
    int base = b * 1024 + tid * 4;
#pragma unroll
    for (int u = 0; u < 4; u++) { int i = base + u; if (i < N_NODES) rowp[i] += add; }
}

__global__ void k_fill(const int* __restrict__ src, const int* __restrict__ dst,
                       const int* __restrict__ rowp, int* __restrict__ cursor,
                       int* __restrict__ csr_src, int* __restrict__ csr_dst,
                       int* __restrict__ csr_aid) {
    int t = blockIdx.x * 256 + threadIdx.x;
    if (t < N_EDGES) {
        int d = dst[t];
        int pos = atomicAdd(&cursor[d], 1);
        int w = rowp[d] + pos;
        csr_src[w] = src[t];
        csr_dst[w] = d;
        csr_aid[w] = t;
    } else if (t < N_E2) {
        int n = t - N_EDGES;
        int pos = atomicAdd(&cursor[n], 1);
        int w = rowp[n] + pos;
        csr_src[w] = n;
        csr_dst[w] = n;
        csr_aid[w] = N_EDGES + n;   // self loop, attr = loop_attr[n]
    }
}

// zero the +512 padding of csr_src/csr_dst (tail-chunk int4 reads)
__global__ void k_pad(int* csr_src, int* csr_dst) {
    int i = threadIdx.x;   // 512 threads
    csr_src[N_E2 + i] = 0;
    csr_dst[N_E2 + i] = 0;
}

// loop_attr[n][j] = mean over incoming (original) edges of edge_attr
__global__ void k_loopattr(const int* __restrict__ rowp, const int* __restrict__ csr_aid,
                           const float* __restrict__ edge_attr, float* __restrict__ lattr) {
    int t = blockIdx.x * 256 + threadIdx.x;
    if (t >= N_NODES * 16) return;
    int n = t >> 4, j = t & 15;
    int st = rowp[n], en = rowp[n + 1];
    float s = 0.f;
    for (int i = st; i < en; i++) {
        int aid = csr_aid[i];
        if (aid < N_EDGES) s += edge_attr[(size_t)aid * 16 + j];
    }
    float deg = (float)(en - st - 1);
    lattr[(size_t)n * 16 + j] = s / fmaxf(deg, 1.0f);
}

// ea_bf[e][0:16] = bf16(edge_attr[csr_aid[e]]) (or loop_attr), CSR order — built once.
__global__ void k_eacsr(const int* __restrict__ csr_aid,
                        const float* __restrict__ edge_attr,
                        const float* __restrict__ lattr,
                        u16* __restrict__ ea_bf) {
    int t = blockIdx.x * 256 + threadIdx.x;   // one thread per 8 attrs
    if (t >= N_E2 * 2) return;
    int e = t >> 1, hf = t & 1;
    int aid = csr_aid[e];
    const float* ap = (aid < N_EDGES) ? edge_attr + (size_t)aid * 16
                                      : lattr + (size_t)(aid - N_EDGES) * 16;
    float4 a = ((const float4*)ap)[hf * 2];
    float4 b = ((const float4*)ap)[hf * 2 + 1];
    u16 v[8] = {f2b(a.x), f2b(a.y), f2b(a.z), f2b(a.w),
                f2b(b.x), f2b(b.y), f2b(b.z), f2b(b.w)};
    *(uint4*)(ea_bf + (size_t)t * 8) = *(uint4*)v;
}

// We[layer][16][256] fp32 -> B-fragment layout Wef[layer][nt][lane][8] bf16 (K padded to 32)
__global__ void k_wef(const float* __restrict__ We, u16* __restrict__ Wef) {
    int t = blockIdx.x * 256 + threadIdx.x;   // 3*16*64 = 3072
    if (t >= 3 * 16 * 64) return;
    int layer = t >> 10, r = t & 1023;
    int nt = r >> 6, l = r & 63;
    int kc = l >> 4, ch = nt * 16 + (l & 15);
    u16 v[8];
#pragma unroll
    for (int q = 0; q < 8; q++) {
        float x = 0.f;
        if (kc < 2) x = We[(size_t)layer * 4096 + (size_t)(kc * 8 + q) * 256 + ch];
        v[q] = f2b(x);
    }
    *(uint4*)(Wef + (size_t)t * 8) = *(uint4*)v;
}

// x (fp32) -> bf16
__global__ void k_xbf(const float* __restrict__ x, u16* __restrict__ xb) {
    int t = blockIdx.x * 256 + threadIdx.x;   // N*64/4 threads
    if (t >= N_NODES * 16) return;
    float4 v = ((const float4*)x)[t];
    u16 o[4] = {f2b(v.x), f2b(v.y), f2b(v.z), f2b(v.w)};
    *(ushort4*)(xb + (size_t)t * 4) = *(ushort4*)o;
}

// W[layer][K][N] fp32 -> Wt[layer][N][K] bf16 (32x32 LDS tile transpose)
__global__ void k_twg(const float* __restrict__ W, u16* __restrict__ Wt, int K, int N) {
    __shared__ float tile[32][33];
    int layer = blockIdx.z;
    const float* Wp = W + (size_t)layer * K * N;
    u16* Wtp = Wt + (size_t)layer * K * N;
    int bk = blockIdx.x * 32, bn = blockIdx.y * 32;
    int tx = threadIdx.x & 31, ty = threadIdx.x >> 5; // 32 x 8
#pragma unroll
    for (int q = 0; q < 4; q++) {
        int k = bk + ty + q * 8;
        tile[ty + q * 8][tx] = Wp[(size_t)k * N + bn + tx];
    }
    __syncthreads();
#pragma unroll
    for (int q = 0; q < 4; q++) {
        int n = bn + ty + q * 8;
        Wtp[(size_t)n * K + bk + tx] = f2b(tile[tx][ty + q * 8]);
    }
}

// ---------------------------------------------------------------- GEMM bf16 MFMA
// C[M,N=256-wide grid] = A[M,K] @ Bt^T + bias; Bt n-major [n][K].
// EPI 0: store bf16 to Cbf at ldc/coff (xlr). EPI 1: relu, store fp32 Cf + bf16 Cbf (ldc).
template <int EPI>
__global__ __launch_bounds__(256) void k_gemm_bf(
    const u16* __restrict__ A, int lda,
    const u16* __restrict__ Bt, int ldb, int K,
    const float* __restrict__ bias,
    u16* __restrict__ Cbf, int ldc, int coff,
    float* __restrict__ Cf, int M)
{
    __shared__ __align__(16) u16 As[128 * 40];   // [128][32+8]
    __shared__ __align__(16) u16 Bs[64 * 40];    // [64][32+8]
    int tid = threadIdx.x;
    int lane = tid & 63, w = tid >> 6;
    int m0 = blockIdx.x * 128, n0 = blockIdx.y * 64;

    f32x4 acc[2][4];
#pragma unroll
    for (int i = 0; i < 2; i++)
#pragma unroll
        for (int j = 0; j < 4; j++) acc[i][j] = (f32x4){0.f, 0.f, 0.f, 0.f};

    int srow = tid >> 2, skc = (tid & 3) * 8;    // staging: row, k-chunk
    int lr = lane & 15, lk = (lane >> 4) * 8;

    int ktiles = K >> 5;
    for (int kt = 0; kt < ktiles; kt++) {
        if (kt) __syncthreads();
#pragma unroll
        for (int q = 0; q < 2; q++) {
            int arow = q * 64 + srow;
            uint4 av = make_uint4(0, 0, 0, 0);
            if (m0 + arow < M)
                av = *(const uint4*)(A + (size_t)(m0 + arow) * lda + kt * 32 + skc);
            *(uint4*)&As[arow * 40 + skc] = av;
        }
        {
            uint4 bv = *(const uint4*)(Bt + (size_t)(n0 + srow) * ldb + kt * 32 + skc);
            *(uint4*)&Bs[srow * 40 + skc] = bv;
        }
        __syncthreads();

        short8 af0 = *(const short8*)&As[(w * 32 + lr) * 40 + lk];
        short8 af1 = *(const short8*)&As[(w * 32 + 16 + lr) * 40 + lk];
        short8 bf[4];
#pragma unroll
        for (int nt = 0; nt < 4; nt++)
            bf[nt] = *(const short8*)&Bs[(nt * 16 + lr) * 40 + lk];
#pragma unroll
        for (int nt = 0; nt < 4; nt++) {
            acc[0][nt] = __builtin_amdgcn_mfma_f32_16x16x32_bf16(af0, bf[nt], acc[0][nt], 0, 0, 0);
            acc[1][nt] = __builtin_amdgcn_mfma_f32_16x16x32_bf16(af1, bf[nt], acc[1][nt], 0, 0, 0);
        }
    }

    // C/D layout: col = lane&15, row = (lane>>4)*4 + j
    int rq = (lane >> 4) * 4;
#pragma unroll
    for (int nt = 0; nt < 4; nt++) {
        int col = n0 + nt * 16 + lr;
        float bv = bias[col];
#pragma unroll
        for (int mt = 0; mt < 2; mt++) {
#pragma unroll
            for (int j = 0; j < 4; j++) {
                int row = m0 + w * 32 + mt * 16 + rq + j;
                if (row < M) {
                    float v = acc[mt][nt][j] + bv;
                    if (EPI == 1) {
                        v = fmaxf(v, 0.f);
                        Cf[(size_t)row * ldc + col] = v;
                        Cbf[(size_t)row * ldc + col] = f2b(v);
                    } else {
                        Cbf[(size_t)row * ldc + coff + col] = f2b(v);
                    }
                }
            }
        }
    }
}

// ---------------------------------------------------------------- GATv2 pass 1: alpha per edge (MFMA ea@We)
// one wave per 16 edges, CPB 64-edge chunks per block (Wef staged once).
__global__ __launch_bounds__(256) void k_alpha3(
    const u16* __restrict__ xlr,        // [N,512] bf16 xl|xr
    const u16* __restrict__ ea_bf,      // [E2,16] bf16 CSR order
    const int* __restrict__ csr_src, const int* __restrict__ csr_dst,  // padded +512
    const u16* __restrict__ Wef,        // [16][64][8] bf16 fragments, this layer
    const float* __restrict__ att,      // [256]
    float* __restrict__ alpha)          // [E2,4]
{
    __shared__ __align__(16) u16 wef_s[16 * 64 * 8];   // 16 KB
    int tid = threadIdx.x, lane = tid & 63, w = tid >> 6;
    {
        const uint4* s = (const uint4*)Wef;
        uint4* d = (uint4*)wef_s;
#pragma unroll
        for (int q = 0; q < 4; q++) d[q * 256 + tid] = s[q * 256 + tid];
    }
    int eg = lane >> 4, t16 = lane & 15;

    float att_r[16];
#pragma unroll
    for (int q = 0; q < 16; q++) att_r[q] = att[q * 16 + t16];
    __syncthreads();

    for (int it = 0; it < CPB; it++) {
        int chunk = blockIdx.x * CPB + it;
        if (chunk * 64 >= N_E2) break;
        int e_base = chunk * 64 + w * 16;

        // A fragment: row = t16 (edge), k-chunk = eg (0,1 real; 2,3 zero-pad)
        short8 afrag = {0, 0, 0, 0, 0, 0, 0, 0};
        if (eg < 2) {
            int e = e_base + t16; if (e > N_E2 - 1) e = N_E2 - 1;
            afrag = *(const short8*)(ea_bf + (size_t)e * 16 + eg * 8);
        }
        int4 s4 = *(const int4*)(csr_src + e_base + eg * 4);
        int4 d4 = *(const int4*)(csr_dst + e_base + eg * 4);
        const u16* xlp[4]; const u16* xrp[4];
        xlp[0] = xlr + (size_t)s4.x * 512;       xlp[1] = xlr + (size_t)s4.y * 512;
        xlp[2] = xlr + (size_t)s4.z * 512;       xlp[3] = xlr + (size_t)s4.w * 512;
        xrp[0] = xlr + (size_t)d4.x * 512 + 256; xrp[1] = xlr + (size_t)d4.y * 512 + 256;
        xrp[2] = xlr + (size_t)d4.z * 512 + 256; xrp[3] = xlr + (size_t)d4.w * 512 + 256;

        float pj[4] = {0.f, 0.f, 0.f, 0.f};
#pragma unroll
        for (int nt = 0; nt < 16; nt++) {
            short8 bfrag = *(const short8*)&wef_s[(nt * 64 + lane) * 8];
            f32x4 D = __builtin_amdgcn_mfma_f32_16x16x32_bf16(
                afrag, bfrag, (f32x4){0.f, 0.f, 0.f, 0.f}, 0, 0, 0);
            int ch = nt * 16 + t16;
#pragma unroll
            for (int j = 0; j < 4; j++) {
                float z = D[j] + b2f(xlp[j][ch]) + b2f(xrp[j][ch]);
                z = fmaxf(z, 0.f) + 0.2f * fminf(z, 0.f);   // leaky_relu 0.2
                pj[j] = fmaf(z, att_r[nt], pj[j]);
            }
            if ((nt & 3) == 3) {
                int hh = nt >> 2;
#pragma unroll
                for (int j = 0; j < 4; j++) {
                    float p = pj[j];
                    p += __shfl_xor(p, 1, 64);
                    p += __shfl_xor(p, 2, 64);
                    p += __shfl_xor(p, 4, 64);
                    p += __shfl_xor(p, 8, 64);
                    int e = e_base + eg * 4 + j;
                    if (t16 == 0 && e < N_E2) alpha[(size_t)e * 4 + hh] = p;
                    pj[j] = 0.f;
                }
            }
        }
    }
}

// ---------------------------------------------------------------- GATv2 pass 2: softmax + aggregate
__global__ __launch_bounds__(256) void k_aggr(
    const u16* __restrict__ xlr, const float* __restrict__ alpha,
    const int* __restrict__ rowp, const int* __restrict__ csr_src,
    const float* __restrict__ cbias,
    const float* __restrict__ bng, const float* __restrict__ bnb,
    const float* __restrict__ bnm, const float* __restrict__ bnv,
    float* __restrict__ h, u16* __restrict__ h_bf)   // [N,256] in/out + bf16 copy
{
    __shared__ float lex[4][64][4];      // [wave][edge-in-chunk][head]
    __shared__ int   lsrc[4][64];
    int lane = threadIdx.x & 63;
    int wv = threadIdx.x >> 6;
    int n = blockIdx.x * 4 + wv;
    if (n >= N_NODES) return;
    int st = rowp[n], en = rowp[n + 1];
    int hsel = lane >> 4;                // head owning channels c0..c0+3
    int c0 = lane * 4;

    float m4[4]  = {-3.0e38f, -3.0e38f, -3.0e38f, -3.0e38f};
    float den4[4] = {0.f, 0.f, 0.f, 0.f};
    float acc[4]  = {0.f, 0.f, 0.f, 0.f};

    for (int cs = st; cs < en; cs += 64) {
        int cnt = min(64, en - cs);
        float a4[4];
        int s_i = 0;
        if (lane < cnt) {
            float4 v = *(const float4*)(alpha + (size_t)(cs + lane) * 4);
            a4[0] = v.x; a4[1] = v.y; a4[2] = v.z; a4[3] = v.w;
            s_i = csr_src[cs + lane];
        } else {
            a4[0] = a4[1] = a4[2] = a4[3] = -3.0e38f;
        }
        float cm[4] = {a4[0], a4[1], a4[2], a4[3]};
#pragma unroll
        for (int o = 32; o >= 1; o >>= 1)
#pragma unroll
            for (int u = 0; u < 4; u++) cm[u] = fmaxf(cm[u], __shfl_xor(cm[u], o, 64));
        float sc[4];
#pragma unroll
        for (int u = 0; u < 4; u++) {
            float nm = fmaxf(m4[u], cm[u]);
            sc[u] = __expf(m4[u] - nm);
            den4[u] *= sc[u];
            m4[u] = nm;
        }
        float scl = sc[hsel];
#pragma unroll
        for (int u = 0; u < 4; u++) acc[u] *= scl;
        float ex[4];
#pragma unroll
        for (int u = 0; u < 4; u++) ex[u] = (lane < cnt) ? __expf(a4[u] - m4[u]) : 0.f;
        float sx[4] = {ex[0], ex[1], ex[2], ex[3]};
#pragma unroll
        for (int o = 32; o >= 1; o >>= 1)
#pragma unroll
            for (int u = 0; u < 4; u++) sx[u] += __shfl_xor(sx[u], o, 64);
#pragma unroll
        for (int u = 0; u < 4; u++) den4[u] += sx[u];
        *(float4*)&lex[wv][lane][0] = make_float4(ex[0], ex[1], ex[2], ex[3]);
        lsrc[wv][lane] = s_i;
        // weighted gather-sum: 8 row-gathers (8B bf16x4) in flight per step
        int j = 0;
        for (; j + 8 <= cnt; j += 8) {
            float a[8]; int sj[8];
#pragma unroll
            for (int q = 0; q < 8; q++) { a[q] = lex[wv][j + q][hsel]; sj[q] = lsrc[wv][j + q]; }
            ushort4 xg[8];
#pragma unroll
            for (int q = 0; q < 8; q++) xg[q] = *(const ushort4*)(xlr + (size_t)sj[q] * 512 + c0);
#pragma unroll
            for (int q = 0; q < 8; q++) {
                acc[0] += a[q] * b2f(((const u16*)&xg[q])[0]);
                acc[1] += a[q] * b2f(((const u16*)&xg[q])[1]);
                acc[2] += a[q] * b2f(((const u16*)&xg[q])[2]);
                acc[3] += a[q] * b2f(((const u16*)&xg[q])[3]);
            }
        }
        for (; j < cnt; j++) {
            float a = lex[wv][j][hsel];
            int sj = lsrc[wv][j];
            ushort4 xg = *(const ushort4*)(xlr + (size_t)sj * 512 + c0);
            acc[0] += a * b2f(((const u16*)&xg)[0]);
            acc[1] += a * b2f(((const u16*)&xg)[1]);
            acc[2] += a * b2f(((const u16*)&xg)[2]);
            acc[3] += a * b2f(((const u16*)&xg)[3]);
        }
    }

    float dd = den4[hsel];
    float4 hin = *(const float4*)(h + (size_t)n * 256 + c0);
    float4 cb  = *(const float4*)(cbias + c0);
    float4 gg  = *(const float4*)(bng + c0);
    float4 bb  = *(const float4*)(bnb + c0);
    float4 mm  = *(const float4*)(bnm + c0);
    float4 vv  = *(const float4*)(bnv + c0);
    float hi[4] = {hin.x, hin.y, hin.z, hin.w};
    float cbv[4] = {cb.x, cb.y, cb.z, cb.w};
    float gv[4] = {gg.x, gg.y, gg.z, gg.w};
    float bv[4] = {bb.x, bb.y, bb.z, bb.w};
    float mv[4] = {mm.x, mm.y, mm.z, mm.w};
    float vvv[4] = {vv.x, vv.y, vv.z, vv.w};
    float4 o;
    ushort4 ob;
#pragma unroll
    for (int u = 0; u < 4; u++) {
        float val = acc[u] / dd + cbv[u];
        val = (val - mv[u]) * rsqrtf(vvv[u] + EPS) * gv[u] + bv[u];
        val = fmaxf(val, 0.f) + hi[u];
        ((float*)&o)[u] = val;
        ((u16*)&ob)[u] = f2b(val);
    }
    *(float4*)(h + (size_t)n * 256 + c0) = o;
    *(ushort4*)(h_bf + (size_t)n * 256 + c0) = ob;
}

// ---------------------------------------------------------------- fused pool + classifier
// one block per graph: pool rows -> xp (LDS) -> z1 -> z2 -> out[g]
__global__ __launch_bounds__(256) void k_head(
    const float* __restrict__ h,
    const float* __restrict__ W1, const float* __restrict__ b1,
    const float* __restrict__ g1, const float* __restrict__ bt1,
    const float* __restrict__ m1, const float* __restrict__ v1,
    const float* __restrict__ W2, const float* __restrict__ b2,
    const float* __restrict__ g2, const float* __restrict__ bt2,
    const float* __restrict__ m2, const float* __restrict__ v2,
    const float* __restrict__ W3, const float* __restrict__ b3,
    float* __restrict__ out)
{
    __shared__ float xp_s[512];
    __shared__ float z1_s[256];
    __shared__ float z2_s[128];
    int g = blockIdx.x, c = threadIdx.x;
    int st = (g * N_NODES + N_GRAPHS - 1) / N_GRAPHS;
    int en = ((g + 1) * N_NODES + N_GRAPHS - 1) / N_GRAPHS;

    float s = 0.f, mx = -3.0e38f;
    for (int i = st; i < en; i++) {
        float v = h[(size_t)i * 256 + c];
        s += v;
        mx = fmaxf(mx, v);
    }
    xp_s[c] = s / (float)(en - st);
    xp_s[256 + c] = mx;
    __syncthreads();

    float a = 0.f;
#pragma unroll 8
    for (int k = 0; k < 512; k++) a = fmaf(xp_s[k], W1[k * 256 + c], a);
    a += b1[c];
    a = (a - m1[c]) * rsqrtf(v1[c] + EPS) * g1[c] + bt1[c];
    z1_s[c] = fmaxf(a, 0.f);
    __syncthreads();

    if (c < 128) {
        float a2 = 0.f;
#pragma unroll 8
        for (int k = 0; k < 256; k++) a2 = fmaf(z1_s[k], W2[k * 128 + c], a2);
        a2 += b2[c];
        a2 = (a2 - m2[c]) * rsqrtf(v2[c] + EPS) * g2[c] + bt2[c];
        z2_s[c] = fmaxf(a2, 0.f);
    }
    __syncthreads();

    if (c < 64) {
        float a3 = z2_s[c] * W3[c] + z2_s[c + 64] * W3[c + 64];
#pragma unroll
        for (int o = 32; o >= 1; o >>= 1) a3 += __shfl_xor(a3, o, 64);
        if (c == 0) out[g] = a3 + b3[0];
    }
}

// ---------------------------------------------------------------- launch
extern "C" void kernel_launch(void* const* d_in, const int* in_sizes, int n_in,
                              void* d_out, int out_size, void* d_ws, size_t ws_size,
                              hipStream_t stream) {
    const float* x         = (const float*)d_in[0];
    const int*   ei        = (const int*)d_in[1];
    const int*   src       = ei;
    const int*   dst       = ei + N_EDGES;
    const float* edge_attr = (const float*)d_in[3];
    const float* enc_W     = (const float*)d_in[4];
    const float* enc_b     = (const float*)d_in[5];
    const float* conv_Wl   = (const float*)d_in[6];
    const float* conv_bl   = (const float*)d_in[7];
    const float* conv_Wr   = (const float*)d_in[8];
    const float* conv_br   = (const float*)d_in[9];
    const float* conv_We   = (const float*)d_in[10];
    const float* conv_att  = (const float*)d_in[11];
    const float* conv_bias = (const float*)d_in[12];
    const float* bn_g      = (const float*)d_in[13];
    const float* bn_b      = (const float*)d_in[14];
    const float* bn_m      = (const float*)d_in[15];
    const float* bn_v      = (const float*)d_in[16];
    const float* cls_W1    = (const float*)d_in[17];
    const float* cls_b1    = (const float*)d_in[18];
    const float* cls_g1    = (const float*)d_in[19];
    const float* cls_bt1   = (const float*)d_in[20];
    const float* cls_m1    = (const float*)d_in[21];
    const float* cls_v1    = (const float*)d_in[22];
    const float* cls_W2    = (const float*)d_in[23];
    const float* cls_b2    = (const float*)d_in[24];
    const float* cls_g2    = (const float*)d_in[25];
    const float* cls_bt2   = (const float*)d_in[26];
    const float* cls_m2    = (const float*)d_in[27];
    const float* cls_v2    = (const float*)d_in[28];
    const float* cls_W3    = (const float*)d_in[29];
    const float* cls_b3    = (const float*)d_in[30];
    float* out = (float*)d_out;

    char* ws = (char*)d_ws;
    size_t off = 0;
    auto alloc = [&](size_t bytes) -> void* {
        void* p = ws + off;
        off += (bytes + 255) & ~(size_t)255;
        return p;
    };
    float* h       = (float*)alloc((size_t)N_NODES * 256 * 4);    // 20.5 MB
    u16*   h_bf    = (u16*)alloc((size_t)N_NODES * 256 * 2);      // 10.2 MB
    u16*   xlr_bf  = (u16*)alloc((size_t)N_NODES * 512 * 2);      // 20.5 MB
    float* lattr   = (float*)alloc((size_t)N_NODES * 16 * 4);     // 1.3 MB
    u16*   ea_bf   = (u16*)alloc((size_t)N_E2 * 16 * 2);          // 10.9 MB
    float* alphas  = (float*)alloc((size_t)N_E2 * 4 * 4);         // 5.4 MB
    u16*   x_bf    = (u16*)alloc((size_t)N_NODES * 64 * 2);       // 2.6 MB
    u16*   enc_Wt  = (u16*)alloc((size_t)64 * 256 * 2);           // 32 KB
    u16*   Wtl     = (u16*)alloc((size_t)3 * 65536 * 2);          // 0.4 MB
    u16*   Wtr     = (u16*)alloc((size_t)3 * 65536 * 2);          // 0.4 MB
    u16*   Wef     = (u16*)alloc((size_t)3 * 16 * 64 * 8 * 2);    // 48 KB
    int*   cnt     = (int*)alloc((size_t)N_NODES * 4);
    int*   rowp    = (int*)alloc((size_t)(N_NODES + 1) * 4);
    int*   cursor  = (int*)alloc((size_t)N_NODES * 4);
    int*   csr_src = (int*)alloc((size_t)(N_E2 + 512) * 4);
    int*   csr_dst = (int*)alloc((size_t)(N_E2 + 512) * 4);
    int*   csr_aid = (int*)alloc((size_t)N_E2 * 4);
    int*   part    = (int*)alloc(64 * 4);

    // CSR build
    k_init<<<(N_NODES + 255) / 256, 256, 0, stream>>>(cnt, cursor);
    k_count<<<(N_EDGES + 255) / 256, 256, 0, stream>>>(dst, cnt);
    k_scan1<<<NSCAN, 256, 0, stream>>>(cnt, rowp, part);
    k_scan2<<<1, 1, 0, stream>>>(part, rowp);
    k_scan3<<<NSCAN, 256, 0, stream>>>(rowp, part);
    k_fill<<<(N_E2 + 255) / 256, 256, 0, stream>>>(src, dst, rowp, cursor, csr_src, csr_dst, csr_aid);
    k_pad<<<1, 512, 0, stream>>>(csr_src, csr_dst);
    k_loopattr<<<(N_NODES * 16 + 255) / 256, 256, 0, stream>>>(rowp, csr_aid, edge_attr, lattr);
    k_eacsr<<<(N_E2 * 2 + 255) / 256, 256, 0, stream>>>(csr_aid, edge_attr, lattr, ea_bf);

    // weight / input prep
    k_xbf<<<(N_NODES * 16 + 255) / 256, 256, 0, stream>>>(x, x_bf);
    k_twg<<<dim3(2, 8, 1), 256, 0, stream>>>(enc_W, enc_Wt, 64, 256);
    k_twg<<<dim3(8, 8, 3), 256, 0, stream>>>(conv_Wl, Wtl, 256, 256);
    k_twg<<<dim3(8, 8, 3), 256, 0, stream>>>(conv_Wr, Wtr, 256, 256);
    k_wef<<<12, 256, 0, stream>>>(conv_We, Wef);

    dim3 ggrid((N_NODES + 127) / 128, 4);
    // encoder: h = relu(x @ enc_W + enc_b) via MFMA, emits h fp32 + h_bf
    k_gemm_bf<1><<<ggrid, 256, 0, stream>>>(x_bf, 64, enc_Wt, 64, 64,
                                            enc_b, h_bf, 256, 0, h, N_NODES);

    // 3 GATv2 layers
    int nchunks = (N_E2 + 63) / 64;               // 5313
    int ablocks = (nchunks + CPB - 1) / CPB;      // 665
    for (int i = 0; i < 3; i++) {
        k_gemm_bf<0><<<ggrid, 256, 0, stream>>>(h_bf, 256, Wtl + (size_t)i * 65536, 256, 256,
                                                conv_bl + i * HID, xlr_bf, 512, 0, nullptr, N_NODES);
        k_gemm_bf<0><<<ggrid, 256, 0, stream>>>(h_bf, 256, Wtr + (size_t)i * 65536, 256, 256,
                                                conv_br + i * HID, xlr_bf, 512, 256, nullptr, N_NODES);
        k_alpha3<<<ablocks, 256, 0, stream>>>(
            xlr_bf, ea_bf, csr_src, csr_dst,
            Wef + (size_t)i * 8192, conv_att + (size_t)i * 256, alphas);
        k_aggr<<<N_NODES / 4, 256, 0, stream>>>(
            xlr_bf, alphas, rowp, csr_src,
            conv_bias + (size_t)i * HID,
            bn_g + (size_t)i * HID, bn_b + (size_t)i * HID,
            bn_m + (size_t)i * HID, bn_v + (size_t)i * HID, h, h_bf);
    }

    // fused pooling + classifier
    k_head<<<N_GRAPHS, 256, 0, stream>>>(
        h, cls_W1, cls_b1, cls_g1, cls_bt1, cls_m1, cls_v1,
        cls_W2, cls_b2, cls_g2, cls_bt2, cls_m2, cls_v2,
        cls_W3, cls_b3, out);
}

// Round 8
// 496.156 us; speedup vs baseline: 2.5397x; 1.0003x over previous
//
#include <hip/hip_runtime.h>
#include <hip/hip_bf16.h>

#define N_NODES 20000
#define N_EDGES 320000
#define N_E2    (N_EDGES + N_NODES)   // 340000 edges incl self loops
#define N_GRAPHS 256
#define HID 256
#define EPS 1e-5f
#define NSCAN 20                       // ceil(20000/1024)
#define CPB 8                          // 64-edge chunks per k_alpha3 block

typedef unsigned short u16;
typedef __attribute__((ext_vector_type(8))) short short8;
typedef __attribute__((ext_vector_type(4))) float f32x4;

__device__ __forceinline__ float b2f(u16 u) {
    union { unsigned int i; float f; } v; v.i = ((unsigned int)u) << 16; return v.f;
}
__device__ __forceinline__ u16 f2b(float f) {
    __hip_bfloat16 h = __float2bfloat16(f);   // RNE
    return *reinterpret_cast<u16*>(&h);
}

// ---------------------------------------------------------------- CSR build
__global__ void k_init(int* cnt, int* cursor) {
    int i = blockIdx.x * 256 + threadIdx.x;
    if (i < N_NODES) { cnt[i] = 1; cursor[i] = 0; }  // count starts at 1: self loop
}

__global__ void k_count(const int* __restrict__ dst, int* __restrict__ cnt) {
    int e = blockIdx.x * 256 + threadIdx.x;
    if (e < N_EDGES) atomicAdd(&cnt[dst[e]], 1);
}

__global__ void k_scan1(const int* __restrict__ cnt, int* __restrict__ rowp, int* __restrict__ part) {
    __shared__ int ls[256];
    int b = blockIdx.x, tid = threadIdx.x;
    int base = b * 1024 + tid * 4;
    int c[4]; int s = 0;
#pragma unroll
    for (int u = 0; u < 4; u++) { int i = base + u; c[u] = (i < N_NODES) ? cnt[i] : 0; s += c[u]; }
    ls[tid] = s; __syncthreads();
    for (int off = 1; off < 256; off <<= 1) {
        int v = (tid >= off) ? ls[tid - off] : 0;
        __syncthreads();
        ls[tid] += v;
        __syncthreads();
    }
    int excl = ls[tid] - s;
#pragma unroll
    for (int u = 0; u < 4; u++) { int i = base + u; if (i < N_NODES) rowp[i] = excl; excl += c[u]; }
    if (tid == 255) part[b] = ls[255];
}

__global__ void k_scan2(int* part, int* rowp) {
    int s = 0;
    for (int b = 0; b < NSCAN; b++) { int v = part[b]; part[b] = s; s += v; }
    rowp[N_NODES] = s;   // == N_E2
}

__global__ void k_scan3(int* __restrict__ rowp, const int* __restrict__ part) {
    int b = blockIdx.x, tid = threadIdx.x;
    int add = part[b];
    int base = b * 1024 + tid * 4;
#pragma unroll
    for (int u = 0; u < 4; u++) { int i = base + u; if (i < N_NODES) rowp[i] += add; }
}

__global__ void k_fill(const int* __restrict__ src, const int* __restrict__ dst,
                       const int* __restrict__ rowp, int* __restrict__ cursor,
                       int* __restrict__ csr_src, int* __restrict__ csr_dst,
                       int* __restrict__ csr_aid) {
    int t = blockIdx.x * 256 + threadIdx.x;
    if (t < N_EDGES) {
        int d = dst[t];
        int pos = atomicAdd(&cursor[d], 1);
        int w = rowp[d] + pos;
        csr_src[w] = src[t];
        csr_dst[w] = d;
        csr_aid[w] = t;
    } else if (t < N_E2) {
        int n = t - N_EDGES;
        int pos = atomicAdd(&cursor[n], 1);
        int w = rowp[n] + pos;
        csr_src[w] = n;
        csr_dst[w] = n;
        csr_aid[w] = N_EDGES + n;   // self loop, attr = loop_attr[n]
    }
}

// zero the +512 padding of csr_src/csr_dst
__global__ void k_pad(int* csr_src, int* csr_dst) {
    int i = threadIdx.x;   // 512 threads
    csr_src[N_E2 + i] = 0;
    csr_dst[N_E2 + i] = 0;
}

// loop_attr[n][j] = mean over incoming (original) edges of edge_attr
__global__ void k_loopattr(const int* __restrict__ rowp, const int* __restrict__ csr_aid,
                           const float* __restrict__ edge_attr, float* __restrict__ lattr) {
    int t = blockIdx.x * 256 + threadIdx.x;
    if (t >= N_NODES * 16) return;
    int n = t >> 4, j = t & 15;
    int st = rowp[n], en = rowp[n + 1];
    float s = 0.f;
    for (int i = st; i < en; i++) {
        int aid = csr_aid[i];
        if (aid < N_EDGES) s += edge_attr[(size_t)aid * 16 + j];
    }
    float deg = (float)(en - st - 1);
    lattr[(size_t)n * 16 + j] = s / fmaxf(deg, 1.0f);
}

// ea_bf[e][0:16] = bf16(edge_attr[csr_aid[e]]) (or loop_attr), CSR order — built once.
__global__ void k_eacsr(const int* __restrict__ csr_aid,
                        const float* __restrict__ edge_attr,
                        const float* __restrict__ lattr,
                        u16* __restrict__ ea_bf) {
    int t = blockIdx.x * 256 + threadIdx.x;   // one thread per 8 attrs
    if (t >= N_E2 * 2) return;
    int e = t >> 1, hf = t & 1;
    int aid = csr_aid[e];
    const float* ap = (aid < N_EDGES) ? edge_attr + (size_t)aid * 16
                                      : lattr + (size_t)(aid - N_EDGES) * 16;
    float4 a = ((const float4*)ap)[hf * 2];
    float4 b = ((const float4*)ap)[hf * 2 + 1];
    u16 v[8] = {f2b(a.x), f2b(a.y), f2b(a.z), f2b(a.w),
                f2b(b.x), f2b(b.y), f2b(b.z), f2b(b.w)};
    *(uint4*)(ea_bf + (size_t)t * 8) = *(uint4*)v;
}

// We[layer][16][256] fp32 -> fragment layout Wef[layer][nt][lane][8] bf16 (K padded to 32)
// lane: idx = lane&15 (channel within nt), k-chunk = lane>>4
__global__ void k_wef(const float* __restrict__ We, u16* __restrict__ Wef) {
    int t = blockIdx.x * 256 + threadIdx.x;   // 3*16*64 = 3072
    if (t >= 3 * 16 * 64) return;
    int layer = t >> 10, r = t & 1023;
    int nt = r >> 6, l = r & 63;
    int kc = l >> 4, ch = nt * 16 + (l & 15);
    u16 v[8];
#pragma unroll
    for (int q = 0; q < 8; q++) {
        float x = 0.f;
        if (kc < 2) x = We[(size_t)layer * 4096 + (size_t)(kc * 8 + q) * 256 + ch];
        v[q] = f2b(x);
    }
    *(uint4*)(Wef + (size_t)t * 8) = *(uint4*)v;
}

// x (fp32) -> bf16
__global__ void k_xbf(const float* __restrict__ x, u16* __restrict__ xb) {
    int t = blockIdx.x * 256 + threadIdx.x;   // N*64/4 threads
    if (t >= N_NODES * 16) return;
    float4 v = ((const float4*)x)[t];
    u16 o[4] = {f2b(v.x), f2b(v.y), f2b(v.z), f2b(v.w)};
    *(ushort4*)(xb + (size_t)t * 4) = *(ushort4*)o;
}

// W[layer][K][N] fp32 -> Wt[layer][N][K] bf16 (32x32 LDS tile transpose)
__global__ void k_twg(const float* __restrict__ W, u16* __restrict__ Wt, int K, int N) {
    __shared__ float tile[32][33];
    int layer = blockIdx.z;
    const float* Wp = W + (size_t)layer * K * N;
    u16* Wtp = Wt + (size_t)layer * K * N;
    int bk = blockIdx.x * 32, bn = blockIdx.y * 32;
    int tx = threadIdx.x & 31, ty = threadIdx.x >> 5; // 32 x 8
#pragma unroll
    for (int q = 0; q < 4; q++) {
        int k = bk + ty + q * 8;
        tile[ty + q * 8][tx] = Wp[(size_t)k * N + bn + tx];
    }
    __syncthreads();
#pragma unroll
    for (int q = 0; q < 4; q++) {
        int n = bn + ty + q * 8;
        Wtp[(size_t)n * K + bk + tx] = f2b(tile[tx][ty + q * 8]);
    }
}

// ---------------------------------------------------------------- GEMM bf16 MFMA
template <int EPI>
__global__ __launch_bounds__(256) void k_gemm_bf(
    const u16* __restrict__ A, int lda,
    const u16* __restrict__ Bt, int ldb, int K,
    const float* __restrict__ bias,
    u16* __restrict__ Cbf, int ldc, int coff,
    float* __restrict__ Cf, int M)
{
    __shared__ __align__(16) u16 As[128 * 40];   // [128][32+8]
    __shared__ __align__(16) u16 Bs[64 * 40];    // [64][32+8]
    int tid = threadIdx.x;
    int lane = tid & 63, w = tid >> 6;
    int m0 = blockIdx.x * 128, n0 = blockIdx.y * 64;

    f32x4 acc[2][4];
#pragma unroll
    for (int i = 0; i < 2; i++)
#pragma unroll
        for (int j = 0; j < 4; j++) acc[i][j] = (f32x4){0.f, 0.f, 0.f, 0.f};

    int srow = tid >> 2, skc = (tid & 3) * 8;    // staging: row, k-chunk
    int lr = lane & 15, lk = (lane >> 4) * 8;

    int ktiles = K >> 5;
    for (int kt = 0; kt < ktiles; kt++) {
        if (kt) __syncthreads();
#pragma unroll
        for (int q = 0; q < 2; q++) {
            int arow = q * 64 + srow;
            uint4 av = make_uint4(0, 0, 0, 0);
            if (m0 + arow < M)
                av = *(const uint4*)(A + (size_t)(m0 + arow) * lda + kt * 32 + skc);
            *(uint4*)&As[arow * 40 + skc] = av;
        }
        {
            uint4 bv = *(const uint4*)(Bt + (size_t)(n0 + srow) * ldb + kt * 32 + skc);
            *(uint4*)&Bs[srow * 40 + skc] = bv;
        }
        __syncthreads();

        short8 af0 = *(const short8*)&As[(w * 32 + lr) * 40 + lk];
        short8 af1 = *(const short8*)&As[(w * 32 + 16 + lr) * 40 + lk];
        short8 bf[4];
#pragma unroll
        for (int nt = 0; nt < 4; nt++)
            bf[nt] = *(const short8*)&Bs[(nt * 16 + lr) * 40 + lk];
#pragma unroll
        for (int nt = 0; nt < 4; nt++) {
            acc[0][nt] = __builtin_amdgcn_mfma_f32_16x16x32_bf16(af0, bf[nt], acc[0][nt], 0, 0, 0);
            acc[1][nt] = __builtin_amdgcn_mfma_f32_16x16x32_bf16(af1, bf[nt], acc[1][nt], 0, 0, 0);
        }
    }

    // C/D layout: col = lane&15, row = (lane>>4)*4 + j
    int rq = (lane >> 4) * 4;
#pragma unroll
    for (int nt = 0; nt < 4; nt++) {
        int col = n0 + nt * 16 + lr;
        float bv = bias[col];
#pragma unroll
        for (int mt = 0; mt < 2; mt++) {
#pragma unroll
            for (int j = 0; j < 4; j++) {
                int row = m0 + w * 32 + mt * 16 + rq + j;
                if (row < M) {
                    float v = acc[mt][nt][j] + bv;
                    if (EPI == 1) {
                        v = fmaxf(v, 0.f);
                        Cf[(size_t)row * ldc + col] = v;
                        Cbf[(size_t)row * ldc + col] = f2b(v);
                    } else {
                        Cbf[(size_t)row * ldc + coff + col] = f2b(v);
                    }
                }
            }
        }
    }
}

// ---------------------------------------------------------------- GATv2 pass 1: alpha per edge
// SWAPPED operands: D = Wef_nt · ea  -> D row = channel-in-nt (eg*4+j), col = edge (t16).
// Each lane: ONE edge (t16), 4 contiguous channels per nt -> ushort4 xl/xr loads.
__global__ __launch_bounds__(256) void k_alpha3(
    const u16* __restrict__ xlr,        // [N,512] bf16 xl|xr
    const u16* __restrict__ ea_bf,      // [E2,16] bf16 CSR order
    const int* __restrict__ csr_src, const int* __restrict__ csr_dst,
    const u16* __restrict__ Wef,        // [16][64][8] bf16 fragments, this layer
    const float* __restrict__ att,      // [256]
    float* __restrict__ alpha)          // [E2,4]
{
    __shared__ __align__(16) u16 wef_s[16 * 64 * 8];   // 16 KB
    __shared__ float att_s[256];
    int tid = threadIdx.x, lane = tid & 63, w = tid >> 6;
    {
        const uint4* s = (const uint4*)Wef;
        uint4* d = (uint4*)wef_s;
#pragma unroll
        for (int q = 0; q < 4; q++) d[q * 256 + tid] = s[q * 256 + tid];
        att_s[tid] = att[tid];
    }
    int eg = lane >> 4, t16 = lane & 15;
    __syncthreads();

    for (int it = 0; it < CPB; it++) {
        int chunk = blockIdx.x * CPB + it;
        if (chunk * 64 >= N_E2) break;
        int e_base = chunk * 64 + w * 16;
        int e_raw = e_base + t16;
        int e = (e_raw < N_E2) ? e_raw : N_E2 - 1;

        // ea fragment (B operand): lane provides ea[edge=t16][k = eg*8..+8] (eg 2,3 zero-pad)
        short8 eafrag = {0, 0, 0, 0, 0, 0, 0, 0};
        if (eg < 2) eafrag = *(const short8*)(ea_bf + (size_t)e * 16 + eg * 8);
        int s = csr_src[e], d = csr_dst[e];
        const u16* xlp = xlr + (size_t)s * 512;
        const u16* xrp = xlr + (size_t)d * 512 + 256;

        float pj = 0.f;
#pragma unroll
        for (int nt = 0; nt < 16; nt++) {
            short8 wfrag = *(const short8*)&wef_s[(nt * 64 + lane) * 8];
            f32x4 D = __builtin_amdgcn_mfma_f32_16x16x32_bf16(
                wfrag, eafrag, (f32x4){0.f, 0.f, 0.f, 0.f}, 0, 0, 0);
            int ch0 = nt * 16 + eg * 4;
            ushort4 xl4 = *(const ushort4*)(xlp + ch0);
            ushort4 xr4 = *(const ushort4*)(xrp + ch0);
            float4 at4 = *(const float4*)&att_s[ch0];
#pragma unroll
            for (int j = 0; j < 4; j++) {
                float z = D[j] + b2f(((const u16*)&xl4)[j]) + b2f(((const u16*)&xr4)[j]);
                z = fmaxf(z, 0.f) + 0.2f * fminf(z, 0.f);   // leaky_relu 0.2
                pj = fmaf(z, ((const float*)&at4)[j], pj);
            }
            if ((nt & 3) == 3) {
                float p = pj;
                p += __shfl_xor(p, 16, 64);   // sum across eg
                p += __shfl_xor(p, 32, 64);
                if (eg == 0 && e_raw < N_E2) alpha[(size_t)e_raw * 4 + (nt >> 2)] = p;
                pj = 0.f;
            }
        }
    }
}

// ---------------------------------------------------------------- GATv2 pass 2: softmax + aggregate
__global__ __launch_bounds__(256) void k_aggr(
    const u16* __restrict__ xlr, const float* __restrict__ alpha,
    const int* __restrict__ rowp, const int* __restrict__ csr_src,
    const float* __restrict__ cbias,
    const float* __restrict__ bng, const float* __restrict__ bnb,
    const float* __restrict__ bnm, const float* __restrict__ bnv,
    float* __restrict__ h, u16* __restrict__ h_bf)   // [N,256] in/out + bf16 copy
{
    __shared__ float lex[4][64][4];      // [wave][edge-in-chunk][head]
    __shared__ int   lsrc[4][64];
    int lane = threadIdx.x & 63;
    int wv = threadIdx.x >> 6;
    int n = blockIdx.x * 4 + wv;
    if (n >= N_NODES) return;
    int st = rowp[n], en = rowp[n + 1];
    int hsel = lane >> 4;                // head owning channels c0..c0+3
    int c0 = lane * 4;

    float m4[4]  = {-3.0e38f, -3.0e38f, -3.0e38f, -3.0e38f};
    float den4[4] = {0.f, 0.f, 0.f, 0.f};
    float acc[4]  = {0.f, 0.f, 0.f, 0.f};

    for (int cs = st; cs < en; cs += 64) {
        int cnt = min(64, en - cs);
        float a4[4];
        int s_i = 0;
        if (lane < cnt) {
            float4 v = *(const float4*)(alpha + (size_t)(cs + lane) * 4);
            a4[0] = v.x; a4[1] = v.y; a4[2] = v.z; a4[3] = v.w;
            s_i = csr_src[cs + lane];
        } else {
            a4[0] = a4[1] = a4[2] = a4[3] = -3.0e38f;
        }
        float cm[4] = {a4[0], a4[1], a4[2], a4[3]};
#pragma unroll
        for (int o = 32; o >= 1; o >>= 1)
#pragma unroll
            for (int u = 0; u < 4; u++) cm[u] = fmaxf(cm[u], __shfl_xor(cm[u], o, 64));
        float sc[4];
#pragma unroll
        for (int u = 0; u < 4; u++) {
            float nm = fmaxf(m4[u], cm[u]);
            sc[u] = __expf(m4[u] - nm);
            den4[u] *= sc[u];
            m4[u] = nm;
        }
        float scl = sc[hsel];
#pragma unroll
        for (int u = 0; u < 4; u++) acc[u] *= scl;
        float ex[4];
#pragma unroll
        for (int u = 0; u < 4; u++) ex[u] = (lane < cnt) ? __expf(a4[u] - m4[u]) : 0.f;
        float sx[4] = {ex[0], ex[1], ex[2], ex[3]};
#pragma unroll
        for (int o = 32; o >= 1; o >>= 1)
#pragma unroll
            for (int u = 0; u < 4; u++) sx[u] += __shfl_xor(sx[u], o, 64);
#pragma unroll
        for (int u = 0; u < 4; u++) den4[u] += sx[u];
        *(float4*)&lex[wv][lane][0] = make_float4(ex[0], ex[1], ex[2], ex[3]);
        lsrc[wv][lane] = s_i;
        // weighted gather-sum: 8 row-gathers (8B bf16x4) in flight per step
        int j = 0;
        for (; j + 8 <= cnt; j += 8) {
            float a[8]; int sj[8];
#pragma unroll
            for (int q = 0; q < 8; q++) { a[q] = lex[wv][j + q][hsel]; sj[q] = lsrc[wv][j + q]; }
            ushort4 xg[8];
#pragma unroll
            for (int q = 0; q < 8; q++) xg[q] = *(const ushort4*)(xlr + (size_t)sj[q] * 512 + c0);
#pragma unroll
            for (int q = 0; q < 8; q++) {
                acc[0] += a[q] * b2f(((const u16*)&xg[q])[0]);
                acc[1] += a[q] * b2f(((const u16*)&xg[q])[1]);
                acc[2] += a[q] * b2f(((const u16*)&xg[q])[2]);
                acc[3] += a[q] * b2f(((const u16*)&xg[q])[3]);
            }
        }
        for (; j < cnt; j++) {
            float a = lex[wv][j][hsel];
            int sj = lsrc[wv][j];
            ushort4 xg = *(const ushort4*)(xlr + (size_t)sj * 512 + c0);
            acc[0] += a * b2f(((const u16*)&xg)[0]);
            acc[1] += a * b2f(((const u16*)&xg)[1]);
            acc[2] += a * b2f(((const u16*)&xg)[2]);
            acc[3] += a * b2f(((const u16*)&xg)[3]);
        }
    }

    float dd = den4[hsel];
    float4 hin = *(const float4*)(h + (size_t)n * 256 + c0);
    float4 cb  = *(const float4*)(cbias + c0);
    float4 gg  = *(const float4*)(bng + c0);
    float4 bb  = *(const float4*)(bnb + c0);
    float4 mm  = *(const float4*)(bnm + c0);
    float4 vv  = *(const float4*)(bnv + c0);
    float hi[4] = {hin.x, hin.y, hin.z, hin.w};
    float cbv[4] = {cb.x, cb.y, cb.z, cb.w};
    float gv[4] = {gg.x, gg.y, gg.z, gg.w};
    float bv[4] = {bb.x, bb.y, bb.z, bb.w};
    float mv[4] = {mm.x, mm.y, mm.z, mm.w};
    float vvv[4] = {vv.x, vv.y, vv.z, vv.w};
    float4 o;
    ushort4 ob;
#pragma unroll
    for (int u = 0; u < 4; u++) {
        float val = acc[u] / dd + cbv[u];
        val = (val - mv[u]) * rsqrtf(vvv[u] + EPS) * gv[u] + bv[u];
        val = fmaxf(val, 0.f) + hi[u];
        ((float*)&o)[u] = val;
        ((u16*)&ob)[u] = f2b(val);
    }
    *(float4*)(h + (size_t)n * 256 + c0) = o;
    *(ushort4*)(h_bf + (size_t)n * 256 + c0) = ob;
}

// ---------------------------------------------------------------- pooling partials (parallel)
// grid (G, 8): block (g,p) pools its row sub-range -> psum/pmax[(g*8+p)*256+c]
__global__ __launch_bounds__(256) void k_poolp(
    const float* __restrict__ h, float* __restrict__ psum, float* __restrict__ pmax)
{
    int g = blockIdx.x, p = blockIdx.y, c = threadIdx.x;
    int gst = (g * N_NODES + N_GRAPHS - 1) / N_GRAPHS;
    int gen = ((g + 1) * N_NODES + N_GRAPHS - 1) / N_GRAPHS;
    int len = gen - gst;
    int cst = gst + (len * p) / 8;
    int cen = gst + (len * (p + 1)) / 8;
    float s = 0.f, mx = -3.0e38f;
    for (int i = cst; i < cen; i++) {
        float v = h[(size_t)i * 256 + c];
        s += v;
        mx = fmaxf(mx, v);
    }
    psum[(size_t)(g * 8 + p) * 256 + c] = s;
    pmax[(size_t)(g * 8 + p) * 256 + c] = mx;
}

// ---------------------------------------------------------------- fused classifier head
__global__ __launch_bounds__(256) void k_head(
    const float* __restrict__ psum, const float* __restrict__ pmax,
    const float* __restrict__ W1, const float* __restrict__ b1,
    const float* __restrict__ g1, const float* __restrict__ bt1,
    const float* __restrict__ m1, const float* __restrict__ v1,
    const float* __restrict__ W2, const float* __restrict__ b2,
    const float* __restrict__ g2, const float* __restrict__ bt2,
    const float* __restrict__ m2, const float* __restrict__ v2,
    const float* __restrict__ W3, const float* __restrict__ b3,
    float* __restrict__ out)
{
    __shared__ float xp_s[512];
    __shared__ float z1_s[256];
    __shared__ float z2p[2][128];
    __shared__ float z2_s[128];
    int g = blockIdx.x, c = threadIdx.x;
    int gst = (g * N_NODES + N_GRAPHS - 1) / N_GRAPHS;
    int gen = ((g + 1) * N_NODES + N_GRAPHS - 1) / N_GRAPHS;

    float s = 0.f, mx = -3.0e38f;
#pragma unroll
    for (int p = 0; p < 8; p++) {
        s += psum[(size_t)(g * 8 + p) * 256 + c];
        mx = fmaxf(mx, pmax[(size_t)(g * 8 + p) * 256 + c]);
    }
    xp_s[c] = s / (float)(gen - gst);
    xp_s[256 + c] = mx;
    __syncthreads();

    // z1: 4 independent accumulators for MLP on the W1 stream
    float a0 = 0.f, a1 = 0.f, a2 = 0.f, a3 = 0.f;
#pragma unroll 4
    for (int k = 0; k < 512; k += 4) {
        a0 = fmaf(xp_s[k + 0], W1[(k + 0) * 256 + c], a0);
        a1 = fmaf(xp_s[k + 1], W1[(k + 1) * 256 + c], a1);
        a2 = fmaf(xp_s[k + 2], W1[(k + 2) * 256 + c], a2);
        a3 = fmaf(xp_s[k + 3], W1[(k + 3) * 256 + c], a3);
    }
    float a = (a0 + a1) + (a2 + a3) + b1[c];
    a = (a - m1[c]) * rsqrtf(v1[c] + EPS) * g1[c] + bt1[c];
    z1_s[c] = fmaxf(a, 0.f);
    __syncthreads();

    // z2: split-K across 256 threads (2 halves x 128 outputs)
    {
        int c2 = c & 127, half = c >> 7;
        float b_acc = 0.f;
#pragma unroll 4
        for (int k = 0; k < 128; k++) {
            int kk = half * 128 + k;
            b_acc = fmaf(z1_s[kk], W2[kk * 128 + c2], b_acc);
        }
        z2p[half][c2] = b_acc;
    }
    __syncthreads();
    if (c < 128) {
        float a2v = z2p[0][c] + z2p[1][c] + b2[c];
        a2v = (a2v - m2[c]) * rsqrtf(v2[c] + EPS) * g2[c] + bt2[c];
        z2_s[c] = fmaxf(a2v, 0.f);
    }
    __syncthreads();

    if (c < 64) {
        float a3v = z2_s[c] * W3[c] + z2_s[c + 64] * W3[c + 64];
#pragma unroll
        for (int o = 32; o >= 1; o >>= 1) a3v += __shfl_xor(a3v, o, 64);
        if (c == 0) out[g] = a3v + b3[0];
    }
}

// ---------------------------------------------------------------- launch
extern "C" void kernel_launch(void* const* d_in, const int* in_sizes, int n_in,
                              void* d_out, int out_size, void* d_ws, size_t ws_size,
                              hipStream_t stream) {
    const float* x         = (const float*)d_in[0];
    const int*   ei        = (const int*)d_in[1];
    const int*   src       = ei;
    const int*   dst       = ei + N_EDGES;
    const float* edge_attr = (const float*)d_in[3];
    const float* enc_W     = (const float*)d_in[4];
    const float* enc_b     = (const float*)d_in[5];
    const float* conv_Wl   = (const float*)d_in[6];
    const float* conv_bl   = (const float*)d_in[7];
    const float* conv_Wr   = (const float*)d_in[8];
    const float* conv_br   = (const float*)d_in[9];
    const float* conv_We   = (const float*)d_in[10];
    const float* conv_att  = (const float*)d_in[11];
    const float* conv_bias = (const float*)d_in[12];
    const float* bn_g      = (const float*)d_in[13];
    const float* bn_b      = (const float*)d_in[14];
    const float* bn_m      = (const float*)d_in[15];
    const float* bn_v      = (const float*)d_in[16];
    const float* cls_W1    = (const float*)d_in[17];
    const float* cls_b1    = (const float*)d_in[18];
    const float* cls_g1    = (const float*)d_in[19];
    const float* cls_bt1   = (const float*)d_in[20];
    const float* cls_m1    = (const float*)d_in[21];
    const float* cls_v1    = (const float*)d_in[22];
    const float* cls_W2    = (const float*)d_in[23];
    const float* cls_b2    = (const float*)d_in[24];
    const float* cls_g2    = (const float*)d_in[25];
    const float* cls_bt2   = (const float*)d_in[26];
    const float* cls_m2    = (const float*)d_in[27];
    const float* cls_v2    = (const float*)d_in[28];
    const float* cls_W3    = (const float*)d_in[29];
    const float* cls_b3    = (const float*)d_in[30];
    float* out = (float*)d_out;

    char* ws = (char*)d_ws;
    size_t off = 0;
    auto alloc = [&](size_t bytes) -> void* {
        void* p = ws + off;
        off += (bytes + 255) & ~(size_t)255;
        return p;
    };
    float* h       = (float*)alloc((size_t)N_NODES * 256 * 4);    // 20.5 MB
    u16*   h_bf    = (u16*)alloc((size_t)N_NODES * 256 * 2);      // 10.2 MB
    u16*   xlr_bf  = (u16*)alloc((size_t)N_NODES * 512 * 2);      // 20.5 MB
    float* lattr   = (float*)alloc((size_t)N_NODES * 16 * 4);     // 1.3 MB
    u16*   ea_bf   = (u16*)alloc((size_t)N_E2 * 16 * 2);          // 10.9 MB
    float* alphas  = (float*)alloc((size_t)N_E2 * 4 * 4);         // 5.4 MB
    u16*   x_bf    = (u16*)alloc((size_t)N_NODES * 64 * 2);       // 2.6 MB
    u16*   enc_Wt  = (u16*)alloc((size_t)64 * 256 * 2);           // 32 KB
    u16*   Wtl     = (u16*)alloc((size_t)3 * 65536 * 2);          // 0.4 MB
    u16*   Wtr     = (u16*)alloc((size_t)3 * 65536 * 2);          // 0.4 MB
    u16*   Wef     = (u16*)alloc((size_t)3 * 16 * 64 * 8 * 2);    // 48 KB
    float* psum    = (float*)alloc((size_t)N_GRAPHS * 8 * 256 * 4); // 2 MB
    float* pmax    = (float*)alloc((size_t)N_GRAPHS * 8 * 256 * 4); // 2 MB
    int*   cnt     = (int*)alloc((size_t)N_NODES * 4);
    int*   rowp    = (int*)alloc((size_t)(N_NODES + 1) * 4);
    int*   cursor  = (int*)alloc((size_t)N_NODES * 4);
    int*   csr_src = (int*)alloc((size_t)(N_E2 + 512) * 4);
    int*   csr_dst = (int*)alloc((size_t)(N_E2 + 512) * 4);
    int*   csr_aid = (int*)alloc((size_t)N_E2 * 4);
    int*   part    = (int*)alloc(64 * 4);

    // CSR build
    k_init<<<(N_NODES + 255) / 256, 256, 0, stream>>>(cnt, cursor);
    k_count<<<(N_EDGES + 255) / 256, 256, 0, stream>>>(dst, cnt);
    k_scan1<<<NSCAN, 256, 0, stream>>>(cnt, rowp, part);
    k_scan2<<<1, 1, 0, stream>>>(part, rowp);
    k_scan3<<<NSCAN, 256, 0, stream>>>(rowp, part);
    k_fill<<<(N_E2 + 255) / 256, 256, 0, stream>>>(src, dst, rowp, cursor, csr_src, csr_dst, csr_aid);
    k_pad<<<1, 512, 0, stream>>>(csr_src, csr_dst);
    k_loopattr<<<(N_NODES * 16 + 255) / 256, 256, 0, stream>>>(rowp, csr_aid, edge_attr, lattr);
    k_eacsr<<<(N_E2 * 2 + 255) / 256, 256, 0, stream>>>(csr_aid, edge_attr, lattr, ea_bf);

    // weight / input prep
    k_xbf<<<(N_NODES * 16 + 255) / 256, 256, 0, stream>>>(x, x_bf);
    k_twg<<<dim3(2, 8, 1), 256, 0, stream>>>(enc_W, enc_Wt, 64, 256);
    k_twg<<<dim3(8, 8, 3), 256, 0, stream>>>(conv_Wl, Wtl, 256, 256);
    k_twg<<<dim3(8, 8, 3), 256, 0, stream>>>(conv_Wr, Wtr, 256, 256);
    k_wef<<<12, 256, 0, stream>>>(conv_We, Wef);

    dim3 ggrid((N_NODES + 127) / 128, 4);
    // encoder: h = relu(x @ enc_W + enc_b) via MFMA, emits h fp32 + h_bf
    k_gemm_bf<1><<<ggrid, 256, 0, stream>>>(x_bf, 64, enc_Wt, 64, 64,
                                            enc_b, h_bf, 256, 0, h, N_NODES);

    // 3 GATv2 layers
    int nchunks = (N_E2 + 63) / 64;               // 5313
    int ablocks = (nchunks + CPB - 1) / CPB;      // 665
    for (int i = 0; i < 3; i++) {
        k_gemm_bf<0><<<ggrid, 256, 0, stream>>>(h_bf, 256, Wtl + (size_t)i * 65536, 256, 256,
                                                conv_bl + i * HID, xlr_bf, 512, 0, nullptr, N_NODES);
        k_gemm_bf<0><<<ggrid, 256, 0, stream>>>(h_bf, 256, Wtr + (size_t)i * 65536, 256, 256,
                                                conv_br + i * HID, xlr_bf, 512, 256, nullptr, N_NODES);
        k_alpha3<<<ablocks, 256, 0, stream>>>(
            xlr_bf, ea_bf, csr_src, csr_dst,
            Wef + (size_t)i * 8192, conv_att + (size_t)i * 256, alphas);
        k_aggr<<<N_NODES / 4, 256, 0, stream>>>(
            xlr_bf, alphas, rowp, csr_src,
            conv_bias + (size_t)i * HID,
            bn_g + (size_t)i * HID, bn_b + (size_t)i * HID,
            bn_m + (size_t)i * HID, bn_v + (size_t)i * HID, h, h_bf);
    }

    // pooling partials + fused classifier
    k_poolp<<<dim3(N_GRAPHS, 8), 256, 0, stream>>>(h, psum, pmax);
    k_head<<<N_GRAPHS, 256, 0, stream>>>(
        psum, pmax, cls_W1, cls_b1, cls_g1, cls_bt1, cls_m1, cls_v1,
        cls_W2, cls_b2, cls_g2, cls_bt2, cls_m2, cls_v2,
        cls_W3, cls_b3, out);
}

// Round 9
// 481.728 us; speedup vs baseline: 2.6158x; 1.0300x over previous
//
#include <hip/hip_runtime.h>
#include <hip/hip_bf16.h>

#define N_NODES 20000
#define N_EDGES 320000
#define N_E2    (N_EDGES + N_NODES)   // 340000 edges incl self loops
#define N_GRAPHS 256
#define HID 256
#define EPS 1e-5f
#define NSCAN 20                       // ceil(20000/1024)
#define CPB 4                          // 64-edge chunks per k_alpha3 block

typedef unsigned short u16;
typedef __attribute__((ext_vector_type(8))) short short8;
typedef __attribute__((ext_vector_type(4))) float f32x4;

__device__ __forceinline__ float b2f(u16 u) {
    union { unsigned int i; float f; } v; v.i = ((unsigned int)u) << 16; return v.f;
}
__device__ __forceinline__ u16 f2b(float f) {
    __hip_bfloat16 h = __float2bfloat16(f);   // RNE
    return *reinterpret_cast<u16*>(&h);
}

// ---------------------------------------------------------------- CSR build
__global__ void k_init(int* cnt, int* cursor) {
    int i = blockIdx.x * 256 + threadIdx.x;
    if (i < N_NODES) { cnt[i] = 1; cursor[i] = 0; }  // count starts at 1: self loop
}

__global__ void k_count(const int* __restrict__ dst, int* __restrict__ cnt) {
    int e = blockIdx.x * 256 + threadIdx.x;
    if (e < N_EDGES) atomicAdd(&cnt[dst[e]], 1);
}

__global__ void k_scan1(const int* __restrict__ cnt, int* __restrict__ rowp, int* __restrict__ part) {
    __shared__ int ls[256];
    int b = blockIdx.x, tid = threadIdx.x;
    int base = b * 1024 + tid * 4;
    int c[4]; int s = 0;
#pragma unroll
    for (int u = 0; u < 4; u++) { int i = base + u; c[u] = (i < N_NODES) ? cnt[i] : 0; s += c[u]; }
    ls[tid] = s; __syncthreads();
    for (int off = 1; off < 256; off <<= 1) {
        int v = (tid >= off) ? ls[tid - off] : 0;
        __syncthreads();
        ls[tid] += v;
        __syncthreads();
    }
    int excl = ls[tid] - s;
#pragma unroll
    for (int u = 0; u < 4; u++) { int i = base + u; if (i < N_NODES) rowp[i] = excl; excl += c[u]; }
    if (tid == 255) part[b] = ls[255];
}

__global__ void k_scan2(int* part, int* rowp) {
    int s = 0;
    for (int b = 0; b < NSCAN; b++) { int v = part[b]; part[b] = s; s += v; }
    rowp[N_NODES] = s;   // == N_E2
}

__global__ void k_scan3(int* __restrict__ rowp, const int* __restrict__ part) {
    int b = blockIdx.x, tid = threadIdx.x;
    int add = part[b];
    int base = b * 1024 + tid * 4;
#pragma unroll
    for (int u = 0; u < 4; u++) { int i = base + u; if (i < N_NODES) rowp[i] += add; }
}

__global__ void k_fill(const int* __restrict__ src, const int* __restrict__ dst,
                       const int* __restrict__ rowp, int* __restrict__ cursor,
                       int* __restrict__ csr_src, int* __restrict__ csr_dst,
                       int* __restrict__ csr_aid) {
    int t = blockIdx.x * 256 + threadIdx.x;
    if (t < N_EDGES) {
        int d = dst[t];
        int pos = atomicAdd(&cursor[d], 1);
        int w = rowp[d] + pos;
        csr_src[w] = src[t];
        csr_dst[w] = d;
        csr_aid[w] = t;
    } else if (t < N_E2) {
        int n = t - N_EDGES;
        int pos = atomicAdd(&cursor[n], 1);
        int w = rowp[n] + pos;
        csr_src[w] = n;
        csr_dst[w] = n;
        csr_aid[w] = N_EDGES + n;   // self loop, attr = loop_attr[n]
    }
}

// zero the +512 padding of csr_src/csr_dst
__global__ void k_pad(int* csr_src, int* csr_dst) {
    int i = threadIdx.x;   // 512 threads
    csr_src[N_E2 + i] = 0;
    csr_dst[N_E2 + i] = 0;
}

// loop_attr[n][j] = mean over incoming (original) edges of edge_attr
__global__ void k_loopattr(const int* __restrict__ rowp, const int* __restrict__ csr_aid,
                           const float* __restrict__ edge_attr, float* __restrict__ lattr) {
    int t = blockIdx.x * 256 + threadIdx.x;
    if (t >= N_NODES * 16) return;
    int n = t >> 4, j = t & 15;
    int st = rowp[n], en = rowp[n + 1];
    float s = 0.f;
    for (int i = st; i < en; i++) {
        int aid = csr_aid[i];
        if (aid < N_EDGES) s += edge_attr[(size_t)aid * 16 + j];
    }
    float deg = (float)(en - st - 1);
    lattr[(size_t)n * 16 + j] = s / fmaxf(deg, 1.0f);
}

// ea_bf[e][0:16] = bf16(edge_attr[csr_aid[e]]) (or loop_attr), CSR order — built once.
__global__ void k_eacsr(const int* __restrict__ csr_aid,
                        const float* __restrict__ edge_attr,
                        const float* __restrict__ lattr,
                        u16* __restrict__ ea_bf) {
    int t = blockIdx.x * 256 + threadIdx.x;   // one thread per 8 attrs
    if (t >= N_E2 * 2) return;
    int e = t >> 1, hf = t & 1;
    int aid = csr_aid[e];
    const float* ap = (aid < N_EDGES) ? edge_attr + (size_t)aid * 16
                                      : lattr + (size_t)(aid - N_EDGES) * 16;
    float4 a = ((const float4*)ap)[hf * 2];
    float4 b = ((const float4*)ap)[hf * 2 + 1];
    u16 v[8] = {f2b(a.x), f2b(a.y), f2b(a.z), f2b(a.w),
                f2b(b.x), f2b(b.y), f2b(b.z), f2b(b.w)};
    *(uint4*)(ea_bf + (size_t)t * 8) = *(uint4*)v;
}

// We[layer][16][256] fp32 -> fragment layout Wef[layer][nt][lane][8] bf16 (K padded to 32)
__global__ void k_wef(const float* __restrict__ We, u16* __restrict__ Wef) {
    int t = blockIdx.x * 256 + threadIdx.x;   // 3*16*64 = 3072
    if (t >= 3 * 16 * 64) return;
    int layer = t >> 10, r = t & 1023;
    int nt = r >> 6, l = r & 63;
    int kc = l >> 4, ch = nt * 16 + (l & 15);
    u16 v[8];
#pragma unroll
    for (int q = 0; q < 8; q++) {
        float x = 0.f;
        if (kc < 2) x = We[(size_t)layer * 4096 + (size_t)(kc * 8 + q) * 256 + ch];
        v[q] = f2b(x);
    }
    *(uint4*)(Wef + (size_t)t * 8) = *(uint4*)v;
}

// x (fp32) -> bf16
__global__ void k_xbf(const float* __restrict__ x, u16* __restrict__ xb) {
    int t = blockIdx.x * 256 + threadIdx.x;   // N*64/4 threads
    if (t >= N_NODES * 16) return;
    float4 v = ((const float4*)x)[t];
    u16 o[4] = {f2b(v.x), f2b(v.y), f2b(v.z), f2b(v.w)};
    *(ushort4*)(xb + (size_t)t * 4) = *(ushort4*)o;
}

// W[layer][K][N] fp32 -> Wt[layer(lstride)][N][K] bf16 (32x32 LDS tile transpose)
__global__ void k_twg(const float* __restrict__ W, u16* __restrict__ Wt, int K, int N,
                      unsigned int lstride) {
    __shared__ float tile[32][33];
    int layer = blockIdx.z;
    const float* Wp = W + (size_t)layer * K * N;
    u16* Wtp = Wt + (size_t)layer * lstride;
    int bk = blockIdx.x * 32, bn = blockIdx.y * 32;
    int tx = threadIdx.x & 31, ty = threadIdx.x >> 5; // 32 x 8
#pragma unroll
    for (int q = 0; q < 4; q++) {
        int k = bk + ty + q * 8;
        tile[ty + q * 8][tx] = Wp[(size_t)k * N + bn + tx];
    }
    __syncthreads();
#pragma unroll
    for (int q = 0; q < 4; q++) {
        int n = bn + ty + q * 8;
        Wtp[(size_t)n * K + bk + tx] = f2b(tile[tx][ty + q * 8]);
    }
}

// concat conv_bl / conv_br -> blr[layer][512]
__global__ void k_blr(const float* __restrict__ bl, const float* __restrict__ br,
                      float* __restrict__ blr) {
    int t = blockIdx.x * 256 + threadIdx.x;   // 3*512
    if (t >= 3 * 512) return;
    int l = t >> 9, c = t & 511;
    blr[t] = (c < 256) ? bl[l * 256 + c] : br[l * 256 + (c - 256)];
}

// ---------------------------------------------------------------- GEMM bf16 MFMA
template <int EPI>
__global__ __launch_bounds__(256) void k_gemm_bf(
    const u16* __restrict__ A, int lda,
    const u16* __restrict__ Bt, int ldb, int K,
    const float* __restrict__ bias,
    u16* __restrict__ Cbf, int ldc, int coff,
    float* __restrict__ Cf, int M)
{
    __shared__ __align__(16) u16 As[128 * 40];   // [128][32+8]
    __shared__ __align__(16) u16 Bs[64 * 40];    // [64][32+8]
    int tid = threadIdx.x;
    int lane = tid & 63, w = tid >> 6;
    int m0 = blockIdx.x * 128, n0 = blockIdx.y * 64;

    f32x4 acc[2][4];
#pragma unroll
    for (int i = 0; i < 2; i++)
#pragma unroll
        for (int j = 0; j < 4; j++) acc[i][j] = (f32x4){0.f, 0.f, 0.f, 0.f};

    int srow = tid >> 2, skc = (tid & 3) * 8;    // staging: row, k-chunk
    int lr = lane & 15, lk = (lane >> 4) * 8;

    int ktiles = K >> 5;
    for (int kt = 0; kt < ktiles; kt++) {
        if (kt) __syncthreads();
#pragma unroll
        for (int q = 0; q < 2; q++) {
            int arow = q * 64 + srow;
            uint4 av = make_uint4(0, 0, 0, 0);
            if (m0 + arow < M)
                av = *(const uint4*)(A + (size_t)(m0 + arow) * lda + kt * 32 + skc);
            *(uint4*)&As[arow * 40 + skc] = av;
        }
        {
            uint4 bv = *(const uint4*)(Bt + (size_t)(n0 + srow) * ldb + kt * 32 + skc);
            *(uint4*)&Bs[srow * 40 + skc] = bv;
        }
        __syncthreads();

        short8 af0 = *(const short8*)&As[(w * 32 + lr) * 40 + lk];
        short8 af1 = *(const short8*)&As[(w * 32 + 16 + lr) * 40 + lk];
        short8 bf[4];
#pragma unroll
        for (int nt = 0; nt < 4; nt++)
            bf[nt] = *(const short8*)&Bs[(nt * 16 + lr) * 40 + lk];
#pragma unroll
        for (int nt = 0; nt < 4; nt++) {
            acc[0][nt] = __builtin_amdgcn_mfma_f32_16x16x32_bf16(af0, bf[nt], acc[0][nt], 0, 0, 0);
            acc[1][nt] = __builtin_amdgcn_mfma_f32_16x16x32_bf16(af1, bf[nt], acc[1][nt], 0, 0, 0);
        }
    }

    // C/D layout: col = lane&15, row = (lane>>4)*4 + j
    int rq = (lane >> 4) * 4;
#pragma unroll
    for (int nt = 0; nt < 4; nt++) {
        int col = n0 + nt * 16 + lr;
        float bv = bias[col];
#pragma unroll
        for (int mt = 0; mt < 2; mt++) {
#pragma unroll
            for (int j = 0; j < 4; j++) {
                int row = m0 + w * 32 + mt * 16 + rq + j;
                if (row < M) {
                    float v = acc[mt][nt][j] + bv;
                    if (EPI == 1) {
                        v = fmaxf(v, 0.f);
                        Cf[(size_t)row * ldc + col] = v;
                        Cbf[(size_t)row * ldc + col] = f2b(v);
                    } else {
                        Cbf[(size_t)row * ldc + coff + col] = f2b(v);
                    }
                }
            }
        }
    }
}

// ---------------------------------------------------------------- GATv2 pass 1: alpha per edge
// D = Wef_nt · ea -> D row = channel-in-nt (eg*4+j), col = edge (t16).
// ALL 32 xl/xr gathers hoisted before the nt loop (one latency exposure per chunk).
__global__ __launch_bounds__(256) void k_alpha3(
    const u16* __restrict__ xlr,        // [N,512] bf16 xl|xr
    const u16* __restrict__ ea_bf,      // [E2,16] bf16 CSR order
    const int* __restrict__ csr_src, const int* __restrict__ csr_dst,
    const u16* __restrict__ Wef,        // [16][64][8] bf16 fragments, this layer
    const float* __restrict__ att,      // [256]
    float* __restrict__ alpha)          // [E2,4]
{
    __shared__ __align__(16) u16 wef_s[16 * 64 * 8];   // 16 KB
    __shared__ float att_s[256];
    int tid = threadIdx.x, lane = tid & 63, w = tid >> 6;
    {
        const uint4* s = (const uint4*)Wef;
        uint4* d = (uint4*)wef_s;
#pragma unroll
        for (int q = 0; q < 4; q++) d[q * 256 + tid] = s[q * 256 + tid];
        att_s[tid] = att[tid];
    }
    int eg = lane >> 4, t16 = lane & 15;
    __syncthreads();

    for (int it = 0; it < CPB; it++) {
        int chunk = blockIdx.x * CPB + it;
        if (chunk * 64 >= N_E2) break;
        int e_base = chunk * 64 + w * 16;
        int e_raw = e_base + t16;
        int e = (e_raw < N_E2) ? e_raw : N_E2 - 1;

        short8 eafrag = {0, 0, 0, 0, 0, 0, 0, 0};
        if (eg < 2) eafrag = *(const short8*)(ea_bf + (size_t)e * 16 + eg * 8);
        int s = csr_src[e], d = csr_dst[e];
        const u16* xlp = xlr + (size_t)s * 512 + eg * 4;
        const u16* xrp = xlr + (size_t)d * 512 + 256 + eg * 4;

        // hoist all 32 8B gathers (independent -> all in flight)
        uint2 xlv[16], xrv[16];
#pragma unroll
        for (int nt = 0; nt < 16; nt++) {
            xlv[nt] = *(const uint2*)(xlp + nt * 16);
            xrv[nt] = *(const uint2*)(xrp + nt * 16);
        }

        float pj = 0.f;
#pragma unroll
        for (int nt = 0; nt < 16; nt++) {
            short8 wfrag = *(const short8*)&wef_s[(nt * 64 + lane) * 8];
            f32x4 D = __builtin_amdgcn_mfma_f32_16x16x32_bf16(
                wfrag, eafrag, (f32x4){0.f, 0.f, 0.f, 0.f}, 0, 0, 0);
            int ch0 = nt * 16 + eg * 4;
            float4 at4 = *(const float4*)&att_s[ch0];
            const u16* xl4 = (const u16*)&xlv[nt];
            const u16* xr4 = (const u16*)&xrv[nt];
#pragma unroll
            for (int j = 0; j < 4; j++) {
                float z = D[j] + b2f(xl4[j]) + b2f(xr4[j]);
                z = fmaxf(z, 0.f) + 0.2f * fminf(z, 0.f);   // leaky_relu 0.2
                pj = fmaf(z, ((const float*)&at4)[j], pj);
            }
            if ((nt & 3) == 3) {
                float p = pj;
                p += __shfl_xor(p, 16, 64);   // sum across eg
                p += __shfl_xor(p, 32, 64);
                if (eg == 0 && e_raw < N_E2) alpha[(size_t)e_raw * 4 + (nt >> 2)] = p;
                pj = 0.f;
            }
        }
    }
}

// ---------------------------------------------------------------- GATv2 pass 2: softmax + aggregate
__global__ __launch_bounds__(256) void k_aggr(
    const u16* __restrict__ xlr, const float* __restrict__ alpha,
    const int* __restrict__ rowp, const int* __restrict__ csr_src,
    const float* __restrict__ cbias,
    const float* __restrict__ bng, const float* __restrict__ bnb,
    const float* __restrict__ bnm, const float* __restrict__ bnv,
    float* __restrict__ h, u16* __restrict__ h_bf)   // [N,256] in/out + bf16 copy
{
    __shared__ float lex[4][64][4];      // [wave][edge-in-chunk][head]
    __shared__ int   lsrc[4][64];
    int lane = threadIdx.x & 63;
    int wv = threadIdx.x >> 6;
    int n = blockIdx.x * 4 + wv;
    if (n >= N_NODES) return;
    int st = rowp[n], en = rowp[n + 1];
    int hsel = lane >> 4;                // head owning channels c0..c0+3
    int c0 = lane * 4;

    float m4[4]  = {-3.0e38f, -3.0e38f, -3.0e38f, -3.0e38f};
    float den4[4] = {0.f, 0.f, 0.f, 0.f};
    float acc[4]  = {0.f, 0.f, 0.f, 0.f};

    for (int cs = st; cs < en; cs += 64) {
        int cnt = min(64, en - cs);
        float a4[4];
        int s_i = 0;
        if (lane < cnt) {
            float4 v = *(const float4*)(alpha + (size_t)(cs + lane) * 4);
            a4[0] = v.x; a4[1] = v.y; a4[2] = v.z; a4[3] = v.w;
            s_i = csr_src[cs + lane];
        } else {
            a4[0] = a4[1] = a4[2] = a4[3] = -3.0e38f;
        }
        float cm[4] = {a4[0], a4[1], a4[2], a4[3]};
#pragma unroll
        for (int o = 32; o >= 1; o >>= 1)
#pragma unroll
            for (int u = 0; u < 4; u++) cm[u] = fmaxf(cm[u], __shfl_xor(cm[u], o, 64));
        float sc[4];
#pragma unroll
        for (int u = 0; u < 4; u++) {
            float nm = fmaxf(m4[u], cm[u]);
            sc[u] = __expf(m4[u] - nm);
            den4[u] *= sc[u];
            m4[u] = nm;
        }
        float scl = sc[hsel];
#pragma unroll
        for (int u = 0; u < 4; u++) acc[u] *= scl;
        float ex[4];
#pragma unroll
        for (int u = 0; u < 4; u++) ex[u] = (lane < cnt) ? __expf(a4[u] - m4[u]) : 0.f;
        float sx[4] = {ex[0], ex[1], ex[2], ex[3]};
#pragma unroll
        for (int o = 32; o >= 1; o >>= 1)
#pragma unroll
            for (int u = 0; u < 4; u++) sx[u] += __shfl_xor(sx[u], o, 64);
#pragma unroll
        for (int u = 0; u < 4; u++) den4[u] += sx[u];
        *(float4*)&lex[wv][lane][0] = make_float4(ex[0], ex[1], ex[2], ex[3]);
        lsrc[wv][lane] = s_i;
        // weighted gather-sum: 8 row-gathers (8B bf16x4) in flight per step
        int j = 0;
        for (; j + 8 <= cnt; j += 8) {
            float a[8]; int sj[8];
#pragma unroll
            for (int q = 0; q < 8; q++) { a[q] = lex[wv][j + q][hsel]; sj[q] = lsrc[wv][j + q]; }
            ushort4 xg[8];
#pragma unroll
            for (int q = 0; q < 8; q++) xg[q] = *(const ushort4*)(xlr + (size_t)sj[q] * 512 + c0);
#pragma unroll
            for (int q = 0; q < 8; q++) {
                acc[0] += a[q] * b2f(((const u16*)&xg[q])[0]);
                acc[1] += a[q] * b2f(((const u16*)&xg[q])[1]);
                acc[2] += a[q] * b2f(((const u16*)&xg[q])[2]);
                acc[3] += a[q] * b2f(((const u16*)&xg[q])[3]);
            }
        }
        for (; j < cnt; j++) {
            float a = lex[wv][j][hsel];
            int sj = lsrc[wv][j];
            ushort4 xg = *(const ushort4*)(xlr + (size_t)sj * 512 + c0);
            acc[0] += a * b2f(((const u16*)&xg)[0]);
            acc[1] += a * b2f(((const u16*)&xg)[1]);
            acc[2] += a * b2f(((const u16*)&xg)[2]);
            acc[3] += a * b2f(((const u16*)&xg)[3]);
        }
    }

    float dd = den4[hsel];
    float4 hin = *(const float4*)(h + (size_t)n * 256 + c0);
    float4 cb  = *(const float4*)(cbias + c0);
    float4 gg  = *(const float4*)(bng + c0);
    float4 bb  = *(const float4*)(bnb + c0);
    float4 mm  = *(const float4*)(bnm + c0);
    float4 vv  = *(const float4*)(bnv + c0);
    float hi[4] = {hin.x, hin.y, hin.z, hin.w};
    float cbv[4] = {cb.x, cb.y, cb.z, cb.w};
    float gv[4] = {gg.x, gg.y, gg.z, gg.w};
    float bv[4] = {bb.x, bb.y, bb.z, bb.w};
    float mv[4] = {mm.x, mm.y, mm.z, mm.w};
    float vvv[4] = {vv.x, vv.y, vv.z, vv.w};
    float4 o;
    ushort4 ob;
#pragma unroll
    for (int u = 0; u < 4; u++) {
        float val = acc[u] / dd + cbv[u];
        val = (val - mv[u]) * rsqrtf(vvv[u] + EPS) * gv[u] + bv[u];
        val = fmaxf(val, 0.f) + hi[u];
        ((float*)&o)[u] = val;
        ((u16*)&ob)[u] = f2b(val);
    }
    *(float4*)(h + (size_t)n * 256 + c0) = o;
    *(ushort4*)(h_bf + (size_t)n * 256 + c0) = ob;
}

// ---------------------------------------------------------------- pooling partials (parallel)
__global__ __launch_bounds__(256) void k_poolp(
    const float* __restrict__ h, float* __restrict__ psum, float* __restrict__ pmax)
{
    int g = blockIdx.x, p = blockIdx.y, c = threadIdx.x;
    int gst = (g * N_NODES + N_GRAPHS - 1) / N_GRAPHS;
    int gen = ((g + 1) * N_NODES + N_GRAPHS - 1) / N_GRAPHS;
    int len = gen - gst;
    int cst = gst + (len * p) / 8;
    int cen = gst + (len * (p + 1)) / 8;
    float s = 0.f, mx = -3.0e38f;
    for (int i = cst; i < cen; i++) {
        float v = h[(size_t)i * 256 + c];
        s += v;
        mx = fmaxf(mx, v);
    }
    psum[(size_t)(g * 8 + p) * 256 + c] = s;
    pmax[(size_t)(g * 8 + p) * 256 + c] = mx;
}

// ---------------------------------------------------------------- fused classifier head
__global__ __launch_bounds__(256) void k_head(
    const float* __restrict__ psum, const float* __restrict__ pmax,
    const float* __restrict__ W1, const float* __restrict__ b1,
    const float* __restrict__ g1, const float* __restrict__ bt1,
    const float* __restrict__ m1, const float* __restrict__ v1,
    const float* __restrict__ W2, const float* __restrict__ b2,
    const float* __restrict__ g2, const float* __restrict__ bt2,
    const float* __restrict__ m2, const float* __restrict__ v2,
    const float* __restrict__ W3, const float* __restrict__ b3,
    float* __restrict__ out)
{
    __shared__ float xp_s[512];
    __shared__ float z1_s[256];
    __shared__ float z2p[2][128];
    __shared__ float z2_s[128];
    int g = blockIdx.x, c = threadIdx.x;
    int gst = (g * N_NODES + N_GRAPHS - 1) / N_GRAPHS;
    int gen = ((g + 1) * N_NODES + N_GRAPHS - 1) / N_GRAPHS;

    float s = 0.f, mx = -3.0e38f;
#pragma unroll
    for (int p = 0; p < 8; p++) {
        s += psum[(size_t)(g * 8 + p) * 256 + c];
        mx = fmaxf(mx, pmax[(size_t)(g * 8 + p) * 256 + c]);
    }
    xp_s[c] = s / (float)(gen - gst);
    xp_s[256 + c] = mx;
    __syncthreads();

    float a0 = 0.f, a1 = 0.f, a2 = 0.f, a3 = 0.f;
#pragma unroll 4
    for (int k = 0; k < 512; k += 4) {
        a0 = fmaf(xp_s[k + 0], W1[(k + 0) * 256 + c], a0);
        a1 = fmaf(xp_s[k + 1], W1[(k + 1) * 256 + c], a1);
        a2 = fmaf(xp_s[k + 2], W1[(k + 2) * 256 + c], a2);
        a3 = fmaf(xp_s[k + 3], W1[(k + 3) * 256 + c], a3);
    }
    float a = (a0 + a1) + (a2 + a3) + b1[c];
    a = (a - m1[c]) * rsqrtf(v1[c] + EPS) * g1[c] + bt1[c];
    z1_s[c] = fmaxf(a, 0.f);
    __syncthreads();

    {
        int c2 = c & 127, half = c >> 7;
        float b_acc = 0.f;
#pragma unroll 4
        for (int k = 0; k < 128; k++) {
            int kk = half * 128 + k;
            b_acc = fmaf(z1_s[kk], W2[kk * 128 + c2], b_acc);
        }
        z2p[half][c2] = b_acc;
    }
    __syncthreads();
    if (c < 128) {
        float a2v = z2p[0][c] + z2p[1][c] + b2[c];
        a2v = (a2v - m2[c]) * rsqrtf(v2[c] + EPS) * g2[c] + bt2[c];
        z2_s[c] = fmaxf(a2v, 0.f);
    }
    __syncthreads();

    if (c < 64) {
        float a3v = z2_s[c] * W3[c] + z2_s[c + 64] * W3[c + 64];
#pragma unroll
        for (int o = 32; o >= 1; o >>= 1) a3v += __shfl_xor(a3v, o, 64);
        if (c == 0) out[g] = a3v + b3[0];
    }
}

// ---------------------------------------------------------------- launch
extern "C" void kernel_launch(void* const* d_in, const int* in_sizes, int n_in,
                              void* d_out, int out_size, void* d_ws, size_t ws_size,
                              hipStream_t stream) {
    const float* x         = (const float*)d_in[0];
    const int*   ei        = (const int*)d_in[1];
    const int*   src       = ei;
    const int*   dst       = ei + N_EDGES;
    const float* edge_attr = (const float*)d_in[3];
    const float* enc_W     = (const float*)d_in[4];
    const float* enc_b     = (const float*)d_in[5];
    const float* conv_Wl   = (const float*)d_in[6];
    const float* conv_bl   = (const float*)d_in[7];
    const float* conv_Wr   = (const float*)d_in[8];
    const float* conv_br   = (const float*)d_in[9];
    const float* conv_We   = (const float*)d_in[10];
    const float* conv_att  = (const float*)d_in[11];
    const float* conv_bias = (const float*)d_in[12];
    const float* bn_g      = (const float*)d_in[13];
    const float* bn_b      = (const float*)d_in[14];
    const float* bn_m      = (const float*)d_in[15];
    const float* bn_v      = (const float*)d_in[16];
    const float* cls_W1    = (const float*)d_in[17];
    const float* cls_b1    = (const float*)d_in[18];
    const float* cls_g1    = (const float*)d_in[19];
    const float* cls_bt1   = (const float*)d_in[20];
    const float* cls_m1    = (const float*)d_in[21];
    const float* cls_v1    = (const float*)d_in[22];
    const float* cls_W2    = (const float*)d_in[23];
    const float* cls_b2    = (const float*)d_in[24];
    const float* cls_g2    = (const float*)d_in[25];
    const float* cls_bt2   = (const float*)d_in[26];
    const float* cls_m2    = (const float*)d_in[27];
    const float* cls_v2    = (const float*)d_in[28];
    const float* cls_W3    = (const float*)d_in[29];
    const float* cls_b3    = (const float*)d_in[30];
    float* out = (float*)d_out;

    char* ws = (char*)d_ws;
    size_t off = 0;
    auto alloc = [&](size_t bytes) -> void* {
        void* p = ws + off;
        off += (bytes + 255) & ~(size_t)255;
        return p;
    };
    float* h       = (float*)alloc((size_t)N_NODES * 256 * 4);    // 20.5 MB
    u16*   h_bf    = (u16*)alloc((size_t)N_NODES * 256 * 2);      // 10.2 MB
    u16*   xlr_bf  = (u16*)alloc((size_t)N_NODES * 512 * 2);      // 20.5 MB
    float* lattr   = (float*)alloc((size_t)N_NODES * 16 * 4);     // 1.3 MB
    u16*   ea_bf   = (u16*)alloc((size_t)N_E2 * 16 * 2);          // 10.9 MB
    float* alphas  = (float*)alloc((size_t)N_E2 * 4 * 4);         // 5.4 MB
    u16*   x_bf    = (u16*)alloc((size_t)N_NODES * 64 * 2);       // 2.6 MB
    u16*   enc_Wt  = (u16*)alloc((size_t)64 * 256 * 2);           // 32 KB
    u16*   Wtlr    = (u16*)alloc((size_t)3 * 512 * 256 * 2);      // 786 KB
    float* blr     = (float*)alloc((size_t)3 * 512 * 4);          // 6 KB
    u16*   Wef     = (u16*)alloc((size_t)3 * 16 * 64 * 8 * 2);    // 48 KB
    float* psum    = (float*)alloc((size_t)N_GRAPHS * 8 * 256 * 4); // 2 MB
    float* pmax    = (float*)alloc((size_t)N_GRAPHS * 8 * 256 * 4); // 2 MB
    int*   cnt     = (int*)alloc((size_t)N_NODES * 4);
    int*   rowp    = (int*)alloc((size_t)(N_NODES + 1) * 4);
    int*   cursor  = (int*)alloc((size_t)N_NODES * 4);
    int*   csr_src = (int*)alloc((size_t)(N_E2 + 512) * 4);
    int*   csr_dst = (int*)alloc((size_t)(N_E2 + 512) * 4);
    int*   csr_aid = (int*)alloc((size_t)N_E2 * 4);
    int*   part    = (int*)alloc(64 * 4);

    // CSR build
    k_init<<<(N_NODES + 255) / 256, 256, 0, stream>>>(cnt, cursor);
    k_count<<<(N_EDGES + 255) / 256, 256, 0, stream>>>(dst, cnt);
    k_scan1<<<NSCAN, 256, 0, stream>>>(cnt, rowp, part);
    k_scan2<<<1, 1, 0, stream>>>(part, rowp);
    k_scan3<<<NSCAN, 256, 0, stream>>>(rowp, part);
    k_fill<<<(N_E2 + 255) / 256, 256, 0, stream>>>(src, dst, rowp, cursor, csr_src, csr_dst, csr_aid);
    k_pad<<<1, 512, 0, stream>>>(csr_src, csr_dst);
    k_loopattr<<<(N_NODES * 16 + 255) / 256, 256, 0, stream>>>(rowp, csr_aid, edge_attr, lattr);
    k_eacsr<<<(N_E2 * 2 + 255) / 256, 256, 0, stream>>>(csr_aid, edge_attr, lattr, ea_bf);

    // weight / input prep
    k_xbf<<<(N_NODES * 16 + 255) / 256, 256, 0, stream>>>(x, x_bf);
    k_twg<<<dim3(2, 8, 1), 256, 0, stream>>>(enc_W, enc_Wt, 64, 256, 64 * 256);
    k_twg<<<dim3(8, 8, 3), 256, 0, stream>>>(conv_Wl, Wtlr, 256, 256, 512 * 256);
    k_twg<<<dim3(8, 8, 3), 256, 0, stream>>>(conv_Wr, Wtlr + 256 * 256, 256, 256, 512 * 256);
    k_blr<<<6, 256, 0, stream>>>(conv_bl, conv_br, blr);
    k_wef<<<12, 256, 0, stream>>>(conv_We, Wef);

    dim3 ggrid((N_NODES + 127) / 128, 4);
    dim3 ggrid2((N_NODES + 127) / 128, 8);
    // encoder: h = relu(x @ enc_W + enc_b) via MFMA, emits h fp32 + h_bf
    k_gemm_bf<1><<<ggrid, 256, 0, stream>>>(x_bf, 64, enc_Wt, 64, 64,
                                            enc_b, h_bf, 256, 0, h, N_NODES);

    // 3 GATv2 layers
    int nchunks = (N_E2 + 63) / 64;               // 5313
    int ablocks = (nchunks + CPB - 1) / CPB;      // 1329
    for (int i = 0; i < 3; i++) {
        // merged Wl|Wr GEMM: one dispatch, xlr = [xl | xr]
        k_gemm_bf<0><<<ggrid2, 256, 0, stream>>>(h_bf, 256, Wtlr + (size_t)i * 131072, 256, 256,
                                                 blr + (size_t)i * 512, xlr_bf, 512, 0, nullptr, N_NODES);
        k_alpha3<<<ablocks, 256, 0, stream>>>(
            xlr_bf, ea_bf, csr_src, csr_dst,
            Wef + (size_t)i * 8192, conv_att + (size_t)i * 256, alphas);
        k_aggr<<<N_NODES / 4, 256, 0, stream>>>(
            xlr_bf, alphas, rowp, csr_src,
            conv_bias + (size_t)i * HID,
            bn_g + (size_t)i * HID, bn_b + (size_t)i * HID,
            bn_m + (size_t)i * HID, bn_v + (size_t)i * HID, h, h_bf);
    }

    // pooling partials + fused classifier
    k_poolp<<<dim3(N_GRAPHS, 8), 256, 0, stream>>>(h, psum, pmax);
    k_head<<<N_GRAPHS, 256, 0, stream>>>(
        psum, pmax, cls_W1, cls_b1, cls_g1, cls_bt1, cls_m1, cls_v1,
        cls_W2, cls_b2, cls_g2, cls_bt2, cls_m2, cls_v2,
        cls_W3, cls_b3, out);
}